// Round 8
// baseline (861.945 us; speedup 1.0000x reference)
//
#include <hip/hip_runtime.h>
#include <cfloat>
#include <climits>
#include <math.h>

#define HD   768
#define MSW  10
#define WFK  20
#define DD   2324    // 3*768+20
#define K2   50
#define NEGF (-1e30f)

// MFMA geometry (K padded to mult of 128 for deep-K tiles)
#define KPAD 2432          // 19*128, >= DD
#define KAW  4864          // 2*KPAD  (K-concat of [cur | att] for the gate GEMM)
#define MPAD 896           // 7 * 128 (>= m=819)
#define NPAD 2432          // 19 * 128 (>= DD)

typedef __attribute__((ext_vector_type(8))) short    s8b;
typedef __attribute__((ext_vector_type(8))) unsigned short u16x8;
typedef __attribute__((ext_vector_type(4))) float    f32x4;

__device__ inline unsigned short f2bf(float f){
  unsigned u = __float_as_uint(f);
  unsigned r = (u + 0x7FFFu + ((u >> 16) & 1u)) >> 16;   // RNE
  return (unsigned short)r;
}
__device__ inline float bf2f(unsigned short h){
  return __uint_as_float(((unsigned)h) << 16);
}

// async global->LDS, 16B per lane; LDS dest must be wave-uniform base (+lane*16 implicit)
__device__ __forceinline__ void gload16(const unsigned short* g, void* l){
  __builtin_amdgcn_global_load_lds(
      (const __attribute__((address_space(1))) void*)g,
      (__attribute__((address_space(3))) void*)l, 16, 0, 0);
}

// ---- bank-conflict swizzle (both-sides involution, rule #21) ----------------
// Staging planes store chunk (16B = 8 shorts) j of row r at position j^(r&7)
// within each 64-short K-tile. global_load_lds copies linearly; ds_read XORs.
// Verified R2: SQ_LDS_BANK_CONFLICT 7.76M -> 0.
__device__ __forceinline__ int swz_col(int row, int col){
  return col ^ ((row & 7) << 3);
}

// ---- T1: XCD-aware bijective block remap (m204 form) ------------------------
// Verified R7: g1 64.4 -> ~58us, frame -30us. Pure index permutation.
__device__ __forceinline__ void xcd_remap(int &bx, int &by, int &bz){
  int nwg  = (int)(gridDim.x*gridDim.y*gridDim.z);
  int orig = (int)(blockIdx.x + gridDim.x*(blockIdx.y + gridDim.y*blockIdx.z));
  int q = nwg >> 3, r = nwg & 7;
  int x8 = orig & 7, o8 = orig >> 3;
  int wg = (x8 < r ? x8*(q+1) : r*(q+1) + (x8-r)*q) + o8;
  bx = wg % (int)gridDim.x;
  int tmp = wg / (int)gridDim.x;
  by = tmp % (int)gridDim.y;
  bz = tmp / (int)gridDim.y;
}

// ---------------- per-token projections: alphas, p1,p2,p3 -------------------
__global__ void row_proj(const float* __restrict__ seq, const float* __restrict__ Wa,
                         const float* __restrict__ ba, const float* __restrict__ Wm,
                         float* alphas, float* p1, float* p2, float* p3, int W){
  int w = blockIdx.x; int tid = threadIdx.x;
  const float* row = seq + (size_t)w * HD;
  float s0=0.f, s1=0.f, s2=0.f, s3=0.f;
  for(int h=tid; h<HD; h+=256){
    float x = row[h];
    s0 += x * Wa[h];
    s1 += x * Wm[h];
    s2 += x * Wm[HD + h];
    s3 += x * Wm[2*HD + h];
  }
  __shared__ float r0[256], r1[256], r2[256], r3[256];
  r0[tid]=s0; r1[tid]=s1; r2[tid]=s2; r3[tid]=s3;
  __syncthreads();
  for(int st=128; st>0; st>>=1){
    if(tid<st){ r0[tid]+=r0[tid+st]; r1[tid]+=r1[tid+st]; r2[tid]+=r2[tid+st]; r3[tid]+=r3[tid+st]; }
    __syncthreads();
  }
  if(tid==0){ alphas[w]=r0[0]+ba[0]; p1[w]=r1[0]; p2[w]=r2[0]; p3[w]=r3[0]; }
}

// ---------------- mention scoring per candidate -----------------------------
__global__ void mention_kernel(const float* __restrict__ alphas, const float* __restrict__ p1,
                               const float* __restrict__ p2, const float* __restrict__ p3,
                               const float* __restrict__ wfeat, const float* __restrict__ Wm,
                               const float* __restrict__ bm,
                               const int* __restrict__ smap, const int* __restrict__ gs,
                               const int* __restrict__ ge, const int* __restrict__ cid, int G,
                               float* mscore, float* mmask, int* ccl, int W){
  int c = blockIdx.x*blockDim.x + threadIdx.x;
  int C = W * MSW;
  if(c >= C) return;
  int s = c / MSW, r = c - s*MSW;
  int e = s + r; int ec = min(e, W-1);
  int L = ec - s;
  bool valid = (e < W) && (smap[s] == smap[ec]);
  float maxa = -FLT_MAX;
  for(int j=0;j<=L;j++) maxa = fmaxf(maxa, alphas[s+j]);
  float sum=0.f, sdot=0.f;
  for(int j=0;j<=L;j++){ float ee = expf(alphas[s+j]-maxa); sum += ee; sdot += ee*p3[s+j]; }
  sdot /= sum;
  float wp=0.f;
  for(int f=0; f<WFK; f++) wp += wfeat[L*WFK+f] * Wm[3*HD+f];
  float ms = p1[s] + p2[ec] + sdot + wp + bm[0];
  mscore[c] = ms;
  mmask[c]  = valid ? ms : NEGF;
  int cc = 0;
  for(int g=0; g<G; g++) if(s==gs[g] && ec==ge[g]) cc += cid[g];
  ccl[c] = cc;
}

// ---------------- single-block exact top-m radix select ---------------------
__device__ inline unsigned fkey(float f){
  unsigned b = __float_as_uint(f);
  return (b & 0x80000000u) ? ~b : (b | 0x80000000u);
}

__global__ __launch_bounds__(1024)
void select_kernel(const float* __restrict__ mmask, const float* __restrict__ mscore,
                   const int* __restrict__ ccl, int m, int C, int W,
                   int* top_idx, float* tscore, int* tclust,
                   float* out_ts, float* out_te){
  const int T = 1024;
  int tid = threadIdx.x;
  int chunk = (C + T - 1)/T;
  int lo = tid*chunk, hi = min(lo+chunk, C);
  int n = hi - lo; if(n < 0) n = 0;
  unsigned kb[32];
  for(int t=0;t<n;t++) kb[t] = fkey(mmask[lo+t]);

  __shared__ unsigned s_hist[256];
  __shared__ unsigned s_scan[1024];
  __shared__ unsigned s_pref;
  __shared__ int s_rem;
  if(tid==0){ s_pref=0u; s_rem=m; }
  __syncthreads();

  for(int b=3;b>=0;b--){
    if(tid<256) s_hist[tid]=0u;
    __syncthreads();
    unsigned pref = s_pref;
    unsigned msk = (b==3)?0u:(0xFFFFFFFFu << ((b+1)*8));
    for(int t=0;t<n;t++){
      unsigned u = kb[t];
      if((u & msk)==pref) atomicAdd(&s_hist[(u>>(b*8))&0xFFu], 1u);
    }
    __syncthreads();
    if(tid==0){
      int rem = s_rem; unsigned acc=0u; int bin;
      for(bin=255;bin>=1;bin--){
        unsigned h = s_hist[bin];
        if(acc + h >= (unsigned)rem) break;
        acc += h;
      }
      if(bin < 0) bin = 0;
      s_pref = pref | ((unsigned)bin << (b*8));
      s_rem = rem - (int)acc;
    }
    __syncthreads();
  }
  unsigned Tk = s_pref;
  int need = s_rem;

  unsigned nG=0, nE=0;
  for(int t=0;t<n;t++){ unsigned u=kb[t]; nG += (u>Tk)?1u:0u; nE += (u==Tk)?1u:0u; }

  s_scan[tid]=nE; __syncthreads();
  for(int off=1; off<T; off<<=1){
    unsigned x = (tid>=off)? s_scan[tid-off]:0u; __syncthreads();
    s_scan[tid]+=x; __syncthreads();
  }
  unsigned eqBase = s_scan[tid]-nE;
  __syncthreads();

  int takeLeft = need - (int)eqBase;
  int take = takeLeft<0?0:(takeLeft>(int)nE?(int)nE:takeLeft);
  unsigned selCnt = nG + (unsigned)take;

  s_scan[tid]=selCnt; __syncthreads();
  for(int off=1; off<T; off<<=1){
    unsigned x = (tid>=off)? s_scan[tid-off]:0u; __syncthreads();
    s_scan[tid]+=x; __syncthreads();
  }
  unsigned posBase = s_scan[tid]-selCnt;

  int pos = (int)posBase; int eq = (int)eqBase;
  for(int t=0;t<n;t++){
    unsigned u = kb[t];
    bool sel = false;
    if(u>Tk) sel=true;
    else if(u==Tk){ if(eq<need) sel=true; eq++; }
    if(sel){
      int c = lo+t;
      top_idx[pos] = c;
      int s = c/MSW, r = c - s*MSW; int e = min(s + r, W-1);
      tscore[pos] = mscore[c];
      tclust[pos] = ccl[c];
      out_ts[pos] = (float)s;
      out_te[pos] = (float)e;
      pos++;
    }
  }
}

// ---------------- build top_rep (m x D) -------------------------------------
__global__ void build_rep(const float* __restrict__ seq, const float* __restrict__ alphas,
                          const float* __restrict__ wfeat, const int* __restrict__ top_idx,
                          float* rep, int W){
  int i = blockIdx.x; int tid = threadIdx.x;
  int c = top_idx[i];
  int s = c/MSW, r = c - s*MSW; int ec = min(s + r, W-1); int L = ec - s;
  float wv[MSW];
  float maxa = -FLT_MAX;
  for(int j=0;j<=L;j++) maxa = fmaxf(maxa, alphas[s+j]);
  float sum = 0.f;
  for(int j=0;j<=L;j++){ wv[j] = expf(alphas[s+j]-maxa); sum += wv[j]; }
  float inv = 1.f/sum;
  float* o = rep + (size_t)i*DD;
  for(int d=tid; d<HD; d+=256){
    o[d]      = seq[(size_t)s*HD + d];
    o[HD+d]   = seq[(size_t)ec*HD + d];
    float sp = 0.f;
    for(int j=0;j<=L;j++) sp += wv[j]*seq[(size_t)(s+j)*HD + d];
    o[2*HD+d] = sp*inv;
  }
  for(int f=tid; f<WFK; f+=256) o[3*HD+f] = wfeat[L*WFK+f];
}

// ---------------- zero helper -----------------------------------------------
__global__ void zero_buf(float* __restrict__ p, int n){
  int i = blockIdx.x*256 + threadIdx.x;
  if(i < n) p[i] = 0.f;
}

// ---------------- split-bf16 conversions (SWIZZLED output layout) -----------
__global__ void conv_split(const float* __restrict__ src, int rows, int cols,
                           unsigned short* __restrict__ hi, unsigned short* __restrict__ lo){
  int idx = blockIdx.x*256 + threadIdx.x;
  if(idx >= MPAD*KPAD) return;
  int row = idx / KPAD, col = idx - row*KPAD;
  float v = (row < rows && col < cols) ? src[(size_t)row*cols + col] : 0.f;
  unsigned short h = f2bf(v);
  int w = row*KPAD + swz_col(row, col);
  hi[w] = h;
  lo[w] = f2bf(v - bf2f(h));
}

// Wc (DD x DD) -> transposed hi/lo planes (NPAD x KPAD): Wt[n][k] = Wc[k][n]
__global__ void conv_split_wcT(const float* __restrict__ Wc,
                               unsigned short* __restrict__ WtH, unsigned short* __restrict__ WtL){
  int n  = blockIdx.y*64 + threadIdx.x;
  int k8 = blockIdx.x*8;
  u16x8 vh, vl;
  #pragma unroll
  for(int j=0;j<8;j++){
    int k = k8 + j;
    float f = (n < DD && k < DD) ? Wc[(size_t)k*DD + n] : 0.f;
    unsigned short h = f2bf(f);
    vh[j] = h;
    vl[j] = f2bf(f - bf2f(h));
  }
  int k8s = swz_col(n, k8);          // XOR hits bits 3-5 only; 16B granularity
  *(u16x8*)(WtH + (size_t)n*KPAD + k8s) = vh;
  *(u16x8*)(WtL + (size_t)n*KPAD + k8s) = vl;
}

// cur -> CurBf (bf16) and Xbf = bf16(cur * w3row)  (both MPAD x KPAD)
__global__ void conv_slow_ops(const float* __restrict__ cur, const float* __restrict__ Wa3,
                              unsigned short* __restrict__ CurBf, unsigned short* __restrict__ Xbf,
                              int m){
  int idx = blockIdx.x*256 + threadIdx.x;
  if(idx >= MPAD*KPAD) return;
  int row = idx / KPAD, col = idx - row*KPAD;
  float v = 0.f, w = 0.f;
  if(row < m && col < DD){ v = cur[(size_t)row*DD + col]; w = Wa3[2*DD + col]; }
  int ws = row*KPAD + swz_col(row, col);
  CurBf[ws] = f2bf(v);
  Xbf[ws]   = f2bf(v * w);
}

// ---------------- split-bf16 3-term MFMA GEMM, split-K ----------------------
// R5-measured-best structure + R7 T1 remap: single-buffered linear LDS via
// global_load_lds, 2 barriers per BK=64 step. LDS = 4 planes x 16 KiB = 64 KiB
// -> 2 blocks/CU. Swizzled reads (conflicts = 0). Grid <= 512 blocks.
__global__ __launch_bounds__(256,2)
void gemm_split3_sk(const unsigned short* __restrict__ Ah, const unsigned short* __restrict__ Al,
                    const unsigned short* __restrict__ Bth, const unsigned short* __restrict__ Btl,
                    float* __restrict__ C, int M, int N, int ldc){
  __shared__ __align__(16) unsigned short sAh[128*64];
  __shared__ __align__(16) unsigned short sAl[128*64];
  __shared__ __align__(16) unsigned short sBh[128*64];
  __shared__ __align__(16) unsigned short sBl[128*64];
  int bx, by, bz; xcd_remap(bx, by, bz);
  int t = threadIdx.x;
  int row0 = by*128, col0 = bx*128;
  const int tiles = KPAD/64;                              // 38
  int per = (tiles + (int)gridDim.z - 1)/(int)gridDim.z;
  int tb = min(bz*per, tiles), te = min(tb + per, tiles);
  if(tb >= te) return;
  int lane = t&63, w = t>>6;
  int wr = (w>>1)*64, wc = (w&1)*64;
  int quad = lane>>4, l15 = lane&15;
  int seg = lane&7;
  size_t ro = (size_t)(w*8 + (lane>>3));                  // staging row within 32-row group
  const unsigned short* gAh = Ah  + ((size_t)row0 + ro)*KPAD + seg*8;
  const unsigned short* gAl = Al  + ((size_t)row0 + ro)*KPAD + seg*8;
  const unsigned short* gBh = Bth + ((size_t)col0 + ro)*KPAD + seg*8;
  const unsigned short* gBl = Btl + ((size_t)col0 + ro)*KPAD + seg*8;
  const int lds0 = (w*8)*64;                              // wave-uniform LDS base (shorts)
  // swizzled read chunk offsets (shorts): ks=0 -> c0, ks=1 -> c0^32
  const int c0 = ((quad ^ (l15 & 7)) << 3);

  f32x4 acc[4][4];
  #pragma unroll
  for(int mi=0;mi<4;mi++)
    #pragma unroll
    for(int ni=0;ni<4;ni++) acc[mi][ni] = (f32x4){0.f,0.f,0.f,0.f};

  for(int kt=tb; kt<te; ++kt){
    size_t k0 = (size_t)kt*64;
    #pragma unroll
    for(int r=0;r<4;r++){
      size_t go = (size_t)(r*32)*KPAD + k0;
      int lo = lds0 + r*32*64;
      gload16(gAh + go, sAh + lo);
      gload16(gAl + go, sAl + lo);
      gload16(gBh + go, sBh + lo);
      gload16(gBl + go, sBl + lo);
    }
    __syncthreads();   // drains vmcnt(0): tile landed in LDS
    #pragma unroll
    for(int ks=0;ks<2;ks++){
      const int co = c0 ^ (ks<<5);
      s8b fah[4], fal[4], fbh[4], fbl[4];
      #pragma unroll
      for(int mi=0;mi<4;mi++){
        int ra = (wr+mi*16+l15)*64 + co;
        fah[mi] = *(const s8b*)&sAh[ra];
        fal[mi] = *(const s8b*)&sAl[ra];
      }
      #pragma unroll
      for(int ni=0;ni<4;ni++){
        int rb = (wc+ni*16+l15)*64 + co;
        fbh[ni] = *(const s8b*)&sBh[rb];
        fbl[ni] = *(const s8b*)&sBl[rb];
      }
      #pragma unroll
      for(int mi=0;mi<4;mi++)
        #pragma unroll
        for(int ni=0;ni<4;ni++){
          acc[mi][ni] = __builtin_amdgcn_mfma_f32_16x16x32_bf16(fah[mi], fbh[ni], acc[mi][ni], 0,0,0);
          acc[mi][ni] = __builtin_amdgcn_mfma_f32_16x16x32_bf16(fah[mi], fbl[ni], acc[mi][ni], 0,0,0);
          acc[mi][ni] = __builtin_amdgcn_mfma_f32_16x16x32_bf16(fal[mi], fbh[ni], acc[mi][ni], 0,0,0);
        }
    }
    __syncthreads();   // all waves done reading before next stage overwrites
  }

  #pragma unroll
  for(int ni=0;ni<4;ni++){
    int gn = col0 + wc + ni*16 + l15;
    if(gn >= N) continue;
    #pragma unroll
    for(int mi=0;mi<4;mi++){
      #pragma unroll
      for(int rg=0;rg<4;rg++){
        int gr = row0 + wr + mi*16 + quad*4 + rg;
        if(gr >= M) continue;
        atomicAdd(&C[(size_t)gr*ldc + gn], acc[mi][ni][rg]);
      }
    }
  }
}

// ---------------- plain bf16 MFMA GEMM, split-K (single-buf, 4 blk/CU) ------
// R8: single-buffered 32 KiB LDS (R5-proven loop shape) + launch_bounds(256,4)
// -> 4 blocks/CU capacity (1024 slots). Cross-block TLP hides the per-step
// vmcnt drain (in-block dbuf prefetch was dead at the barrier anyway — R6).
// Used for slow-score P GEMM (ldk=KPAD) and gate GEMM (ldk=KAW). + T1 remap.
__global__ __launch_bounds__(256,4)
void gemm_bf16_m97(const unsigned short* __restrict__ A, const unsigned short* __restrict__ Bt,
                   float* __restrict__ C, int M, int N, int ldc, int ldk, int tiles){
  __shared__ __align__(16) unsigned short sA[128*64];
  __shared__ __align__(16) unsigned short sB[128*64];
  int bx, by, bz; xcd_remap(bx, by, bz);
  int t = threadIdx.x;
  int row0 = by*128, col0 = bx*128;
  int per = (tiles + (int)gridDim.z - 1)/(int)gridDim.z;
  int tb = min(bz*per, tiles), te = min(tb + per, tiles);
  if(tb >= te) return;
  int lane = t&63, w = t>>6;
  int wr = (w>>1)*64, wc = (w&1)*64;
  int quad = lane>>4, l15 = lane&15;
  int seg = lane&7;
  size_t ro = (size_t)(w*8 + (lane>>3));
  const unsigned short* gA = A  + ((size_t)row0 + ro)*ldk + seg*8;
  const unsigned short* gB = Bt + ((size_t)col0 + ro)*ldk + seg*8;
  const int lds0 = (w*8)*64;
  const int c0 = ((quad ^ (l15 & 7)) << 3);

  f32x4 acc[4][4];
  #pragma unroll
  for(int mi=0;mi<4;mi++)
    #pragma unroll
    for(int ni=0;ni<4;ni++) acc[mi][ni] = (f32x4){0.f,0.f,0.f,0.f};

  for(int kt=tb; kt<te; ++kt){
    size_t k0 = (size_t)kt*64;
    #pragma unroll
    for(int r=0;r<4;r++){
      size_t go = (size_t)(r*32)*ldk + k0;
      int lo = lds0 + r*32*64;
      gload16(gA + go, sA + lo);
      gload16(gB + go, sB + lo);
    }
    __syncthreads();   // drain: tile in LDS
    #pragma unroll
    for(int ks=0;ks<2;ks++){
      const int co = c0 ^ (ks<<5);
      s8b fa[4], fb[4];
      #pragma unroll
      for(int mi=0;mi<4;mi++) fa[mi] = *(const s8b*)&sA[(wr+mi*16+l15)*64 + co];
      #pragma unroll
      for(int ni=0;ni<4;ni++) fb[ni] = *(const s8b*)&sB[(wc+ni*16+l15)*64 + co];
      #pragma unroll
      for(int mi=0;mi<4;mi++)
        #pragma unroll
        for(int ni=0;ni<4;ni++)
          acc[mi][ni] = __builtin_amdgcn_mfma_f32_16x16x32_bf16(fa[mi], fb[ni], acc[mi][ni], 0,0,0);
    }
    __syncthreads();   // all waves done reading before next stage overwrites
  }

  #pragma unroll
  for(int ni=0;ni<4;ni++){
    int gn = col0 + wc + ni*16 + l15;
    if(gn >= N) continue;
    #pragma unroll
    for(int mi=0;mi<4;mi++){
      #pragma unroll
      for(int rg=0;rg<4;rg++){
        int gr = row0 + wr + mi*16 + quad*4 + rg;
        if(gr >= M) continue;
        atomicAdd(&C[(size_t)gr*ldc + gn], acc[mi][ni][rg]);
      }
    }
  }
}

// ---------------- per-row top-50 antecedents (1 wave / row) -----------------
// Register-resident selection (R5-verified: bit-identical, ~10x faster than LDS).
#define NT 13   // ceil(m/64) for m<=832
__global__ void topante_kernel(const float* __restrict__ tscore, const float* __restrict__ bilin,
                               int m, int* ante, float* tafast, float* out_ante){
  int i = blockIdx.x; int lane = threadIdx.x;
  float tsi = tscore[i];
  float v[NT];
  #pragma unroll
  for(int t=0;t<NT;t++){
    int j = lane + t*64;
    float f = -FLT_MAX;
    if(j < m){
      f = tsi + tscore[j];
      f += (j < i) ? 0.f : NEGF;
      f += bilin[(size_t)i*m + j];
    }
    v[t] = f;
  }
  unsigned consumed = 0u;
  int r_ante = 0; float r_fast = 0.f;
  for(int it=0; it<K2; ++it){
    float lv = -FLT_MAX; int li = m;
    #pragma unroll
    for(int t=0;t<NT;t++){
      bool live = ((consumed >> t) & 1u) == 0u;
      if(live && v[t] > lv){ lv = v[t]; li = lane + t*64; }
    }
    float bv = lv; int bi = li;
    #pragma unroll
    for(int off=32; off>0; off>>=1){
      float ov = __shfl_xor(bv, off);
      int   oi = __shfl_xor(bi, off);
      if(ov > bv || (ov == bv && oi < bi)){ bv = ov; bi = oi; }
    }
    if(bi < m && (bi & 63) == lane) consumed |= (1u << (bi >> 6));
    if(lane == it){ r_ante = bi; r_fast = bv; }
  }
  if(lane < K2){
    ante[(size_t)i*K2 + lane]   = r_ante;
    tafast[(size_t)i*K2 + lane] = r_fast;
    out_ante[(size_t)i*K2+lane] = (float)r_ante;
  }
}

// ---------------- depth loop pieces -----------------------------------------
__global__ void uv_kernel(const float* __restrict__ reps, const float* __restrict__ Wa3,
                          float* u, float* v, int m){
  int i = blockIdx.x; int tid = threadIdx.x;
  const float* rp = reps + (size_t)i*DD;
  float s1=0.f, s2=0.f;
  for(int d=tid; d<DD; d+=256){ float x = rp[d]; s1 += x*Wa3[d]; s2 += x*Wa3[DD+d]; }
  __shared__ float r1[256], r2[256];
  r1[tid]=s1; r2[tid]=s2; __syncthreads();
  for(int st=128; st>0; st>>=1){
    if(tid<st){ r1[tid]+=r1[tid+st]; r2[tid]+=r2[tid+st]; }
    __syncthreads();
  }
  if(tid==0){ u[i]=r1[0]; v[i]=r2[0]; }
}

// sc[p] = tafast[p] + u[i] + v[j] + P[i][j] + ba
__global__ void slow_gather(const float* __restrict__ P, const float* __restrict__ u,
                            const float* __restrict__ v, const int* __restrict__ ante,
                            const float* __restrict__ tafast, const float* __restrict__ ba,
                            float* sc, int m){
  int p = blockIdx.x*256 + threadIdx.x;
  if(p >= m*K2) return;
  int i = p / K2; int j = ante[p];
  sc[p] = tafast[p] + u[i] + v[j] + P[(size_t)i*m + j] + ba[0];
}

__global__ void attend_kernel(const float* __restrict__ reps, const float* __restrict__ sc,
                              const int* __restrict__ ante, float* att, int m){
  int i = blockIdx.x; int tid = threadIdx.x;
  __shared__ float wts[K2+1];
  __shared__ float scs[K2];
  __shared__ int   js[K2];
  if(tid < K2){ scs[tid] = sc[(size_t)i*K2 + tid]; js[tid] = ante[(size_t)i*K2 + tid]; }
  __syncthreads();
  if(tid==0){
    float mx = 0.f;
    for(int t=0;t<K2;t++) mx = fmaxf(mx, scs[t]);
    float sum = expf(0.f - mx); wts[0] = sum;
    for(int t=0;t<K2;t++){ float e = expf(scs[t]-mx); wts[t+1]=e; sum += e; }
    float inv = 1.f/sum;
    for(int t=0;t<=K2;t++) wts[t] *= inv;
  }
  __syncthreads();
  const float* ri_ = reps + (size_t)i*DD;
  for(int d=tid; d<DD; d+=256){
    float a = wts[0]*ri_[d];
    for(int t=0;t<K2;t++) a += wts[t+1]*reps[(size_t)js[t]*DD + d];
    att[(size_t)i*DD + d] = a;
  }
}

// ---------------- bf16 conversion for the fused gate GEMM (SWIZZLED) --------
__global__ void conv_acat(const float* __restrict__ cur, const float* __restrict__ att,
                          unsigned short* __restrict__ A, int m){
  int idx = blockIdx.x*256 + threadIdx.x;
  if(idx >= MPAD*KAW) return;
  int row = idx / KAW, col = idx - row*KAW;
  float v = 0.f;
  if(row < m){
    if(col < DD) v = cur[(size_t)row*DD + col];
    else if(col >= KPAD && col < KPAD + DD) v = att[(size_t)row*DD + (col - KPAD)];
  }
  A[row*KAW + swz_col(row, col)] = f2bf(v);
}

// Bt_cat (NPAD x KAW): Bt[n][s*KPAD+k] = Wf[s*DD+k][n], zero-padded
__global__ void conv_wf(const float* __restrict__ Wf, unsigned short* __restrict__ Bt){
  int n  = blockIdx.y*64 + threadIdx.x;
  int k8 = blockIdx.x*8;
  int s  = (k8 >= KPAD) ? 1 : 0;
  int kk = k8 - s*KPAD;
  u16x8 v;
  #pragma unroll
  for(int j=0;j<8;j++){
    int k = kk + j;
    float f = (n < DD && k < DD) ? Wf[(size_t)(s*DD + k)*DD + n] : 0.f;
    v[j] = f2bf(f);
  }
  int k8s = swz_col(n, k8);
  *(u16x8*)(Bt + (size_t)n*KAW + k8s) = v;
}

// gate epilogue: nxt holds accumulated pre-activation; apply bias+sigmoid+update
__global__ void gate_update(const float* __restrict__ bfv, const float* __restrict__ att,
                            const float* __restrict__ cur, float* __restrict__ nxt, int total){
  int idx = blockIdx.x*256 + threadIdx.x;
  if(idx >= total) return;
  int col = idx % DD;
  float pre = nxt[idx] + bfv[col];
  float g = 1.f/(1.f + expf(-pre));
  nxt[idx] = g*att[idx] + (1.f - g)*cur[idx];
}

// ---------------- final scores + per-row loss -------------------------------
__global__ void final_loss(const float* __restrict__ sc, const int* __restrict__ ante,
                           const int* __restrict__ tclust, float* out_fs, float* row_loss, int m){
  int i = blockIdx.x*blockDim.x + threadIdx.x;
  if(i >= m) return;
  int tci = tclust[i];
  unsigned long long labm = 0ull;
  bool anyp = false;
  float mx = 0.f;
  float mg = -FLT_MAX;
  for(int t=0;t<K2;t++){
    float v = sc[(size_t)i*K2 + t];
    mx = fmaxf(mx, v);
    int j = ante[(size_t)i*K2 + t];
    bool mk = (j < i);
    int ac = mk ? tclust[j] : -1;
    bool p = (ac == tci) && (tci > 0);
    if(p){ labm |= (1ull << (t+1)); anyp = true; mg = fmaxf(mg, v); }
  }
  if(!anyp){ labm |= 1ull; mg = 0.f; }
  float s1 = expf(0.f - mx);
  float s2 = (labm & 1ull) ? expf(0.f - mg) : 0.f;
  float* o = out_fs + (size_t)i*(K2+1);
  o[0] = 0.f;
  for(int t=0;t<K2;t++){
    float v = sc[(size_t)i*K2 + t];
    o[t+1] = v;
    s1 += expf(v - mx);
    if(labm & (1ull << (t+1))) s2 += expf(v - mg);
  }
  row_loss[i] = (mx + logf(s1)) - (mg + logf(s2));
}

__global__ void loss_sum(const float* __restrict__ row_loss, float* out, int m){
  int tid = threadIdx.x;
  float s = 0.f;
  for(int i=tid; i<m; i+=256) s += row_loss[i];
  __shared__ float red[256];
  red[tid]=s; __syncthreads();
  for(int st=128; st>0; st>>=1){ if(tid<st) red[tid]+=red[tid+st]; __syncthreads(); }
  if(tid==0) out[0] = red[0];
}

// ---------------------------------------------------------------------------
extern "C" void kernel_launch(void* const* d_in, const int* in_sizes, int n_in,
                              void* d_out, int out_size, void* d_ws, size_t ws_size,
                              hipStream_t stream){
  const int W = in_sizes[11];
  const int G = in_sizes[12];
  const int C = W * MSW;
  const int m = (int)(0.4 * (double)W);

  const float* seq   = (const float*)d_in[0];
  const float* Wal   = (const float*)d_in[1];
  const float* bal   = (const float*)d_in[2];
  const float* Wm    = (const float*)d_in[3];
  const float* bm    = (const float*)d_in[4];
  const float* Wc    = (const float*)d_in[5];
  const float* WaA   = (const float*)d_in[6];
  const float* baA   = (const float*)d_in[7];
  const float* Wf    = (const float*)d_in[8];
  const float* bf    = (const float*)d_in[9];
  const float* wfeat = (const float*)d_in[10];
  const int*   smap  = (const int*)d_in[11];
  const int*   gs    = (const int*)d_in[12];
  const int*   ge    = (const int*)d_in[13];
  const int*   cid   = (const int*)d_in[14];
  float* out = (float*)d_out;

  // workspace layout (phase-aliased; peak ~59 MB, proven safe <65 MB)
  char* ws = (char*)d_ws;
  size_t off = 0;
  auto alloc = [&](size_t bytes)->char*{
    char* p = ws + off;
    off += (bytes + 255) & ~(size_t)255;
    return p;
  };
  const size_t PLANE  = (size_t)MPAD*KPAD*2;   // 4.36 MB
  const size_t WPLANE = (size_t)NPAD*KPAD*2;   // 11.83 MB

  float* alphas  = (float*)alloc((size_t)W*4);
  float* p1      = (float*)alloc((size_t)W*4);
  float* p2      = (float*)alloc((size_t)W*4);
  float* p3      = (float*)alloc((size_t)W*4);
  float* mscore  = (float*)alloc((size_t)C*4);
  float* mmask   = (float*)alloc((size_t)C*4);
  int*   ccl     = (int*)  alloc((size_t)C*4);
  int*   top_idx = (int*)  alloc((size_t)m*4);
  float* tscore  = (float*)alloc((size_t)m*4);
  int*   tclust  = (int*)  alloc((size_t)m*4);
  float* B1      = (float*)alloc((size_t)m*DD*4);  // top_rep / reps ping
  float* B2      = (float*)alloc((size_t)m*DD*4);  // tmp / reps pong
  float* B3      = (float*)alloc((size_t)m*DD*4);  // attended
  float* bilin   = (float*)alloc((size_t)m*m*4);   // bilin, later P (slow matrix)
  int*   ante    = (int*)  alloc((size_t)m*K2*4);
  float* tafast  = (float*)alloc((size_t)m*K2*4);
  float* uB      = (float*)alloc((size_t)m*4);
  float* vB      = (float*)alloc((size_t)m*4);
  float* scB     = (float*)alloc((size_t)m*K2*4);
  float* rloss   = (float*)alloc((size_t)m*4);
  // regionA (2*PLANE), phase-aliased:
  //   bilinear: RepH | RepL      slow: XbfA | CurBf      gate: Acat (spans both)
  char* regionA = alloc(2*PLANE);
  unsigned short* RepH  = (unsigned short*)regionA;
  unsigned short* RepL  = (unsigned short*)(regionA + PLANE);
  unsigned short* XbfA  = (unsigned short*)regionA;
  unsigned short* CurBf = (unsigned short*)(regionA + PLANE);
  unsigned short* Acat  = (unsigned short*)regionA;            // MPAD*KAW*2 == 2*PLANE
  // regionB (2*WPLANE), phase-aliased:
  //   gemm1: WtH | WtL   ->  gemm2: A2H | A2L (after gemm1 done)  ->  depth: BtWf
  char* regionB = alloc(2*WPLANE);
  unsigned short* WtH  = (unsigned short*)regionB;
  unsigned short* WtL  = (unsigned short*)(regionB + WPLANE);
  unsigned short* A2H  = (unsigned short*)regionB;
  unsigned short* A2L  = (unsigned short*)(regionB + PLANE);
  unsigned short* BtWf = (unsigned short*)regionB;             // NPAD*KAW*2 == 2*WPLANE

  // output offsets (all float32)
  float* out_ts   = out;
  float* out_te   = out + m;
  float* out_ante = out + 2*m;
  float* out_fs   = out + 2*m + (size_t)m*K2;
  float* out_loss = out + 2*m + (size_t)m*K2 + (size_t)m*(K2+1);

  // 1) per-token projections
  row_proj<<<W, 256, 0, stream>>>(seq, Wal, bal, Wm, alphas, p1, p2, p3, W);
  // 2) candidate mention scores
  mention_kernel<<<(C+255)/256, 256, 0, stream>>>(alphas, p1, p2, p3, wfeat, Wm, bm,
                                                  smap, gs, ge, cid, G,
                                                  mscore, mmask, ccl, W);
  // 3) exact top-m selection + compaction
  select_kernel<<<1, 1024, 0, stream>>>(mmask, mscore, ccl, m, C, W,
                                        top_idx, tscore, tclust, out_ts, out_te);
  // 4) build top_rep into B1
  build_rep<<<m, 256, 0, stream>>>(seq, alphas, wfeat, top_idx, B1, W);
  // 5) bilinear antecedent scores via split-bf16 3-term MFMA (split-K, atomic)
  {
    const int NEL = MPAD*KPAD;
    conv_split<<<(NEL+255)/256, 256, 0, stream>>>(B1, m, DD, RepH, RepL);
    dim3 gw(KPAD/8, NPAD/64);
    conv_split_wcT<<<gw, 64, 0, stream>>>(Wc, WtH, WtL);
    zero_buf<<<(m*DD+255)/256, 256, 0, stream>>>(B2, m*DD);
    dim3 g1(NPAD/128, MPAD/128, 3);     // (19, 7, 3) = 399 blocks <= 512: no tail wave
    gemm_split3_sk<<<g1, 256, 0, stream>>>(RepH, RepL, WtH, WtL, B2, m, DD, DD);
    conv_split<<<(NEL+255)/256, 256, 0, stream>>>(B2, m, DD, A2H, A2L);
    zero_buf<<<(m*m+255)/256, 256, 0, stream>>>(bilin, m*m);
    dim3 g2(MPAD/128, MPAD/128, 10);    // (7, 7, 10) = 490 blocks <= 512
    gemm_split3_sk<<<g2, 256, 0, stream>>>(A2H, A2L, RepH, RepL, bilin, m, m, m);
  }
  // 6) per-row top-50 (1 wave per row, register-resident)
  topante_kernel<<<m, 64, 0, stream>>>(tscore, bilin, m, ante, tafast, out_ante);
  // gate weights -> bf16 transposed (AFTER bilinear GEMMs: regionB alias)
  {
    dim3 g(KAW/8, NPAD/64);
    conv_wf<<<g, 64, 0, stream>>>(Wf, BtWf);
  }

  // 7) DEPTH=2 refinement (loss-path GEMMs: split-K + atomic accumulate)
  float* cur = B1; float* nxt = B2;
  const int NEL = MPAD*KPAD;
  const int total = m * DD;
  for(int depth=0; depth<2; depth++){
    uv_kernel<<<m, 256, 0, stream>>>(cur, WaA, uB, vB, m);
    // slow scores: P = (cur .* w3) @ cur^T  (split-K x10, atomic into zeroed bilin)
    conv_slow_ops<<<(NEL+255)/256, 256, 0, stream>>>(cur, WaA, CurBf, XbfA, m);
    zero_buf<<<(m*m+255)/256, 256, 0, stream>>>(bilin, m*m);
    dim3 gp(MPAD/128, MPAD/128, 10);    // 490 blocks: ~1.9/CU at 4-cap
    gemm_bf16_m97<<<gp, 256, 0, stream>>>(XbfA, CurBf, bilin, m, m, m, KPAD, KPAD/64);
    slow_gather<<<(m*K2+255)/256, 256, 0, stream>>>(bilin, uB, vB, ante, tafast, baA, scB, m);
    attend_kernel<<<m, 256, 0, stream>>>(cur, scB, ante, B3, m);
    // gate pre-activation accumulates into zeroed nxt; epilogue applied after
    conv_acat<<<(MPAD*KAW+255)/256, 256, 0, stream>>>(cur, B3, Acat, m);
    zero_buf<<<(total+255)/256, 256, 0, stream>>>(nxt, total);
    dim3 gg(NPAD/128, MPAD/128, 6);     // (19, 7, 6) = 798 blocks ~ 3.1/CU at 4-cap
    gemm_bf16_m97<<<gg, 256, 0, stream>>>(Acat, BtWf, nxt, m, DD, DD, KAW, KAW/64);
    gate_update<<<(total+255)/256, 256, 0, stream>>>(bf, B3, cur, nxt, total);
    float* t = cur; cur = nxt; nxt = t;
  }

  // 8) final scores + loss
  final_loss<<<(m+255)/256, 256, 0, stream>>>(scB, ante, tclust, out_fs, rloss, m);
  loss_sum<<<1, 256, 0, stream>>>(rloss, out_loss, m);
}

// Round 9
// 797.686 us; speedup vs baseline: 1.0806x; 1.0806x over previous
//
#include <hip/hip_runtime.h>
#include <cfloat>
#include <climits>
#include <math.h>

#define HD   768
#define MSW  10
#define WFK  20
#define DD   2324    // 3*768+20
#define K2   50
#define NEGF (-1e30f)

// MFMA geometry (K padded to mult of 128 for deep-K tiles)
#define KPAD 2432          // 19*128, >= DD
#define KAW  4864          // 2*KPAD  (K-concat of [cur | att] for the gate GEMM)
#define MPAD 896           // 7 * 128 (>= m=819)
#define NPAD 2432          // 19 * 128 (>= DD)

typedef __attribute__((ext_vector_type(8))) short    s8b;
typedef __attribute__((ext_vector_type(8))) unsigned short u16x8;
typedef __attribute__((ext_vector_type(4))) float    f32x4;

__device__ inline unsigned short f2bf(float f){
  unsigned u = __float_as_uint(f);
  unsigned r = (u + 0x7FFFu + ((u >> 16) & 1u)) >> 16;   // RNE
  return (unsigned short)r;
}
__device__ inline float bf2f(unsigned short h){
  return __uint_as_float(((unsigned)h) << 16);
}

// async global->LDS, 16B per lane; LDS dest must be wave-uniform base (+lane*16 implicit)
__device__ __forceinline__ void gload16(const unsigned short* g, void* l){
  __builtin_amdgcn_global_load_lds(
      (const __attribute__((address_space(1))) void*)g,
      (__attribute__((address_space(3))) void*)l, 16, 0, 0);
}

// ---- bank-conflict swizzle (both-sides involution, rule #21) ----------------
// Staging planes store chunk (16B = 8 shorts) j of row r at position j^(r&7)
// within each 64-short K-tile. global_load_lds copies linearly; ds_read XORs.
// Verified R2: SQ_LDS_BANK_CONFLICT 7.76M -> 0.
__device__ __forceinline__ int swz_col(int row, int col){
  return col ^ ((row & 7) << 3);
}

// ---- T1: XCD-aware bijective block remap (m204 form) ------------------------
// Verified R7: g1 64.4 -> ~58us, frame -30us. Pure index permutation.
__device__ __forceinline__ void xcd_remap(int &bx, int &by, int &bz){
  int nwg  = (int)(gridDim.x*gridDim.y*gridDim.z);
  int orig = (int)(blockIdx.x + gridDim.x*(blockIdx.y + gridDim.y*blockIdx.z));
  int q = nwg >> 3, r = nwg & 7;
  int x8 = orig & 7, o8 = orig >> 3;
  int wg = (x8 < r ? x8*(q+1) : r*(q+1) + (x8-r)*q) + o8;
  bx = wg % (int)gridDim.x;
  int tmp = wg / (int)gridDim.x;
  by = tmp % (int)gridDim.y;
  bz = tmp / (int)gridDim.y;
}

// ---------------- per-token projections: alphas, p1,p2,p3 -------------------
__global__ void row_proj(const float* __restrict__ seq, const float* __restrict__ Wa,
                         const float* __restrict__ ba, const float* __restrict__ Wm,
                         float* alphas, float* p1, float* p2, float* p3, int W){
  int w = blockIdx.x; int tid = threadIdx.x;
  const float* row = seq + (size_t)w * HD;
  float s0=0.f, s1=0.f, s2=0.f, s3=0.f;
  for(int h=tid; h<HD; h+=256){
    float x = row[h];
    s0 += x * Wa[h];
    s1 += x * Wm[h];
    s2 += x * Wm[HD + h];
    s3 += x * Wm[2*HD + h];
  }
  __shared__ float r0[256], r1[256], r2[256], r3[256];
  r0[tid]=s0; r1[tid]=s1; r2[tid]=s2; r3[tid]=s3;
  __syncthreads();
  for(int st=128; st>0; st>>=1){
    if(tid<st){ r0[tid]+=r0[tid+st]; r1[tid]+=r1[tid+st]; r2[tid]+=r2[tid+st]; r3[tid]+=r3[tid+st]; }
    __syncthreads();
  }
  if(tid==0){ alphas[w]=r0[0]+ba[0]; p1[w]=r1[0]; p2[w]=r2[0]; p3[w]=r3[0]; }
}

// ---------------- mention scoring per candidate -----------------------------
__global__ void mention_kernel(const float* __restrict__ alphas, const float* __restrict__ p1,
                               const float* __restrict__ p2, const float* __restrict__ p3,
                               const float* __restrict__ wfeat, const float* __restrict__ Wm,
                               const float* __restrict__ bm,
                               const int* __restrict__ smap, const int* __restrict__ gs,
                               const int* __restrict__ ge, const int* __restrict__ cid, int G,
                               float* mscore, float* mmask, int* ccl, int W){
  int c = blockIdx.x*blockDim.x + threadIdx.x;
  int C = W * MSW;
  if(c >= C) return;
  int s = c / MSW, r = c - s*MSW;
  int e = s + r; int ec = min(e, W-1);
  int L = ec - s;
  bool valid = (e < W) && (smap[s] == smap[ec]);
  float maxa = -FLT_MAX;
  for(int j=0;j<=L;j++) maxa = fmaxf(maxa, alphas[s+j]);
  float sum=0.f, sdot=0.f;
  for(int j=0;j<=L;j++){ float ee = expf(alphas[s+j]-maxa); sum += ee; sdot += ee*p3[s+j]; }
  sdot /= sum;
  float wp=0.f;
  for(int f=0; f<WFK; f++) wp += wfeat[L*WFK+f] * Wm[3*HD+f];
  float ms = p1[s] + p2[ec] + sdot + wp + bm[0];
  mscore[c] = ms;
  mmask[c]  = valid ? ms : NEGF;
  int cc = 0;
  for(int g=0; g<G; g++) if(s==gs[g] && ec==ge[g]) cc += cid[g];
  ccl[c] = cc;
}

// ---------------- single-block exact top-m radix select ---------------------
__device__ inline unsigned fkey(float f){
  unsigned b = __float_as_uint(f);
  return (b & 0x80000000u) ? ~b : (b | 0x80000000u);
}

__global__ __launch_bounds__(1024)
void select_kernel(const float* __restrict__ mmask, const float* __restrict__ mscore,
                   const int* __restrict__ ccl, int m, int C, int W,
                   int* top_idx, float* tscore, int* tclust,
                   float* out_ts, float* out_te){
  const int T = 1024;
  int tid = threadIdx.x;
  int chunk = (C + T - 1)/T;
  int lo = tid*chunk, hi = min(lo+chunk, C);
  int n = hi - lo; if(n < 0) n = 0;
  unsigned kb[32];
  for(int t=0;t<n;t++) kb[t] = fkey(mmask[lo+t]);

  __shared__ unsigned s_hist[256];
  __shared__ unsigned s_scan[1024];
  __shared__ unsigned s_pref;
  __shared__ int s_rem;
  if(tid==0){ s_pref=0u; s_rem=m; }
  __syncthreads();

  for(int b=3;b>=0;b--){
    if(tid<256) s_hist[tid]=0u;
    __syncthreads();
    unsigned pref = s_pref;
    unsigned msk = (b==3)?0u:(0xFFFFFFFFu << ((b+1)*8));
    for(int t=0;t<n;t++){
      unsigned u = kb[t];
      if((u & msk)==pref) atomicAdd(&s_hist[(u>>(b*8))&0xFFu], 1u);
    }
    __syncthreads();
    if(tid==0){
      int rem = s_rem; unsigned acc=0u; int bin;
      for(bin=255;bin>=1;bin--){
        unsigned h = s_hist[bin];
        if(acc + h >= (unsigned)rem) break;
        acc += h;
      }
      if(bin < 0) bin = 0;
      s_pref = pref | ((unsigned)bin << (b*8));
      s_rem = rem - (int)acc;
    }
    __syncthreads();
  }
  unsigned Tk = s_pref;
  int need = s_rem;

  unsigned nG=0, nE=0;
  for(int t=0;t<n;t++){ unsigned u=kb[t]; nG += (u>Tk)?1u:0u; nE += (u==Tk)?1u:0u; }

  s_scan[tid]=nE; __syncthreads();
  for(int off=1; off<T; off<<=1){
    unsigned x = (tid>=off)? s_scan[tid-off]:0u; __syncthreads();
    s_scan[tid]+=x; __syncthreads();
  }
  unsigned eqBase = s_scan[tid]-nE;
  __syncthreads();

  int takeLeft = need - (int)eqBase;
  int take = takeLeft<0?0:(takeLeft>(int)nE?(int)nE:takeLeft);
  unsigned selCnt = nG + (unsigned)take;

  s_scan[tid]=selCnt; __syncthreads();
  for(int off=1; off<T; off<<=1){
    unsigned x = (tid>=off)? s_scan[tid-off]:0u; __syncthreads();
    s_scan[tid]+=x; __syncthreads();
  }
  unsigned posBase = s_scan[tid]-selCnt;

  int pos = (int)posBase; int eq = (int)eqBase;
  for(int t=0;t<n;t++){
    unsigned u = kb[t];
    bool sel = false;
    if(u>Tk) sel=true;
    else if(u==Tk){ if(eq<need) sel=true; eq++; }
    if(sel){
      int c = lo+t;
      top_idx[pos] = c;
      int s = c/MSW, r = c - s*MSW; int e = min(s + r, W-1);
      tscore[pos] = mscore[c];
      tclust[pos] = ccl[c];
      out_ts[pos] = (float)s;
      out_te[pos] = (float)e;
      pos++;
    }
  }
}

// ---------------- build top_rep (m x D) -------------------------------------
__global__ void build_rep(const float* __restrict__ seq, const float* __restrict__ alphas,
                          const float* __restrict__ wfeat, const int* __restrict__ top_idx,
                          float* rep, int W){
  int i = blockIdx.x; int tid = threadIdx.x;
  int c = top_idx[i];
  int s = c/MSW, r = c - s*MSW; int ec = min(s + r, W-1); int L = ec - s;
  float wv[MSW];
  float maxa = -FLT_MAX;
  for(int j=0;j<=L;j++) maxa = fmaxf(maxa, alphas[s+j]);
  float sum = 0.f;
  for(int j=0;j<=L;j++){ wv[j] = expf(alphas[s+j]-maxa); sum += wv[j]; }
  float inv = 1.f/sum;
  float* o = rep + (size_t)i*DD;
  for(int d=tid; d<HD; d+=256){
    o[d]      = seq[(size_t)s*HD + d];
    o[HD+d]   = seq[(size_t)ec*HD + d];
    float sp = 0.f;
    for(int j=0;j<=L;j++) sp += wv[j]*seq[(size_t)(s+j)*HD + d];
    o[2*HD+d] = sp*inv;
  }
  for(int f=tid; f<WFK; f+=256) o[3*HD+f] = wfeat[L*WFK+f];
}

// ---------------- split-bf16 conversions (SWIZZLED output layout) -----------
// R9: fused zeroing of the next GEMM's accumulation target (ztgt[0..zn)) —
// removes standalone zero_buf launches. No read/write overlap with src.
__global__ void conv_split(const float* __restrict__ src, int rows, int cols,
                           unsigned short* __restrict__ hi, unsigned short* __restrict__ lo,
                           float* __restrict__ ztgt, int zn){
  int idx = blockIdx.x*256 + threadIdx.x;
  if(idx >= MPAD*KPAD) return;
  if(idx < zn) ztgt[idx] = 0.f;
  int row = idx / KPAD, col = idx - row*KPAD;
  float v = (row < rows && col < cols) ? src[(size_t)row*cols + col] : 0.f;
  unsigned short h = f2bf(v);
  int w = row*KPAD + swz_col(row, col);
  hi[w] = h;
  lo[w] = f2bf(v - bf2f(h));
}

// Wc (DD x DD) -> transposed hi/lo planes (NPAD x KPAD): Wt[n][k] = Wc[k][n]
__global__ void conv_split_wcT(const float* __restrict__ Wc,
                               unsigned short* __restrict__ WtH, unsigned short* __restrict__ WtL){
  int n  = blockIdx.y*64 + threadIdx.x;
  int k8 = blockIdx.x*8;
  u16x8 vh, vl;
  #pragma unroll
  for(int j=0;j<8;j++){
    int k = k8 + j;
    float f = (n < DD && k < DD) ? Wc[(size_t)k*DD + n] : 0.f;
    unsigned short h = f2bf(f);
    vh[j] = h;
    vl[j] = f2bf(f - bf2f(h));
  }
  int k8s = swz_col(n, k8);          // XOR hits bits 3-5 only; 16B granularity
  *(u16x8*)(WtH + (size_t)n*KPAD + k8s) = vh;
  *(u16x8*)(WtL + (size_t)n*KPAD + k8s) = vl;
}

// cur -> CurBf (bf16) and Xbf = bf16(cur * w3row)  (both MPAD x KPAD)
// R9: fused zeroing of bilin (the gp GEMM's atomic target).
__global__ void conv_slow_ops(const float* __restrict__ cur, const float* __restrict__ Wa3,
                              unsigned short* __restrict__ CurBf, unsigned short* __restrict__ Xbf,
                              float* __restrict__ bilin, int mm, int m){
  int idx = blockIdx.x*256 + threadIdx.x;
  if(idx >= MPAD*KPAD) return;
  if(idx < mm) bilin[idx] = 0.f;
  int row = idx / KPAD, col = idx - row*KPAD;
  float v = 0.f, w = 0.f;
  if(row < m && col < DD){ v = cur[(size_t)row*DD + col]; w = Wa3[2*DD + col]; }
  int ws = row*KPAD + swz_col(row, col);
  CurBf[ws] = f2bf(v);
  Xbf[ws]   = f2bf(v * w);
}

// ---------------- split-bf16 3-term MFMA GEMM, split-K ----------------------
// R5-measured-best structure + R7 T1 remap: single-buffered linear LDS via
// global_load_lds, 2 barriers per BK=64 step. LDS = 4 planes x 16 KiB = 64 KiB
// -> 2 blocks/CU. Swizzled reads (conflicts = 0). Grid <= 512 blocks.
__global__ __launch_bounds__(256,2)
void gemm_split3_sk(const unsigned short* __restrict__ Ah, const unsigned short* __restrict__ Al,
                    const unsigned short* __restrict__ Bth, const unsigned short* __restrict__ Btl,
                    float* __restrict__ C, int M, int N, int ldc){
  __shared__ __align__(16) unsigned short sAh[128*64];
  __shared__ __align__(16) unsigned short sAl[128*64];
  __shared__ __align__(16) unsigned short sBh[128*64];
  __shared__ __align__(16) unsigned short sBl[128*64];
  int bx, by, bz; xcd_remap(bx, by, bz);
  int t = threadIdx.x;
  int row0 = by*128, col0 = bx*128;
  const int tiles = KPAD/64;                              // 38
  int per = (tiles + (int)gridDim.z - 1)/(int)gridDim.z;
  int tb = min(bz*per, tiles), te = min(tb + per, tiles);
  if(tb >= te) return;
  int lane = t&63, w = t>>6;
  int wr = (w>>1)*64, wc = (w&1)*64;
  int quad = lane>>4, l15 = lane&15;
  int seg = lane&7;
  size_t ro = (size_t)(w*8 + (lane>>3));                  // staging row within 32-row group
  const unsigned short* gAh = Ah  + ((size_t)row0 + ro)*KPAD + seg*8;
  const unsigned short* gAl = Al  + ((size_t)row0 + ro)*KPAD + seg*8;
  const unsigned short* gBh = Bth + ((size_t)col0 + ro)*KPAD + seg*8;
  const unsigned short* gBl = Btl + ((size_t)col0 + ro)*KPAD + seg*8;
  const int lds0 = (w*8)*64;                              // wave-uniform LDS base (shorts)
  // swizzled read chunk offsets (shorts): ks=0 -> c0, ks=1 -> c0^32
  const int c0 = ((quad ^ (l15 & 7)) << 3);

  f32x4 acc[4][4];
  #pragma unroll
  for(int mi=0;mi<4;mi++)
    #pragma unroll
    for(int ni=0;ni<4;ni++) acc[mi][ni] = (f32x4){0.f,0.f,0.f,0.f};

  for(int kt=tb; kt<te; ++kt){
    size_t k0 = (size_t)kt*64;
    #pragma unroll
    for(int r=0;r<4;r++){
      size_t go = (size_t)(r*32)*KPAD + k0;
      int lo = lds0 + r*32*64;
      gload16(gAh + go, sAh + lo);
      gload16(gAl + go, sAl + lo);
      gload16(gBh + go, sBh + lo);
      gload16(gBl + go, sBl + lo);
    }
    __syncthreads();   // drains vmcnt(0): tile landed in LDS
    #pragma unroll
    for(int ks=0;ks<2;ks++){
      const int co = c0 ^ (ks<<5);
      s8b fah[4], fal[4], fbh[4], fbl[4];
      #pragma unroll
      for(int mi=0;mi<4;mi++){
        int ra = (wr+mi*16+l15)*64 + co;
        fah[mi] = *(const s8b*)&sAh[ra];
        fal[mi] = *(const s8b*)&sAl[ra];
      }
      #pragma unroll
      for(int ni=0;ni<4;ni++){
        int rb = (wc+ni*16+l15)*64 + co;
        fbh[ni] = *(const s8b*)&sBh[rb];
        fbl[ni] = *(const s8b*)&sBl[rb];
      }
      #pragma unroll
      for(int mi=0;mi<4;mi++)
        #pragma unroll
        for(int ni=0;ni<4;ni++){
          acc[mi][ni] = __builtin_amdgcn_mfma_f32_16x16x32_bf16(fah[mi], fbh[ni], acc[mi][ni], 0,0,0);
          acc[mi][ni] = __builtin_amdgcn_mfma_f32_16x16x32_bf16(fah[mi], fbl[ni], acc[mi][ni], 0,0,0);
          acc[mi][ni] = __builtin_amdgcn_mfma_f32_16x16x32_bf16(fal[mi], fbh[ni], acc[mi][ni], 0,0,0);
        }
    }
    __syncthreads();   // all waves done reading before next stage overwrites
  }

  #pragma unroll
  for(int ni=0;ni<4;ni++){
    int gn = col0 + wc + ni*16 + l15;
    if(gn >= N) continue;
    #pragma unroll
    for(int mi=0;mi<4;mi++){
      #pragma unroll
      for(int rg=0;rg<4;rg++){
        int gr = row0 + wr + mi*16 + quad*4 + rg;
        if(gr >= M) continue;
        atomicAdd(&C[(size_t)gr*ldc + gn], acc[mi][ni][rg]);
      }
    }
  }
}

// ---------------- plain bf16 MFMA GEMM, split-K (2-phase dbuf, BK=64) -------
// R7-proven config (58.7us @ gg): dbuf 64 KiB, 2 blk/CU, STAGE(t+1) issued
// BEFORE compute(t) -> load latency covered by the MFMA phase, drained cheaply
// at the barrier. (R8's single-buf 4-blk/CU variant regressed 58.7->82: full
// latency exposure per tile; TLP insufficient. Do not repeat.)
__global__ __launch_bounds__(256,2)
void gemm_bf16_m97(const unsigned short* __restrict__ A, const unsigned short* __restrict__ Bt,
                   float* __restrict__ C, int M, int N, int ldc, int ldk, int tiles){
  __shared__ __align__(16) unsigned short sA[2][128*64];
  __shared__ __align__(16) unsigned short sB[2][128*64];
  int bx, by, bz; xcd_remap(bx, by, bz);
  int t = threadIdx.x;
  int row0 = by*128, col0 = bx*128;
  int per = (tiles + (int)gridDim.z - 1)/(int)gridDim.z;
  int tb = min(bz*per, tiles), te = min(tb + per, tiles);
  if(tb >= te) return;
  int lane = t&63, w = t>>6;
  int wr = (w>>1)*64, wc = (w&1)*64;
  int quad = lane>>4, l15 = lane&15;
  int seg = lane&7;
  size_t ro = (size_t)(w*8 + (lane>>3));
  const unsigned short* gA = A  + ((size_t)row0 + ro)*ldk + seg*8;
  const unsigned short* gB = Bt + ((size_t)col0 + ro)*ldk + seg*8;
  const int lds0 = (w*8)*64;
  const int c0 = ((quad ^ (l15 & 7)) << 3);

  f32x4 acc[4][4];
  #pragma unroll
  for(int mi=0;mi<4;mi++)
    #pragma unroll
    for(int ni=0;ni<4;ni++) acc[mi][ni] = (f32x4){0.f,0.f,0.f,0.f};

  auto STAGE = [&](int b, int kt){
    size_t k0 = (size_t)kt*64;
    #pragma unroll
    for(int r=0;r<4;r++){
      size_t go = (size_t)(r*32)*ldk + k0;
      int lo = lds0 + r*32*64;
      gload16(gA + go, &sA[b][lo]);
      gload16(gB + go, &sB[b][lo]);
    }
  };

  STAGE(0, tb);
  __syncthreads();
  int buf = 0;
  for(int kt=tb; kt<te; ++kt){
    if(kt+1 < te) STAGE(buf^1, kt+1);
    #pragma unroll
    for(int ks=0;ks<2;ks++){
      const int co = c0 ^ (ks<<5);
      s8b fa[4], fb[4];
      #pragma unroll
      for(int mi=0;mi<4;mi++) fa[mi] = *(const s8b*)&sA[buf][(wr+mi*16+l15)*64 + co];
      #pragma unroll
      for(int ni=0;ni<4;ni++) fb[ni] = *(const s8b*)&sB[buf][(wc+ni*16+l15)*64 + co];
      #pragma unroll
      for(int mi=0;mi<4;mi++)
        #pragma unroll
        for(int ni=0;ni<4;ni++)
          acc[mi][ni] = __builtin_amdgcn_mfma_f32_16x16x32_bf16(fa[mi], fb[ni], acc[mi][ni], 0,0,0);
    }
    __syncthreads();
    buf ^= 1;
  }

  #pragma unroll
  for(int ni=0;ni<4;ni++){
    int gn = col0 + wc + ni*16 + l15;
    if(gn >= N) continue;
    #pragma unroll
    for(int mi=0;mi<4;mi++){
      #pragma unroll
      for(int rg=0;rg<4;rg++){
        int gr = row0 + wr + mi*16 + quad*4 + rg;
        if(gr >= M) continue;
        atomicAdd(&C[(size_t)gr*ldc + gn], acc[mi][ni][rg]);
      }
    }
  }
}

// ---------------- per-row top-50 antecedents (1 wave / row) -----------------
// Register-resident selection (R5-verified: bit-identical, ~10x faster than LDS).
#define NT 13   // ceil(m/64) for m<=832
__global__ void topante_kernel(const float* __restrict__ tscore, const float* __restrict__ bilin,
                               int m, int* ante, float* tafast, float* out_ante){
  int i = blockIdx.x; int lane = threadIdx.x;
  float tsi = tscore[i];
  float v[NT];
  #pragma unroll
  for(int t=0;t<NT;t++){
    int j = lane + t*64;
    float f = -FLT_MAX;
    if(j < m){
      f = tsi + tscore[j];
      f += (j < i) ? 0.f : NEGF;
      f += bilin[(size_t)i*m + j];
    }
    v[t] = f;
  }
  unsigned consumed = 0u;
  int r_ante = 0; float r_fast = 0.f;
  for(int it=0; it<K2; ++it){
    float lv = -FLT_MAX; int li = m;
    #pragma unroll
    for(int t=0;t<NT;t++){
      bool live = ((consumed >> t) & 1u) == 0u;
      if(live && v[t] > lv){ lv = v[t]; li = lane + t*64; }
    }
    float bv = lv; int bi = li;
    #pragma unroll
    for(int off=32; off>0; off>>=1){
      float ov = __shfl_xor(bv, off);
      int   oi = __shfl_xor(bi, off);
      if(ov > bv || (ov == bv && oi < bi)){ bv = ov; bi = oi; }
    }
    if(bi < m && (bi & 63) == lane) consumed |= (1u << (bi >> 6));
    if(lane == it){ r_ante = bi; r_fast = bv; }
  }
  if(lane < K2){
    ante[(size_t)i*K2 + lane]   = r_ante;
    tafast[(size_t)i*K2 + lane] = r_fast;
    out_ante[(size_t)i*K2+lane] = (float)r_ante;
  }
}

// ---------------- depth loop pieces -----------------------------------------
__global__ void uv_kernel(const float* __restrict__ reps, const float* __restrict__ Wa3,
                          float* u, float* v, int m){
  int i = blockIdx.x; int tid = threadIdx.x;
  const float* rp = reps + (size_t)i*DD;
  float s1=0.f, s2=0.f;
  for(int d=tid; d<DD; d+=256){ float x = rp[d]; s1 += x*Wa3[d]; s2 += x*Wa3[DD+d]; }
  __shared__ float r1[256], r2[256];
  r1[tid]=s1; r2[tid]=s2; __syncthreads();
  for(int st=128; st>0; st>>=1){
    if(tid<st){ r1[tid]+=r1[tid+st]; r2[tid]+=r2[tid+st]; }
    __syncthreads();
  }
  if(tid==0){ u[i]=r1[0]; v[i]=r2[0]; }
}

// sc[p] = tafast[p] + u[i] + v[j] + P[i][j] + ba
__global__ void slow_gather(const float* __restrict__ P, const float* __restrict__ u,
                            const float* __restrict__ v, const int* __restrict__ ante,
                            const float* __restrict__ tafast, const float* __restrict__ ba,
                            float* sc, int m){
  int p = blockIdx.x*256 + threadIdx.x;
  if(p >= m*K2) return;
  int i = p / K2; int j = ante[p];
  sc[p] = tafast[p] + u[i] + v[j] + P[(size_t)i*m + j] + ba[0];
}

__global__ void attend_kernel(const float* __restrict__ reps, const float* __restrict__ sc,
                              const int* __restrict__ ante, float* att, int m){
  int i = blockIdx.x; int tid = threadIdx.x;
  __shared__ float wts[K2+1];
  __shared__ float scs[K2];
  __shared__ int   js[K2];
  if(tid < K2){ scs[tid] = sc[(size_t)i*K2 + tid]; js[tid] = ante[(size_t)i*K2 + tid]; }
  __syncthreads();
  if(tid==0){
    float mx = 0.f;
    for(int t=0;t<K2;t++) mx = fmaxf(mx, scs[t]);
    float sum = expf(0.f - mx); wts[0] = sum;
    for(int t=0;t<K2;t++){ float e = expf(scs[t]-mx); wts[t+1]=e; sum += e; }
    float inv = 1.f/sum;
    for(int t=0;t<=K2;t++) wts[t] *= inv;
  }
  __syncthreads();
  const float* ri_ = reps + (size_t)i*DD;
  for(int d=tid; d<DD; d+=256){
    float a = wts[0]*ri_[d];
    for(int t=0;t<K2;t++) a += wts[t+1]*reps[(size_t)js[t]*DD + d];
    att[(size_t)i*DD + d] = a;
  }
}

// ---------------- bf16 conversion for the fused gate GEMM (SWIZZLED) --------
// R9: fused zeroing of nxt (the gg GEMM's atomic target, total = m*DD elems).
__global__ void conv_acat(const float* __restrict__ cur, const float* __restrict__ att,
                          unsigned short* __restrict__ A,
                          float* __restrict__ nxt, int total, int m){
  int idx = blockIdx.x*256 + threadIdx.x;
  if(idx >= MPAD*KAW) return;
  if(idx < total) nxt[idx] = 0.f;
  int row = idx / KAW, col = idx - row*KAW;
  float v = 0.f;
  if(row < m){
    if(col < DD) v = cur[(size_t)row*DD + col];
    else if(col >= KPAD && col < KPAD + DD) v = att[(size_t)row*DD + (col - KPAD)];
  }
  A[row*KAW + swz_col(row, col)] = f2bf(v);
}

// Bt_cat (NPAD x KAW): Bt[n][s*KPAD+k] = Wf[s*DD+k][n], zero-padded
__global__ void conv_wf(const float* __restrict__ Wf, unsigned short* __restrict__ Bt){
  int n  = blockIdx.y*64 + threadIdx.x;
  int k8 = blockIdx.x*8;
  int s  = (k8 >= KPAD) ? 1 : 0;
  int kk = k8 - s*KPAD;
  u16x8 v;
  #pragma unroll
  for(int j=0;j<8;j++){
    int k = kk + j;
    float f = (n < DD && k < DD) ? Wf[(size_t)(s*DD + k)*DD + n] : 0.f;
    v[j] = f2bf(f);
  }
  int k8s = swz_col(n, k8);
  *(u16x8*)(Bt + (size_t)n*KAW + k8s) = v;
}

// gate epilogue: nxt holds accumulated pre-activation; apply bias+sigmoid+update
__global__ void gate_update(const float* __restrict__ bfv, const float* __restrict__ att,
                            const float* __restrict__ cur, float* __restrict__ nxt, int total){
  int idx = blockIdx.x*256 + threadIdx.x;
  if(idx >= total) return;
  int col = idx % DD;
  float pre = nxt[idx] + bfv[col];
  float g = 1.f/(1.f + expf(-pre));
  nxt[idx] = g*att[idx] + (1.f - g)*cur[idx];
}

// ---------------- final scores + per-row loss -------------------------------
__global__ void final_loss(const float* __restrict__ sc, const int* __restrict__ ante,
                           const int* __restrict__ tclust, float* out_fs, float* row_loss, int m){
  int i = blockIdx.x*blockDim.x + threadIdx.x;
  if(i >= m) return;
  int tci = tclust[i];
  unsigned long long labm = 0ull;
  bool anyp = false;
  float mx = 0.f;
  float mg = -FLT_MAX;
  for(int t=0;t<K2;t++){
    float v = sc[(size_t)i*K2 + t];
    mx = fmaxf(mx, v);
    int j = ante[(size_t)i*K2 + t];
    bool mk = (j < i);
    int ac = mk ? tclust[j] : -1;
    bool p = (ac == tci) && (tci > 0);
    if(p){ labm |= (1ull << (t+1)); anyp = true; mg = fmaxf(mg, v); }
  }
  if(!anyp){ labm |= 1ull; mg = 0.f; }
  float s1 = expf(0.f - mx);
  float s2 = (labm & 1ull) ? expf(0.f - mg) : 0.f;
  float* o = out_fs + (size_t)i*(K2+1);
  o[0] = 0.f;
  for(int t=0;t<K2;t++){
    float v = sc[(size_t)i*K2 + t];
    o[t+1] = v;
    s1 += expf(v - mx);
    if(labm & (1ull << (t+1))) s2 += expf(v - mg);
  }
  row_loss[i] = (mx + logf(s1)) - (mg + logf(s2));
}

__global__ void loss_sum(const float* __restrict__ row_loss, float* out, int m){
  int tid = threadIdx.x;
  float s = 0.f;
  for(int i=tid; i<m; i+=256) s += row_loss[i];
  __shared__ float red[256];
  red[tid]=s; __syncthreads();
  for(int st=128; st>0; st>>=1){ if(tid<st) red[tid]+=red[tid+st]; __syncthreads(); }
  if(tid==0) out[0] = red[0];
}

// ---------------------------------------------------------------------------
extern "C" void kernel_launch(void* const* d_in, const int* in_sizes, int n_in,
                              void* d_out, int out_size, void* d_ws, size_t ws_size,
                              hipStream_t stream){
  const int W = in_sizes[11];
  const int G = in_sizes[12];
  const int C = W * MSW;
  const int m = (int)(0.4 * (double)W);

  const float* seq   = (const float*)d_in[0];
  const float* Wal   = (const float*)d_in[1];
  const float* bal   = (const float*)d_in[2];
  const float* Wm    = (const float*)d_in[3];
  const float* bm    = (const float*)d_in[4];
  const float* Wc    = (const float*)d_in[5];
  const float* WaA   = (const float*)d_in[6];
  const float* baA   = (const float*)d_in[7];
  const float* Wf    = (const float*)d_in[8];
  const float* bf    = (const float*)d_in[9];
  const float* wfeat = (const float*)d_in[10];
  const int*   smap  = (const int*)d_in[11];
  const int*   gs    = (const int*)d_in[12];
  const int*   ge    = (const int*)d_in[13];
  const int*   cid   = (const int*)d_in[14];
  float* out = (float*)d_out;

  // workspace layout (phase-aliased; peak ~59 MB, proven safe <65 MB)
  char* ws = (char*)d_ws;
  size_t off = 0;
  auto alloc = [&](size_t bytes)->char*{
    char* p = ws + off;
    off += (bytes + 255) & ~(size_t)255;
    return p;
  };
  const size_t PLANE  = (size_t)MPAD*KPAD*2;   // 4.36 MB
  const size_t WPLANE = (size_t)NPAD*KPAD*2;   // 11.83 MB

  float* alphas  = (float*)alloc((size_t)W*4);
  float* p1      = (float*)alloc((size_t)W*4);
  float* p2      = (float*)alloc((size_t)W*4);
  float* p3      = (float*)alloc((size_t)W*4);
  float* mscore  = (float*)alloc((size_t)C*4);
  float* mmask   = (float*)alloc((size_t)C*4);
  int*   ccl     = (int*)  alloc((size_t)C*4);
  int*   top_idx = (int*)  alloc((size_t)m*4);
  float* tscore  = (float*)alloc((size_t)m*4);
  int*   tclust  = (int*)  alloc((size_t)m*4);
  float* B1      = (float*)alloc((size_t)m*DD*4);  // top_rep / reps ping
  float* B2      = (float*)alloc((size_t)m*DD*4);  // tmp / reps pong
  float* B3      = (float*)alloc((size_t)m*DD*4);  // attended
  float* bilin   = (float*)alloc((size_t)m*m*4);   // bilin, later P (slow matrix)
  int*   ante    = (int*)  alloc((size_t)m*K2*4);
  float* tafast  = (float*)alloc((size_t)m*K2*4);
  float* uB      = (float*)alloc((size_t)m*4);
  float* vB      = (float*)alloc((size_t)m*4);
  float* scB     = (float*)alloc((size_t)m*K2*4);
  float* rloss   = (float*)alloc((size_t)m*4);
  // regionA (2*PLANE), phase-aliased:
  //   bilinear: RepH | RepL      slow: XbfA | CurBf      gate: Acat (spans both)
  char* regionA = alloc(2*PLANE);
  unsigned short* RepH  = (unsigned short*)regionA;
  unsigned short* RepL  = (unsigned short*)(regionA + PLANE);
  unsigned short* XbfA  = (unsigned short*)regionA;
  unsigned short* CurBf = (unsigned short*)(regionA + PLANE);
  unsigned short* Acat  = (unsigned short*)regionA;            // MPAD*KAW*2 == 2*PLANE
  // regionB (2*WPLANE), phase-aliased:
  //   gemm1: WtH | WtL   ->  gemm2: A2H | A2L (after gemm1 done)  ->  depth: BtWf
  char* regionB = alloc(2*WPLANE);
  unsigned short* WtH  = (unsigned short*)regionB;
  unsigned short* WtL  = (unsigned short*)(regionB + WPLANE);
  unsigned short* A2H  = (unsigned short*)regionB;
  unsigned short* A2L  = (unsigned short*)(regionB + PLANE);
  unsigned short* BtWf = (unsigned short*)regionB;             // NPAD*KAW*2 == 2*WPLANE

  // output offsets (all float32)
  float* out_ts   = out;
  float* out_te   = out + m;
  float* out_ante = out + 2*m;
  float* out_fs   = out + 2*m + (size_t)m*K2;
  float* out_loss = out + 2*m + (size_t)m*K2 + (size_t)m*(K2+1);

  // 1) per-token projections
  row_proj<<<W, 256, 0, stream>>>(seq, Wal, bal, Wm, alphas, p1, p2, p3, W);
  // 2) candidate mention scores
  mention_kernel<<<(C+255)/256, 256, 0, stream>>>(alphas, p1, p2, p3, wfeat, Wm, bm,
                                                  smap, gs, ge, cid, G,
                                                  mscore, mmask, ccl, W);
  // 3) exact top-m selection + compaction
  select_kernel<<<1, 1024, 0, stream>>>(mmask, mscore, ccl, m, C, W,
                                        top_idx, tscore, tclust, out_ts, out_te);
  // 4) build top_rep into B1
  build_rep<<<m, 256, 0, stream>>>(seq, alphas, wfeat, top_idx, B1, W);
  // 5) bilinear antecedent scores via split-bf16 3-term MFMA (split-K, atomic)
  {
    const int NEL = MPAD*KPAD;
    // conv_split also zeroes B2 (g1's atomic target)
    conv_split<<<(NEL+255)/256, 256, 0, stream>>>(B1, m, DD, RepH, RepL, B2, m*DD);
    dim3 gw(KPAD/8, NPAD/64);
    conv_split_wcT<<<gw, 64, 0, stream>>>(Wc, WtH, WtL);
    dim3 g1(NPAD/128, MPAD/128, 3);     // (19, 7, 3) = 399 blocks <= 512: no tail wave
    gemm_split3_sk<<<g1, 256, 0, stream>>>(RepH, RepL, WtH, WtL, B2, m, DD, DD);
    // conv_split also zeroes bilin (g2's atomic target)
    conv_split<<<(NEL+255)/256, 256, 0, stream>>>(B2, m, DD, A2H, A2L, bilin, m*m);
    dim3 g2(MPAD/128, MPAD/128, 10);    // (7, 7, 10) = 490 blocks <= 512
    gemm_split3_sk<<<g2, 256, 0, stream>>>(A2H, A2L, RepH, RepL, bilin, m, m, m);
  }
  // 6) per-row top-50 (1 wave per row, register-resident)
  topante_kernel<<<m, 64, 0, stream>>>(tscore, bilin, m, ante, tafast, out_ante);
  // gate weights -> bf16 transposed (AFTER bilinear GEMMs: regionB alias)
  {
    dim3 g(KAW/8, NPAD/64);
    conv_wf<<<g, 64, 0, stream>>>(Wf, BtWf);
  }

  // 7) DEPTH=2 refinement (loss-path GEMMs: split-K + atomic accumulate)
  float* cur = B1; float* nxt = B2;
  const int NEL = MPAD*KPAD;
  const int total = m * DD;
  for(int depth=0; depth<2; depth++){
    uv_kernel<<<m, 256, 0, stream>>>(cur, WaA, uB, vB, m);
    // slow scores: P = (cur .* w3) @ cur^T; conv also zeroes bilin
    conv_slow_ops<<<(NEL+255)/256, 256, 0, stream>>>(cur, WaA, CurBf, XbfA, bilin, m*m, m);
    dim3 gp(MPAD/128, MPAD/128, 10);    // 490 blocks <= 512
    gemm_bf16_m97<<<gp, 256, 0, stream>>>(XbfA, CurBf, bilin, m, m, m, KPAD, KPAD/64);
    slow_gather<<<(m*K2+255)/256, 256, 0, stream>>>(bilin, uB, vB, ante, tafast, baA, scB, m);
    attend_kernel<<<m, 256, 0, stream>>>(cur, scB, ante, B3, m);
    // gate pre-activation accumulates into zeroed nxt; conv_acat zeroes nxt
    conv_acat<<<(MPAD*KAW+255)/256, 256, 0, stream>>>(cur, B3, Acat, nxt, total, m);
    dim3 gg(NPAD/128, MPAD/128, 3);     // (19, 7, 3) = 399 blocks <= 512: no tail wave
    gemm_bf16_m97<<<gg, 256, 0, stream>>>(Acat, BtWf, nxt, m, DD, DD, KAW, KAW/64);
    gate_update<<<(total+255)/256, 256, 0, stream>>>(bf, B3, cur, nxt, total);
    float* t = cur; cur = nxt; nxt = t;
  }

  // 8) final scores + loss
  final_loss<<<(m+255)/256, 256, 0, stream>>>(scB, ante, tclust, out_fs, rloss, m);
  loss_sum<<<1, 256, 0, stream>>>(rloss, out_loss, m);
}

// Round 10
// 793.897 us; speedup vs baseline: 1.0857x; 1.0048x over previous
//
#include <hip/hip_runtime.h>
#include <cfloat>
#include <climits>
#include <math.h>

#define HD   768
#define MSW  10
#define WFK  20
#define DD   2324    // 3*768+20
#define K2   50
#define NEGF (-1e30f)

// MFMA geometry (K padded to mult of 128 for deep-K tiles)
#define KPAD 2432          // 19*128, >= DD
#define KAW  4864          // 2*KPAD  (K-concat of [cur | att] for the gate GEMM)
#define MPAD 896           // 7 * 128 (>= m=819)
#define NPAD 2432          // 19 * 128 (>= DD)

typedef __attribute__((ext_vector_type(8))) short    s8b;
typedef __attribute__((ext_vector_type(8))) unsigned short u16x8;
typedef __attribute__((ext_vector_type(4))) float    f32x4;

__device__ inline unsigned short f2bf(float f){
  unsigned u = __float_as_uint(f);
  unsigned r = (u + 0x7FFFu + ((u >> 16) & 1u)) >> 16;   // RNE
  return (unsigned short)r;
}
__device__ inline float bf2f(unsigned short h){
  return __uint_as_float(((unsigned)h) << 16);
}

// async global->LDS, 16B per lane; LDS dest must be wave-uniform base (+lane*16 implicit)
__device__ __forceinline__ void gload16(const unsigned short* g, void* l){
  __builtin_amdgcn_global_load_lds(
      (const __attribute__((address_space(1))) void*)g,
      (__attribute__((address_space(3))) void*)l, 16, 0, 0);
}

// ---- bank-conflict swizzle (both-sides involution, rule #21) ----------------
// Staging planes store chunk (16B = 8 shorts) j of row r at position j^(r&7)
// within each 64-short K-tile. global_load_lds copies linearly; ds_read XORs.
// Verified R2: SQ_LDS_BANK_CONFLICT 7.76M -> 0.
__device__ __forceinline__ int swz_col(int row, int col){
  return col ^ ((row & 7) << 3);
}

// ---- T1: XCD-aware bijective block remap (m204 form) ------------------------
// Verified R7: g1 64.4 -> ~58us, frame -30us. Pure index permutation.
__device__ __forceinline__ void xcd_remap(int &bx, int &by, int &bz){
  int nwg  = (int)(gridDim.x*gridDim.y*gridDim.z);
  int orig = (int)(blockIdx.x + gridDim.x*(blockIdx.y + gridDim.y*blockIdx.z));
  int q = nwg >> 3, r = nwg & 7;
  int x8 = orig & 7, o8 = orig >> 3;
  int wg = (x8 < r ? x8*(q+1) : r*(q+1) + (x8-r)*q) + o8;
  bx = wg % (int)gridDim.x;
  int tmp = wg / (int)gridDim.x;
  by = tmp % (int)gridDim.y;
  bz = tmp / (int)gridDim.y;
}

// ---------------- per-token projections: alphas, p1,p2,p3 -------------------
__global__ void row_proj(const float* __restrict__ seq, const float* __restrict__ Wa,
                         const float* __restrict__ ba, const float* __restrict__ Wm,
                         float* alphas, float* p1, float* p2, float* p3, int W){
  int w = blockIdx.x; int tid = threadIdx.x;
  const float* row = seq + (size_t)w * HD;
  float s0=0.f, s1=0.f, s2=0.f, s3=0.f;
  for(int h=tid; h<HD; h+=256){
    float x = row[h];
    s0 += x * Wa[h];
    s1 += x * Wm[h];
    s2 += x * Wm[HD + h];
    s3 += x * Wm[2*HD + h];
  }
  __shared__ float r0[256], r1[256], r2[256], r3[256];
  r0[tid]=s0; r1[tid]=s1; r2[tid]=s2; r3[tid]=s3;
  __syncthreads();
  for(int st=128; st>0; st>>=1){
    if(tid<st){ r0[tid]+=r0[tid+st]; r1[tid]+=r1[tid+st]; r2[tid]+=r2[tid+st]; r3[tid]+=r3[tid+st]; }
    __syncthreads();
  }
  if(tid==0){ alphas[w]=r0[0]+ba[0]; p1[w]=r1[0]; p2[w]=r2[0]; p3[w]=r3[0]; }
}

// ---------------- mention scoring per candidate -----------------------------
__global__ void mention_kernel(const float* __restrict__ alphas, const float* __restrict__ p1,
                               const float* __restrict__ p2, const float* __restrict__ p3,
                               const float* __restrict__ wfeat, const float* __restrict__ Wm,
                               const float* __restrict__ bm,
                               const int* __restrict__ smap, const int* __restrict__ gs,
                               const int* __restrict__ ge, const int* __restrict__ cid, int G,
                               float* mscore, float* mmask, int* ccl, int W){
  int c = blockIdx.x*blockDim.x + threadIdx.x;
  int C = W * MSW;
  if(c >= C) return;
  int s = c / MSW, r = c - s*MSW;
  int e = s + r; int ec = min(e, W-1);
  int L = ec - s;
  bool valid = (e < W) && (smap[s] == smap[ec]);
  float maxa = -FLT_MAX;
  for(int j=0;j<=L;j++) maxa = fmaxf(maxa, alphas[s+j]);
  float sum=0.f, sdot=0.f;
  for(int j=0;j<=L;j++){ float ee = expf(alphas[s+j]-maxa); sum += ee; sdot += ee*p3[s+j]; }
  sdot /= sum;
  float wp=0.f;
  for(int f=0; f<WFK; f++) wp += wfeat[L*WFK+f] * Wm[3*HD+f];
  float ms = p1[s] + p2[ec] + sdot + wp + bm[0];
  mscore[c] = ms;
  mmask[c]  = valid ? ms : NEGF;
  int cc = 0;
  for(int g=0; g<G; g++) if(s==gs[g] && ec==ge[g]) cc += cid[g];
  ccl[c] = cc;
}

// ---------------- single-block exact top-m radix select ---------------------
__device__ inline unsigned fkey(float f){
  unsigned b = __float_as_uint(f);
  return (b & 0x80000000u) ? ~b : (b | 0x80000000u);
}

__global__ __launch_bounds__(1024)
void select_kernel(const float* __restrict__ mmask, const float* __restrict__ mscore,
                   const int* __restrict__ ccl, int m, int C, int W,
                   int* top_idx, float* tscore, int* tclust,
                   float* out_ts, float* out_te){
  const int T = 1024;
  int tid = threadIdx.x;
  int chunk = (C + T - 1)/T;
  int lo = tid*chunk, hi = min(lo+chunk, C);
  int n = hi - lo; if(n < 0) n = 0;
  unsigned kb[32];
  for(int t=0;t<n;t++) kb[t] = fkey(mmask[lo+t]);

  __shared__ unsigned s_hist[256];
  __shared__ unsigned s_scan[1024];
  __shared__ unsigned s_pref;
  __shared__ int s_rem;
  if(tid==0){ s_pref=0u; s_rem=m; }
  __syncthreads();

  for(int b=3;b>=0;b--){
    if(tid<256) s_hist[tid]=0u;
    __syncthreads();
    unsigned pref = s_pref;
    unsigned msk = (b==3)?0u:(0xFFFFFFFFu << ((b+1)*8));
    for(int t=0;t<n;t++){
      unsigned u = kb[t];
      if((u & msk)==pref) atomicAdd(&s_hist[(u>>(b*8))&0xFFu], 1u);
    }
    __syncthreads();
    if(tid==0){
      int rem = s_rem; unsigned acc=0u; int bin;
      for(bin=255;bin>=1;bin--){
        unsigned h = s_hist[bin];
        if(acc + h >= (unsigned)rem) break;
        acc += h;
      }
      if(bin < 0) bin = 0;
      s_pref = pref | ((unsigned)bin << (b*8));
      s_rem = rem - (int)acc;
    }
    __syncthreads();
  }
  unsigned Tk = s_pref;
  int need = s_rem;

  unsigned nG=0, nE=0;
  for(int t=0;t<n;t++){ unsigned u=kb[t]; nG += (u>Tk)?1u:0u; nE += (u==Tk)?1u:0u; }

  s_scan[tid]=nE; __syncthreads();
  for(int off=1; off<T; off<<=1){
    unsigned x = (tid>=off)? s_scan[tid-off]:0u; __syncthreads();
    s_scan[tid]+=x; __syncthreads();
  }
  unsigned eqBase = s_scan[tid]-nE;
  __syncthreads();

  int takeLeft = need - (int)eqBase;
  int take = takeLeft<0?0:(takeLeft>(int)nE?(int)nE:takeLeft);
  unsigned selCnt = nG + (unsigned)take;

  s_scan[tid]=selCnt; __syncthreads();
  for(int off=1; off<T; off<<=1){
    unsigned x = (tid>=off)? s_scan[tid-off]:0u; __syncthreads();
    s_scan[tid]+=x; __syncthreads();
  }
  unsigned posBase = s_scan[tid]-selCnt;

  int pos = (int)posBase; int eq = (int)eqBase;
  for(int t=0;t<n;t++){
    unsigned u = kb[t];
    bool sel = false;
    if(u>Tk) sel=true;
    else if(u==Tk){ if(eq<need) sel=true; eq++; }
    if(sel){
      int c = lo+t;
      top_idx[pos] = c;
      int s = c/MSW, r = c - s*MSW; int e = min(s + r, W-1);
      tscore[pos] = mscore[c];
      tclust[pos] = ccl[c];
      out_ts[pos] = (float)s;
      out_te[pos] = (float)e;
      pos++;
    }
  }
}

// ---------------- build top_rep (m x D) -------------------------------------
__global__ void build_rep(const float* __restrict__ seq, const float* __restrict__ alphas,
                          const float* __restrict__ wfeat, const int* __restrict__ top_idx,
                          float* rep, int W){
  int i = blockIdx.x; int tid = threadIdx.x;
  int c = top_idx[i];
  int s = c/MSW, r = c - s*MSW; int ec = min(s + r, W-1); int L = ec - s;
  float wv[MSW];
  float maxa = -FLT_MAX;
  for(int j=0;j<=L;j++) maxa = fmaxf(maxa, alphas[s+j]);
  float sum = 0.f;
  for(int j=0;j<=L;j++){ wv[j] = expf(alphas[s+j]-maxa); sum += wv[j]; }
  float inv = 1.f/sum;
  float* o = rep + (size_t)i*DD;
  for(int d=tid; d<HD; d+=256){
    o[d]      = seq[(size_t)s*HD + d];
    o[HD+d]   = seq[(size_t)ec*HD + d];
    float sp = 0.f;
    for(int j=0;j<=L;j++) sp += wv[j]*seq[(size_t)(s+j)*HD + d];
    o[2*HD+d] = sp*inv;
  }
  for(int f=tid; f<WFK; f+=256) o[3*HD+f] = wfeat[L*WFK+f];
}

// ---------------- split-bf16 conversions (SWIZZLED output layout) -----------
// Fused zeroing of the next GEMM's accumulation target (ztgt[0..zn)) —
// removes standalone zero_buf launches. No read/write overlap with src.
__global__ void conv_split(const float* __restrict__ src, int rows, int cols,
                           unsigned short* __restrict__ hi, unsigned short* __restrict__ lo,
                           float* __restrict__ ztgt, int zn){
  int idx = blockIdx.x*256 + threadIdx.x;
  if(idx >= MPAD*KPAD) return;
  if(idx < zn) ztgt[idx] = 0.f;
  int row = idx / KPAD, col = idx - row*KPAD;
  float v = (row < rows && col < cols) ? src[(size_t)row*cols + col] : 0.f;
  unsigned short h = f2bf(v);
  int w = row*KPAD + swz_col(row, col);
  hi[w] = h;
  lo[w] = f2bf(v - bf2f(h));
}

// Wc (DD x DD) -> transposed hi/lo planes (NPAD x KPAD): Wt[n][k] = Wc[k][n]
__global__ void conv_split_wcT(const float* __restrict__ Wc,
                               unsigned short* __restrict__ WtH, unsigned short* __restrict__ WtL){
  int n  = blockIdx.y*64 + threadIdx.x;
  int k8 = blockIdx.x*8;
  u16x8 vh, vl;
  #pragma unroll
  for(int j=0;j<8;j++){
    int k = k8 + j;
    float f = (n < DD && k < DD) ? Wc[(size_t)k*DD + n] : 0.f;
    unsigned short h = f2bf(f);
    vh[j] = h;
    vl[j] = f2bf(f - bf2f(h));
  }
  int k8s = swz_col(n, k8);          // XOR hits bits 3-5 only; 16B granularity
  *(u16x8*)(WtH + (size_t)n*KPAD + k8s) = vh;
  *(u16x8*)(WtL + (size_t)n*KPAD + k8s) = vl;
}

// ---------------- split-bf16 3-term MFMA GEMM, split-K ----------------------
// R5-measured-best structure + R7 T1 remap: single-buffered linear LDS via
// global_load_lds, 2 barriers per BK=64 step. LDS = 4 planes x 16 KiB = 64 KiB
// -> 2 blocks/CU. Swizzled reads (conflicts = 0). Grid <= 512 blocks.
__global__ __launch_bounds__(256,2)
void gemm_split3_sk(const unsigned short* __restrict__ Ah, const unsigned short* __restrict__ Al,
                    const unsigned short* __restrict__ Bth, const unsigned short* __restrict__ Btl,
                    float* __restrict__ C, int M, int N, int ldc){
  __shared__ __align__(16) unsigned short sAh[128*64];
  __shared__ __align__(16) unsigned short sAl[128*64];
  __shared__ __align__(16) unsigned short sBh[128*64];
  __shared__ __align__(16) unsigned short sBl[128*64];
  int bx, by, bz; xcd_remap(bx, by, bz);
  int t = threadIdx.x;
  int row0 = by*128, col0 = bx*128;
  const int tiles = KPAD/64;                              // 38
  int per = (tiles + (int)gridDim.z - 1)/(int)gridDim.z;
  int tb = min(bz*per, tiles), te = min(tb + per, tiles);
  if(tb >= te) return;
  int lane = t&63, w = t>>6;
  int wr = (w>>1)*64, wc = (w&1)*64;
  int quad = lane>>4, l15 = lane&15;
  int seg = lane&7;
  size_t ro = (size_t)(w*8 + (lane>>3));                  // staging row within 32-row group
  const unsigned short* gAh = Ah  + ((size_t)row0 + ro)*KPAD + seg*8;
  const unsigned short* gAl = Al  + ((size_t)row0 + ro)*KPAD + seg*8;
  const unsigned short* gBh = Bth + ((size_t)col0 + ro)*KPAD + seg*8;
  const unsigned short* gBl = Btl + ((size_t)col0 + ro)*KPAD + seg*8;
  const int lds0 = (w*8)*64;                              // wave-uniform LDS base (shorts)
  // swizzled read chunk offsets (shorts): ks=0 -> c0, ks=1 -> c0^32
  const int c0 = ((quad ^ (l15 & 7)) << 3);

  f32x4 acc[4][4];
  #pragma unroll
  for(int mi=0;mi<4;mi++)
    #pragma unroll
    for(int ni=0;ni<4;ni++) acc[mi][ni] = (f32x4){0.f,0.f,0.f,0.f};

  for(int kt=tb; kt<te; ++kt){
    size_t k0 = (size_t)kt*64;
    #pragma unroll
    for(int r=0;r<4;r++){
      size_t go = (size_t)(r*32)*KPAD + k0;
      int lo = lds0 + r*32*64;
      gload16(gAh + go, sAh + lo);
      gload16(gAl + go, sAl + lo);
      gload16(gBh + go, sBh + lo);
      gload16(gBl + go, sBl + lo);
    }
    __syncthreads();   // drains vmcnt(0): tile landed in LDS
    #pragma unroll
    for(int ks=0;ks<2;ks++){
      const int co = c0 ^ (ks<<5);
      s8b fah[4], fal[4], fbh[4], fbl[4];
      #pragma unroll
      for(int mi=0;mi<4;mi++){
        int ra = (wr+mi*16+l15)*64 + co;
        fah[mi] = *(const s8b*)&sAh[ra];
        fal[mi] = *(const s8b*)&sAl[ra];
      }
      #pragma unroll
      for(int ni=0;ni<4;ni++){
        int rb = (wc+ni*16+l15)*64 + co;
        fbh[ni] = *(const s8b*)&sBh[rb];
        fbl[ni] = *(const s8b*)&sBl[rb];
      }
      #pragma unroll
      for(int mi=0;mi<4;mi++)
        #pragma unroll
        for(int ni=0;ni<4;ni++){
          acc[mi][ni] = __builtin_amdgcn_mfma_f32_16x16x32_bf16(fah[mi], fbh[ni], acc[mi][ni], 0,0,0);
          acc[mi][ni] = __builtin_amdgcn_mfma_f32_16x16x32_bf16(fah[mi], fbl[ni], acc[mi][ni], 0,0,0);
          acc[mi][ni] = __builtin_amdgcn_mfma_f32_16x16x32_bf16(fal[mi], fbh[ni], acc[mi][ni], 0,0,0);
        }
    }
    __syncthreads();   // all waves done reading before next stage overwrites
  }

  #pragma unroll
  for(int ni=0;ni<4;ni++){
    int gn = col0 + wc + ni*16 + l15;
    if(gn >= N) continue;
    #pragma unroll
    for(int mi=0;mi<4;mi++){
      #pragma unroll
      for(int rg=0;rg<4;rg++){
        int gr = row0 + wr + mi*16 + quad*4 + rg;
        if(gr >= M) continue;
        atomicAdd(&C[(size_t)gr*ldc + gn], acc[mi][ni][rg]);
      }
    }
  }
}

// ---------------- plain bf16 MFMA GEMM, split-K (2-phase dbuf, BK=64) -------
// R7-proven config (58.7us @ gg): dbuf 64 KiB, 2 blk/CU, STAGE(t+1) issued
// BEFORE compute(t) -> load latency covered by the MFMA phase, drained cheaply
// at the barrier. (R8's single-buf 4-blk/CU variant regressed 58.7->82.)
// Now used only for the gate GEMM (ldk=KAW).
__global__ __launch_bounds__(256,2)
void gemm_bf16_m97(const unsigned short* __restrict__ A, const unsigned short* __restrict__ Bt,
                   float* __restrict__ C, int M, int N, int ldc, int ldk, int tiles){
  __shared__ __align__(16) unsigned short sA[2][128*64];
  __shared__ __align__(16) unsigned short sB[2][128*64];
  int bx, by, bz; xcd_remap(bx, by, bz);
  int t = threadIdx.x;
  int row0 = by*128, col0 = bx*128;
  int per = (tiles + (int)gridDim.z - 1)/(int)gridDim.z;
  int tb = min(bz*per, tiles), te = min(tb + per, tiles);
  if(tb >= te) return;
  int lane = t&63, w = t>>6;
  int wr = (w>>1)*64, wc = (w&1)*64;
  int quad = lane>>4, l15 = lane&15;
  int seg = lane&7;
  size_t ro = (size_t)(w*8 + (lane>>3));
  const unsigned short* gA = A  + ((size_t)row0 + ro)*ldk + seg*8;
  const unsigned short* gB = Bt + ((size_t)col0 + ro)*ldk + seg*8;
  const int lds0 = (w*8)*64;
  const int c0 = ((quad ^ (l15 & 7)) << 3);

  f32x4 acc[4][4];
  #pragma unroll
  for(int mi=0;mi<4;mi++)
    #pragma unroll
    for(int ni=0;ni<4;ni++) acc[mi][ni] = (f32x4){0.f,0.f,0.f,0.f};

  auto STAGE = [&](int b, int kt){
    size_t k0 = (size_t)kt*64;
    #pragma unroll
    for(int r=0;r<4;r++){
      size_t go = (size_t)(r*32)*ldk + k0;
      int lo = lds0 + r*32*64;
      gload16(gA + go, &sA[b][lo]);
      gload16(gB + go, &sB[b][lo]);
    }
  };

  STAGE(0, tb);
  __syncthreads();
  int buf = 0;
  for(int kt=tb; kt<te; ++kt){
    if(kt+1 < te) STAGE(buf^1, kt+1);
    #pragma unroll
    for(int ks=0;ks<2;ks++){
      const int co = c0 ^ (ks<<5);
      s8b fa[4], fb[4];
      #pragma unroll
      for(int mi=0;mi<4;mi++) fa[mi] = *(const s8b*)&sA[buf][(wr+mi*16+l15)*64 + co];
      #pragma unroll
      for(int ni=0;ni<4;ni++) fb[ni] = *(const s8b*)&sB[buf][(wc+ni*16+l15)*64 + co];
      #pragma unroll
      for(int mi=0;mi<4;mi++)
        #pragma unroll
        for(int ni=0;ni<4;ni++)
          acc[mi][ni] = __builtin_amdgcn_mfma_f32_16x16x32_bf16(fa[mi], fb[ni], acc[mi][ni], 0,0,0);
    }
    __syncthreads();
    buf ^= 1;
  }

  #pragma unroll
  for(int ni=0;ni<4;ni++){
    int gn = col0 + wc + ni*16 + l15;
    if(gn >= N) continue;
    #pragma unroll
    for(int mi=0;mi<4;mi++){
      #pragma unroll
      for(int rg=0;rg<4;rg++){
        int gr = row0 + wr + mi*16 + quad*4 + rg;
        if(gr >= M) continue;
        atomicAdd(&C[(size_t)gr*ldc + gn], acc[mi][ni][rg]);
      }
    }
  }
}

// ---------------- per-row top-50 antecedents (1 wave / row) -----------------
// Register-resident selection (R5-verified: bit-identical, ~10x faster than LDS).
#define NT 13   // ceil(m/64) for m<=832
__global__ void topante_kernel(const float* __restrict__ tscore, const float* __restrict__ bilin,
                               int m, int* ante, float* tafast, float* out_ante){
  int i = blockIdx.x; int lane = threadIdx.x;
  float tsi = tscore[i];
  float v[NT];
  #pragma unroll
  for(int t=0;t<NT;t++){
    int j = lane + t*64;
    float f = -FLT_MAX;
    if(j < m){
      f = tsi + tscore[j];
      f += (j < i) ? 0.f : NEGF;
      f += bilin[(size_t)i*m + j];
    }
    v[t] = f;
  }
  unsigned consumed = 0u;
  int r_ante = 0; float r_fast = 0.f;
  for(int it=0; it<K2; ++it){
    float lv = -FLT_MAX; int li = m;
    #pragma unroll
    for(int t=0;t<NT;t++){
      bool live = ((consumed >> t) & 1u) == 0u;
      if(live && v[t] > lv){ lv = v[t]; li = lane + t*64; }
    }
    float bv = lv; int bi = li;
    #pragma unroll
    for(int off=32; off>0; off>>=1){
      float ov = __shfl_xor(bv, off);
      int   oi = __shfl_xor(bi, off);
      if(ov > bv || (ov == bv && oi < bi)){ bv = ov; bi = oi; }
    }
    if(bi < m && (bi & 63) == lane) consumed |= (1u << (bi >> 6));
    if(lane == it){ r_ante = bi; r_fast = bv; }
  }
  if(lane < K2){
    ante[(size_t)i*K2 + lane]   = r_ante;
    tafast[(size_t)i*K2 + lane] = r_fast;
    out_ante[(size_t)i*K2+lane] = (float)r_ante;
  }
}

// ---------------- depth loop pieces -----------------------------------------
__global__ void uv_kernel(const float* __restrict__ reps, const float* __restrict__ Wa3,
                          float* u, float* v, int m){
  int i = blockIdx.x; int tid = threadIdx.x;
  const float* rp = reps + (size_t)i*DD;
  float s1=0.f, s2=0.f;
  for(int d=tid; d<DD; d+=256){ float x = rp[d]; s1 += x*Wa3[d]; s2 += x*Wa3[DD+d]; }
  __shared__ float r1[256], r2[256];
  r1[tid]=s1; r2[tid]=s2; __syncthreads();
  for(int st=128; st>0; st>>=1){
    if(tid<st){ r1[tid]+=r1[tid+st]; r2[tid]+=r2[tid+st]; }
    __syncthreads();
  }
  if(tid==0){ u[i]=r1[0]; v[i]=r2[0]; }
}

// ---------------- R10: fused gathered slow scores ---------------------------
// Replaces {conv_slow_ops, gp dense m x m GEMM, slow_gather}: only m x K2 of P
// was ever read. Per block (row i): stage xi[k]=cur[i,k]*w3[k] in LDS (9.3 KB),
// each wave handles t = w, w+4, ...: gather j=ante[i,t], float4 dot over DD,
// 6-step shfl_xor reduce, write sc = tafast + u[i] + v[j] + dot + ba.
// cur (7.6 MB) is L2/L3-resident -> gathers are cache hits. f32 throughout
// (closer to reference than the old bf16-GEMM P).
__global__ __launch_bounds__(256)
void slow_scores(const float* __restrict__ cur, const float* __restrict__ Wa3,
                 const float* __restrict__ u, const float* __restrict__ v,
                 const int* __restrict__ ante, const float* __restrict__ tafast,
                 const float* __restrict__ ba, float* __restrict__ sc, int m){
  int i = blockIdx.x;
  int tid = threadIdx.x;
  int lane = tid & 63, w = tid >> 6;
  __shared__ __align__(16) float xi[DD];            // DD = 2324 = 581 float4s
  const float* ri = cur + (size_t)i*DD;
  for(int k=tid; k<DD; k+=256) xi[k] = ri[k]*Wa3[2*DD + k];
  __syncthreads();
  const float ui = u[i], b0 = ba[0];
  const int D4 = DD/4;                              // 581 exactly
  const f32x4* xi4 = (const f32x4*)xi;
  for(int t=w; t<K2; t+=4){
    int j = ante[(size_t)i*K2 + t];
    const f32x4* rj4 = (const f32x4*)(cur + (size_t)j*DD);
    float s = 0.f;
    for(int k=lane; k<D4; k+=64){
      f32x4 a = xi4[k], b = rj4[k];
      s += a[0]*b[0] + a[1]*b[1] + a[2]*b[2] + a[3]*b[3];
    }
    #pragma unroll
    for(int off=32; off>0; off>>=1) s += __shfl_xor(s, off);
    if(lane==0)
      sc[(size_t)i*K2 + t] = tafast[(size_t)i*K2 + t] + ui + v[j] + s + b0;
  }
}

__global__ void attend_kernel(const float* __restrict__ reps, const float* __restrict__ sc,
                              const int* __restrict__ ante, float* att, int m){
  int i = blockIdx.x; int tid = threadIdx.x;
  __shared__ float wts[K2+1];
  __shared__ float scs[K2];
  __shared__ int   js[K2];
  if(tid < K2){ scs[tid] = sc[(size_t)i*K2 + tid]; js[tid] = ante[(size_t)i*K2 + tid]; }
  __syncthreads();
  if(tid==0){
    float mx = 0.f;
    for(int t=0;t<K2;t++) mx = fmaxf(mx, scs[t]);
    float sum = expf(0.f - mx); wts[0] = sum;
    for(int t=0;t<K2;t++){ float e = expf(scs[t]-mx); wts[t+1]=e; sum += e; }
    float inv = 1.f/sum;
    for(int t=0;t<=K2;t++) wts[t] *= inv;
  }
  __syncthreads();
  const float* ri_ = reps + (size_t)i*DD;
  for(int d=tid; d<DD; d+=256){
    float a = wts[0]*ri_[d];
    for(int t=0;t<K2;t++) a += wts[t+1]*reps[(size_t)js[t]*DD + d];
    att[(size_t)i*DD + d] = a;
  }
}

// ---------------- bf16 conversion for the fused gate GEMM (SWIZZLED) --------
// Fused zeroing of nxt (the gg GEMM's atomic target, total = m*DD elems).
__global__ void conv_acat(const float* __restrict__ cur, const float* __restrict__ att,
                          unsigned short* __restrict__ A,
                          float* __restrict__ nxt, int total, int m){
  int idx = blockIdx.x*256 + threadIdx.x;
  if(idx >= MPAD*KAW) return;
  if(idx < total) nxt[idx] = 0.f;
  int row = idx / KAW, col = idx - row*KAW;
  float v = 0.f;
  if(row < m){
    if(col < DD) v = cur[(size_t)row*DD + col];
    else if(col >= KPAD && col < KPAD + DD) v = att[(size_t)row*DD + (col - KPAD)];
  }
  A[row*KAW + swz_col(row, col)] = f2bf(v);
}

// Bt_cat (NPAD x KAW): Bt[n][s*KPAD+k] = Wf[s*DD+k][n], zero-padded
__global__ void conv_wf(const float* __restrict__ Wf, unsigned short* __restrict__ Bt){
  int n  = blockIdx.y*64 + threadIdx.x;
  int k8 = blockIdx.x*8;
  int s  = (k8 >= KPAD) ? 1 : 0;
  int kk = k8 - s*KPAD;
  u16x8 v;
  #pragma unroll
  for(int j=0;j<8;j++){
    int k = kk + j;
    float f = (n < DD && k < DD) ? Wf[(size_t)(s*DD + k)*DD + n] : 0.f;
    v[j] = f2bf(f);
  }
  int k8s = swz_col(n, k8);
  *(u16x8*)(Bt + (size_t)n*KAW + k8s) = v;
}

// gate epilogue: nxt holds accumulated pre-activation; apply bias+sigmoid+update
__global__ void gate_update(const float* __restrict__ bfv, const float* __restrict__ att,
                            const float* __restrict__ cur, float* __restrict__ nxt, int total){
  int idx = blockIdx.x*256 + threadIdx.x;
  if(idx >= total) return;
  int col = idx % DD;
  float pre = nxt[idx] + bfv[col];
  float g = 1.f/(1.f + expf(-pre));
  nxt[idx] = g*att[idx] + (1.f - g)*cur[idx];
}

// ---------------- final scores + per-row loss -------------------------------
__global__ void final_loss(const float* __restrict__ sc, const int* __restrict__ ante,
                           const int* __restrict__ tclust, float* out_fs, float* row_loss, int m){
  int i = blockIdx.x*blockDim.x + threadIdx.x;
  if(i >= m) return;
  int tci = tclust[i];
  unsigned long long labm = 0ull;
  bool anyp = false;
  float mx = 0.f;
  float mg = -FLT_MAX;
  for(int t=0;t<K2;t++){
    float v = sc[(size_t)i*K2 + t];
    mx = fmaxf(mx, v);
    int j = ante[(size_t)i*K2 + t];
    bool mk = (j < i);
    int ac = mk ? tclust[j] : -1;
    bool p = (ac == tci) && (tci > 0);
    if(p){ labm |= (1ull << (t+1)); anyp = true; mg = fmaxf(mg, v); }
  }
  if(!anyp){ labm |= 1ull; mg = 0.f; }
  float s1 = expf(0.f - mx);
  float s2 = (labm & 1ull) ? expf(0.f - mg) : 0.f;
  float* o = out_fs + (size_t)i*(K2+1);
  o[0] = 0.f;
  for(int t=0;t<K2;t++){
    float v = sc[(size_t)i*K2 + t];
    o[t+1] = v;
    s1 += expf(v - mx);
    if(labm & (1ull << (t+1))) s2 += expf(v - mg);
  }
  row_loss[i] = (mx + logf(s1)) - (mg + logf(s2));
}

__global__ void loss_sum(const float* __restrict__ row_loss, float* out, int m){
  int tid = threadIdx.x;
  float s = 0.f;
  for(int i=tid; i<m; i+=256) s += row_loss[i];
  __shared__ float red[256];
  red[tid]=s; __syncthreads();
  for(int st=128; st>0; st>>=1){ if(tid<st) red[tid]+=red[tid+st]; __syncthreads(); }
  if(tid==0) out[0] = red[0];
}

// ---------------------------------------------------------------------------
extern "C" void kernel_launch(void* const* d_in, const int* in_sizes, int n_in,
                              void* d_out, int out_size, void* d_ws, size_t ws_size,
                              hipStream_t stream){
  const int W = in_sizes[11];
  const int G = in_sizes[12];
  const int C = W * MSW;
  const int m = (int)(0.4 * (double)W);

  const float* seq   = (const float*)d_in[0];
  const float* Wal   = (const float*)d_in[1];
  const float* bal   = (const float*)d_in[2];
  const float* Wm    = (const float*)d_in[3];
  const float* bm    = (const float*)d_in[4];
  const float* Wc    = (const float*)d_in[5];
  const float* WaA   = (const float*)d_in[6];
  const float* baA   = (const float*)d_in[7];
  const float* Wf    = (const float*)d_in[8];
  const float* bf    = (const float*)d_in[9];
  const float* wfeat = (const float*)d_in[10];
  const int*   smap  = (const int*)d_in[11];
  const int*   gs    = (const int*)d_in[12];
  const int*   ge    = (const int*)d_in[13];
  const int*   cid   = (const int*)d_in[14];
  float* out = (float*)d_out;

  // workspace layout (phase-aliased; peak ~59 MB, proven safe <65 MB)
  char* ws = (char*)d_ws;
  size_t off = 0;
  auto alloc = [&](size_t bytes)->char*{
    char* p = ws + off;
    off += (bytes + 255) & ~(size_t)255;
    return p;
  };
  const size_t PLANE  = (size_t)MPAD*KPAD*2;   // 4.36 MB
  const size_t WPLANE = (size_t)NPAD*KPAD*2;   // 11.83 MB

  float* alphas  = (float*)alloc((size_t)W*4);
  float* p1      = (float*)alloc((size_t)W*4);
  float* p2      = (float*)alloc((size_t)W*4);
  float* p3      = (float*)alloc((size_t)W*4);
  float* mscore  = (float*)alloc((size_t)C*4);
  float* mmask   = (float*)alloc((size_t)C*4);
  int*   ccl     = (int*)  alloc((size_t)C*4);
  int*   top_idx = (int*)  alloc((size_t)m*4);
  float* tscore  = (float*)alloc((size_t)m*4);
  int*   tclust  = (int*)  alloc((size_t)m*4);
  float* B1      = (float*)alloc((size_t)m*DD*4);  // top_rep / reps ping
  float* B2      = (float*)alloc((size_t)m*DD*4);  // tmp / reps pong
  float* B3      = (float*)alloc((size_t)m*DD*4);  // attended
  float* bilin   = (float*)alloc((size_t)m*m*4);   // bilin (fast scores)
  int*   ante    = (int*)  alloc((size_t)m*K2*4);
  float* tafast  = (float*)alloc((size_t)m*K2*4);
  float* uB      = (float*)alloc((size_t)m*4);
  float* vB      = (float*)alloc((size_t)m*4);
  float* scB     = (float*)alloc((size_t)m*K2*4);
  float* rloss   = (float*)alloc((size_t)m*4);
  // regionA (2*PLANE), phase-aliased:
  //   bilinear: RepH | RepL      gate: Acat (spans both)
  char* regionA = alloc(2*PLANE);
  unsigned short* RepH  = (unsigned short*)regionA;
  unsigned short* RepL  = (unsigned short*)(regionA + PLANE);
  unsigned short* Acat  = (unsigned short*)regionA;            // MPAD*KAW*2 == 2*PLANE
  // regionB (2*WPLANE), phase-aliased:
  //   gemm1: WtH | WtL   ->  gemm2: A2H | A2L (after gemm1 done)  ->  depth: BtWf
  char* regionB = alloc(2*WPLANE);
  unsigned short* WtH  = (unsigned short*)regionB;
  unsigned short* WtL  = (unsigned short*)(regionB + WPLANE);
  unsigned short* A2H  = (unsigned short*)regionB;
  unsigned short* A2L  = (unsigned short*)(regionB + PLANE);
  unsigned short* BtWf = (unsigned short*)regionB;             // NPAD*KAW*2 == 2*WPLANE

  // output offsets (all float32)
  float* out_ts   = out;
  float* out_te   = out + m;
  float* out_ante = out + 2*m;
  float* out_fs   = out + 2*m + (size_t)m*K2;
  float* out_loss = out + 2*m + (size_t)m*K2 + (size_t)m*(K2+1);

  // 1) per-token projections
  row_proj<<<W, 256, 0, stream>>>(seq, Wal, bal, Wm, alphas, p1, p2, p3, W);
  // 2) candidate mention scores
  mention_kernel<<<(C+255)/256, 256, 0, stream>>>(alphas, p1, p2, p3, wfeat, Wm, bm,
                                                  smap, gs, ge, cid, G,
                                                  mscore, mmask, ccl, W);
  // 3) exact top-m selection + compaction
  select_kernel<<<1, 1024, 0, stream>>>(mmask, mscore, ccl, m, C, W,
                                        top_idx, tscore, tclust, out_ts, out_te);
  // 4) build top_rep into B1
  build_rep<<<m, 256, 0, stream>>>(seq, alphas, wfeat, top_idx, B1, W);
  // 5) bilinear antecedent scores via split-bf16 3-term MFMA (split-K, atomic)
  {
    const int NEL = MPAD*KPAD;
    // conv_split also zeroes B2 (g1's atomic target)
    conv_split<<<(NEL+255)/256, 256, 0, stream>>>(B1, m, DD, RepH, RepL, B2, m*DD);
    dim3 gw(KPAD/8, NPAD/64);
    conv_split_wcT<<<gw, 64, 0, stream>>>(Wc, WtH, WtL);
    dim3 g1(NPAD/128, MPAD/128, 3);     // (19, 7, 3) = 399 blocks <= 512: no tail wave
    gemm_split3_sk<<<g1, 256, 0, stream>>>(RepH, RepL, WtH, WtL, B2, m, DD, DD);
    // conv_split also zeroes bilin (g2's atomic target)
    conv_split<<<(NEL+255)/256, 256, 0, stream>>>(B2, m, DD, A2H, A2L, bilin, m*m);
    dim3 g2(MPAD/128, MPAD/128, 10);    // (7, 7, 10) = 490 blocks <= 512
    gemm_split3_sk<<<g2, 256, 0, stream>>>(A2H, A2L, RepH, RepL, bilin, m, m, m);
  }
  // 6) per-row top-50 (1 wave per row, register-resident)
  topante_kernel<<<m, 64, 0, stream>>>(tscore, bilin, m, ante, tafast, out_ante);
  // gate weights -> bf16 transposed (AFTER bilinear GEMMs: regionB alias)
  {
    dim3 g(KAW/8, NPAD/64);
    conv_wf<<<g, 64, 0, stream>>>(Wf, BtWf);
  }

  // 7) DEPTH=2 refinement (gathered slow scores + gate GEMM)
  float* cur = B1; float* nxt = B2;
  const int total = m * DD;
  for(int depth=0; depth<2; depth++){
    uv_kernel<<<m, 256, 0, stream>>>(cur, WaA, uB, vB, m);
    // R10: gathered slow scores (f32) — replaces conv_slow_ops + gp GEMM + slow_gather
    slow_scores<<<m, 256, 0, stream>>>(cur, WaA, uB, vB, ante, tafast, baA, scB, m);
    attend_kernel<<<m, 256, 0, stream>>>(cur, scB, ante, B3, m);
    // gate pre-activation accumulates into zeroed nxt; conv_acat zeroes nxt
    conv_acat<<<(MPAD*KAW+255)/256, 256, 0, stream>>>(cur, B3, Acat, nxt, total, m);
    dim3 gg(NPAD/128, MPAD/128, 3);     // (19, 7, 3) = 399 blocks <= 512: no tail wave
    gemm_bf16_m97<<<gg, 256, 0, stream>>>(Acat, BtWf, nxt, m, DD, DD, KAW, KAW/64);
    gate_update<<<(total+255)/256, 256, 0, stream>>>(bf, B3, cur, nxt, total);
    float* t = cur; cur = nxt; nxt = t;
  }

  // 8) final scores + loss
  final_loss<<<(m+255)/256, 256, 0, stream>>>(scB, ante, tclust, out_fs, rloss, m);
  loss_sum<<<1, 256, 0, stream>>>(rloss, out_loss, m);
}

// Round 11
// 784.011 us; speedup vs baseline: 1.0994x; 1.0126x over previous
//
#include <hip/hip_runtime.h>
#include <cfloat>
#include <climits>
#include <math.h>

#define HD   768
#define MSW  10
#define WFK  20
#define DD   2324    // 3*768+20
#define K2   50
#define NEGF (-1e30f)

// MFMA geometry (K padded to mult of 128 for deep-K tiles)
#define KPAD 2432          // 19*128, >= DD
#define KAW  4864          // 2*KPAD  (K-concat of [cur | att] for the gate GEMM)
#define MPAD 896           // 7 * 128 (>= m=819)
#define NPAD 2432          // 19 * 128 (>= DD)

typedef __attribute__((ext_vector_type(8))) short    s8b;
typedef __attribute__((ext_vector_type(8))) unsigned short u16x8;
typedef __attribute__((ext_vector_type(4))) float    f32x4;

__device__ inline unsigned short f2bf(float f){
  unsigned u = __float_as_uint(f);
  unsigned r = (u + 0x7FFFu + ((u >> 16) & 1u)) >> 16;   // RNE
  return (unsigned short)r;
}
__device__ inline float bf2f(unsigned short h){
  return __uint_as_float(((unsigned)h) << 16);
}

// async global->LDS, 16B per lane; LDS dest must be wave-uniform base (+lane*16 implicit)
__device__ __forceinline__ void gload16(const unsigned short* g, void* l){
  __builtin_amdgcn_global_load_lds(
      (const __attribute__((address_space(1))) void*)g,
      (__attribute__((address_space(3))) void*)l, 16, 0, 0);
}

// ---- bank-conflict swizzle (both-sides involution, rule #21) ----------------
// Staging planes store chunk (16B = 8 shorts) j of row r at position j^(r&7)
// within each 64-short K-tile. global_load_lds copies linearly; ds_read XORs.
// Verified R2: SQ_LDS_BANK_CONFLICT 7.76M -> 0.
__device__ __forceinline__ int swz_col(int row, int col){
  return col ^ ((row & 7) << 3);
}

// ---- T1: XCD-aware bijective block remap (m204 form) ------------------------
// Verified R7: g1 64.4 -> ~58us, frame -30us. Pure index permutation.
__device__ __forceinline__ void xcd_remap(int &bx, int &by, int &bz){
  int nwg  = (int)(gridDim.x*gridDim.y*gridDim.z);
  int orig = (int)(blockIdx.x + gridDim.x*(blockIdx.y + gridDim.y*blockIdx.z));
  int q = nwg >> 3, r = nwg & 7;
  int x8 = orig & 7, o8 = orig >> 3;
  int wg = (x8 < r ? x8*(q+1) : r*(q+1) + (x8-r)*q) + o8;
  bx = wg % (int)gridDim.x;
  int tmp = wg / (int)gridDim.x;
  by = tmp % (int)gridDim.y;
  bz = tmp / (int)gridDim.y;
}

// ---------------- per-token projections: alphas, p1,p2,p3 -------------------
__global__ void row_proj(const float* __restrict__ seq, const float* __restrict__ Wa,
                         const float* __restrict__ ba, const float* __restrict__ Wm,
                         float* alphas, float* p1, float* p2, float* p3, int W){
  int w = blockIdx.x; int tid = threadIdx.x;
  const float* row = seq + (size_t)w * HD;
  float s0=0.f, s1=0.f, s2=0.f, s3=0.f;
  for(int h=tid; h<HD; h+=256){
    float x = row[h];
    s0 += x * Wa[h];
    s1 += x * Wm[h];
    s2 += x * Wm[HD + h];
    s3 += x * Wm[2*HD + h];
  }
  __shared__ float r0[256], r1[256], r2[256], r3[256];
  r0[tid]=s0; r1[tid]=s1; r2[tid]=s2; r3[tid]=s3;
  __syncthreads();
  for(int st=128; st>0; st>>=1){
    if(tid<st){ r0[tid]+=r0[tid+st]; r1[tid]+=r1[tid+st]; r2[tid]+=r2[tid+st]; r3[tid]+=r3[tid+st]; }
    __syncthreads();
  }
  if(tid==0){ alphas[w]=r0[0]+ba[0]; p1[w]=r1[0]; p2[w]=r2[0]; p3[w]=r3[0]; }
}

// ---------------- mention scoring per candidate -----------------------------
__global__ void mention_kernel(const float* __restrict__ alphas, const float* __restrict__ p1,
                               const float* __restrict__ p2, const float* __restrict__ p3,
                               const float* __restrict__ wfeat, const float* __restrict__ Wm,
                               const float* __restrict__ bm,
                               const int* __restrict__ smap, const int* __restrict__ gs,
                               const int* __restrict__ ge, const int* __restrict__ cid, int G,
                               float* mscore, float* mmask, int* ccl, int W){
  int c = blockIdx.x*blockDim.x + threadIdx.x;
  int C = W * MSW;
  if(c >= C) return;
  int s = c / MSW, r = c - s*MSW;
  int e = s + r; int ec = min(e, W-1);
  int L = ec - s;
  bool valid = (e < W) && (smap[s] == smap[ec]);
  float maxa = -FLT_MAX;
  for(int j=0;j<=L;j++) maxa = fmaxf(maxa, alphas[s+j]);
  float sum=0.f, sdot=0.f;
  for(int j=0;j<=L;j++){ float ee = expf(alphas[s+j]-maxa); sum += ee; sdot += ee*p3[s+j]; }
  sdot /= sum;
  float wp=0.f;
  for(int f=0; f<WFK; f++) wp += wfeat[L*WFK+f] * Wm[3*HD+f];
  float ms = p1[s] + p2[ec] + sdot + wp + bm[0];
  mscore[c] = ms;
  mmask[c]  = valid ? ms : NEGF;
  int cc = 0;
  for(int g=0; g<G; g++) if(s==gs[g] && ec==ge[g]) cc += cid[g];
  ccl[c] = cc;
}

// ---------------- single-block exact top-m radix select ---------------------
__device__ inline unsigned fkey(float f){
  unsigned b = __float_as_uint(f);
  return (b & 0x80000000u) ? ~b : (b | 0x80000000u);
}

__global__ __launch_bounds__(1024)
void select_kernel(const float* __restrict__ mmask, const float* __restrict__ mscore,
                   const int* __restrict__ ccl, int m, int C, int W,
                   int* top_idx, float* tscore, int* tclust,
                   float* out_ts, float* out_te){
  const int T = 1024;
  int tid = threadIdx.x;
  int chunk = (C + T - 1)/T;
  int lo = tid*chunk, hi = min(lo+chunk, C);
  int n = hi - lo; if(n < 0) n = 0;
  unsigned kb[32];
  for(int t=0;t<n;t++) kb[t] = fkey(mmask[lo+t]);

  __shared__ unsigned s_hist[256];
  __shared__ unsigned s_scan[1024];
  __shared__ unsigned s_pref;
  __shared__ int s_rem;
  if(tid==0){ s_pref=0u; s_rem=m; }
  __syncthreads();

  for(int b=3;b>=0;b--){
    if(tid<256) s_hist[tid]=0u;
    __syncthreads();
    unsigned pref = s_pref;
    unsigned msk = (b==3)?0u:(0xFFFFFFFFu << ((b+1)*8));
    for(int t=0;t<n;t++){
      unsigned u = kb[t];
      if((u & msk)==pref) atomicAdd(&s_hist[(u>>(b*8))&0xFFu], 1u);
    }
    __syncthreads();
    if(tid==0){
      int rem = s_rem; unsigned acc=0u; int bin;
      for(bin=255;bin>=1;bin--){
        unsigned h = s_hist[bin];
        if(acc + h >= (unsigned)rem) break;
        acc += h;
      }
      if(bin < 0) bin = 0;
      s_pref = pref | ((unsigned)bin << (b*8));
      s_rem = rem - (int)acc;
    }
    __syncthreads();
  }
  unsigned Tk = s_pref;
  int need = s_rem;

  unsigned nG=0, nE=0;
  for(int t=0;t<n;t++){ unsigned u=kb[t]; nG += (u>Tk)?1u:0u; nE += (u==Tk)?1u:0u; }

  s_scan[tid]=nE; __syncthreads();
  for(int off=1; off<T; off<<=1){
    unsigned x = (tid>=off)? s_scan[tid-off]:0u; __syncthreads();
    s_scan[tid]+=x; __syncthreads();
  }
  unsigned eqBase = s_scan[tid]-nE;
  __syncthreads();

  int takeLeft = need - (int)eqBase;
  int take = takeLeft<0?0:(takeLeft>(int)nE?(int)nE:takeLeft);
  unsigned selCnt = nG + (unsigned)take;

  s_scan[tid]=selCnt; __syncthreads();
  for(int off=1; off<T; off<<=1){
    unsigned x = (tid>=off)? s_scan[tid-off]:0u; __syncthreads();
    s_scan[tid]+=x; __syncthreads();
  }
  unsigned posBase = s_scan[tid]-selCnt;

  int pos = (int)posBase; int eq = (int)eqBase;
  for(int t=0;t<n;t++){
    unsigned u = kb[t];
    bool sel = false;
    if(u>Tk) sel=true;
    else if(u==Tk){ if(eq<need) sel=true; eq++; }
    if(sel){
      int c = lo+t;
      top_idx[pos] = c;
      int s = c/MSW, r = c - s*MSW; int e = min(s + r, W-1);
      tscore[pos] = mscore[c];
      tclust[pos] = ccl[c];
      out_ts[pos] = (float)s;
      out_te[pos] = (float)e;
      pos++;
    }
  }
}

// ---------------- build top_rep (m x D) -------------------------------------
__global__ void build_rep(const float* __restrict__ seq, const float* __restrict__ alphas,
                          const float* __restrict__ wfeat, const int* __restrict__ top_idx,
                          float* rep, int W){
  int i = blockIdx.x; int tid = threadIdx.x;
  int c = top_idx[i];
  int s = c/MSW, r = c - s*MSW; int ec = min(s + r, W-1); int L = ec - s;
  float wv[MSW];
  float maxa = -FLT_MAX;
  for(int j=0;j<=L;j++) maxa = fmaxf(maxa, alphas[s+j]);
  float sum = 0.f;
  for(int j=0;j<=L;j++){ wv[j] = expf(alphas[s+j]-maxa); sum += wv[j]; }
  float inv = 1.f/sum;
  float* o = rep + (size_t)i*DD;
  for(int d=tid; d<HD; d+=256){
    o[d]      = seq[(size_t)s*HD + d];
    o[HD+d]   = seq[(size_t)ec*HD + d];
    float sp = 0.f;
    for(int j=0;j<=L;j++) sp += wv[j]*seq[(size_t)(s+j)*HD + d];
    o[2*HD+d] = sp*inv;
  }
  for(int f=tid; f<WFK; f+=256) o[3*HD+f] = wfeat[L*WFK+f];
}

// ---------------- split-bf16 conversions (SWIZZLED output layout) -----------
// Fused zeroing of the next GEMM's accumulation target (ztgt[0..zn)) —
// removes standalone zero_buf launches. No read/write overlap with src.
__global__ void conv_split(const float* __restrict__ src, int rows, int cols,
                           unsigned short* __restrict__ hi, unsigned short* __restrict__ lo,
                           float* __restrict__ ztgt, int zn){
  int idx = blockIdx.x*256 + threadIdx.x;
  if(idx >= MPAD*KPAD) return;
  if(idx < zn) ztgt[idx] = 0.f;
  int row = idx / KPAD, col = idx - row*KPAD;
  float v = (row < rows && col < cols) ? src[(size_t)row*cols + col] : 0.f;
  unsigned short h = f2bf(v);
  int w = row*KPAD + swz_col(row, col);
  hi[w] = h;
  lo[w] = f2bf(v - bf2f(h));
}

// Wc (DD x DD) -> transposed hi/lo planes (NPAD x KPAD): Wt[n][k] = Wc[k][n]
__global__ void conv_split_wcT(const float* __restrict__ Wc,
                               unsigned short* __restrict__ WtH, unsigned short* __restrict__ WtL){
  int n  = blockIdx.y*64 + threadIdx.x;
  int k8 = blockIdx.x*8;
  u16x8 vh, vl;
  #pragma unroll
  for(int j=0;j<8;j++){
    int k = k8 + j;
    float f = (n < DD && k < DD) ? Wc[(size_t)k*DD + n] : 0.f;
    unsigned short h = f2bf(f);
    vh[j] = h;
    vl[j] = f2bf(f - bf2f(h));
  }
  int k8s = swz_col(n, k8);          // XOR hits bits 3-5 only; 16B granularity
  *(u16x8*)(WtH + (size_t)n*KPAD + k8s) = vh;
  *(u16x8*)(WtL + (size_t)n*KPAD + k8s) = vl;
}

// ---------------- split-bf16 3-term MFMA GEMM, split-K ----------------------
// R5-measured-best structure + R7 T1 remap: single-buffered linear LDS via
// global_load_lds, 2 barriers per BK=64 step. LDS = 4 planes x 16 KiB = 64 KiB
// -> 2 blocks/CU. Swizzled reads (conflicts = 0). Grid <= 512 blocks.
__global__ __launch_bounds__(256,2)
void gemm_split3_sk(const unsigned short* __restrict__ Ah, const unsigned short* __restrict__ Al,
                    const unsigned short* __restrict__ Bth, const unsigned short* __restrict__ Btl,
                    float* __restrict__ C, int M, int N, int ldc){
  __shared__ __align__(16) unsigned short sAh[128*64];
  __shared__ __align__(16) unsigned short sAl[128*64];
  __shared__ __align__(16) unsigned short sBh[128*64];
  __shared__ __align__(16) unsigned short sBl[128*64];
  int bx, by, bz; xcd_remap(bx, by, bz);
  int t = threadIdx.x;
  int row0 = by*128, col0 = bx*128;
  const int tiles = KPAD/64;                              // 38
  int per = (tiles + (int)gridDim.z - 1)/(int)gridDim.z;
  int tb = min(bz*per, tiles), te = min(tb + per, tiles);
  if(tb >= te) return;
  int lane = t&63, w = t>>6;
  int wr = (w>>1)*64, wc = (w&1)*64;
  int quad = lane>>4, l15 = lane&15;
  int seg = lane&7;
  size_t ro = (size_t)(w*8 + (lane>>3));                  // staging row within 32-row group
  const unsigned short* gAh = Ah  + ((size_t)row0 + ro)*KPAD + seg*8;
  const unsigned short* gAl = Al  + ((size_t)row0 + ro)*KPAD + seg*8;
  const unsigned short* gBh = Bth + ((size_t)col0 + ro)*KPAD + seg*8;
  const unsigned short* gBl = Btl + ((size_t)col0 + ro)*KPAD + seg*8;
  const int lds0 = (w*8)*64;                              // wave-uniform LDS base (shorts)
  // swizzled read chunk offsets (shorts): ks=0 -> c0, ks=1 -> c0^32
  const int c0 = ((quad ^ (l15 & 7)) << 3);

  f32x4 acc[4][4];
  #pragma unroll
  for(int mi=0;mi<4;mi++)
    #pragma unroll
    for(int ni=0;ni<4;ni++) acc[mi][ni] = (f32x4){0.f,0.f,0.f,0.f};

  for(int kt=tb; kt<te; ++kt){
    size_t k0 = (size_t)kt*64;
    #pragma unroll
    for(int r=0;r<4;r++){
      size_t go = (size_t)(r*32)*KPAD + k0;
      int lo = lds0 + r*32*64;
      gload16(gAh + go, sAh + lo);
      gload16(gAl + go, sAl + lo);
      gload16(gBh + go, sBh + lo);
      gload16(gBl + go, sBl + lo);
    }
    __syncthreads();   // drains vmcnt(0): tile landed in LDS
    #pragma unroll
    for(int ks=0;ks<2;ks++){
      const int co = c0 ^ (ks<<5);
      s8b fah[4], fal[4], fbh[4], fbl[4];
      #pragma unroll
      for(int mi=0;mi<4;mi++){
        int ra = (wr+mi*16+l15)*64 + co;
        fah[mi] = *(const s8b*)&sAh[ra];
        fal[mi] = *(const s8b*)&sAl[ra];
      }
      #pragma unroll
      for(int ni=0;ni<4;ni++){
        int rb = (wc+ni*16+l15)*64 + co;
        fbh[ni] = *(const s8b*)&sBh[rb];
        fbl[ni] = *(const s8b*)&sBl[rb];
      }
      #pragma unroll
      for(int mi=0;mi<4;mi++)
        #pragma unroll
        for(int ni=0;ni<4;ni++){
          acc[mi][ni] = __builtin_amdgcn_mfma_f32_16x16x32_bf16(fah[mi], fbh[ni], acc[mi][ni], 0,0,0);
          acc[mi][ni] = __builtin_amdgcn_mfma_f32_16x16x32_bf16(fah[mi], fbl[ni], acc[mi][ni], 0,0,0);
          acc[mi][ni] = __builtin_amdgcn_mfma_f32_16x16x32_bf16(fal[mi], fbh[ni], acc[mi][ni], 0,0,0);
        }
    }
    __syncthreads();   // all waves done reading before next stage overwrites
  }

  #pragma unroll
  for(int ni=0;ni<4;ni++){
    int gn = col0 + wc + ni*16 + l15;
    if(gn >= N) continue;
    #pragma unroll
    for(int mi=0;mi<4;mi++){
      #pragma unroll
      for(int rg=0;rg<4;rg++){
        int gr = row0 + wr + mi*16 + quad*4 + rg;
        if(gr >= M) continue;
        atomicAdd(&C[(size_t)gr*ldc + gn], acc[mi][ni][rg]);
      }
    }
  }
}

// ---------------- plain bf16 MFMA GEMM, split-K (2-phase dbuf, BK=64) -------
// R7-proven config (58.7us @ gg): dbuf 64 KiB, 2 blk/CU, STAGE(t+1) issued
// BEFORE compute(t) -> load latency covered by the MFMA phase, drained cheaply
// at the barrier. (R8's single-buf 4-blk/CU variant regressed 58.7->82.)
// Used only for the gate GEMM (ldk=KAW).
__global__ __launch_bounds__(256,2)
void gemm_bf16_m97(const unsigned short* __restrict__ A, const unsigned short* __restrict__ Bt,
                   float* __restrict__ C, int M, int N, int ldc, int ldk, int tiles){
  __shared__ __align__(16) unsigned short sA[2][128*64];
  __shared__ __align__(16) unsigned short sB[2][128*64];
  int bx, by, bz; xcd_remap(bx, by, bz);
  int t = threadIdx.x;
  int row0 = by*128, col0 = bx*128;
  int per = (tiles + (int)gridDim.z - 1)/(int)gridDim.z;
  int tb = min(bz*per, tiles), te = min(tb + per, tiles);
  if(tb >= te) return;
  int lane = t&63, w = t>>6;
  int wr = (w>>1)*64, wc = (w&1)*64;
  int quad = lane>>4, l15 = lane&15;
  int seg = lane&7;
  size_t ro = (size_t)(w*8 + (lane>>3));
  const unsigned short* gA = A  + ((size_t)row0 + ro)*ldk + seg*8;
  const unsigned short* gB = Bt + ((size_t)col0 + ro)*ldk + seg*8;
  const int lds0 = (w*8)*64;
  const int c0 = ((quad ^ (l15 & 7)) << 3);

  f32x4 acc[4][4];
  #pragma unroll
  for(int mi=0;mi<4;mi++)
    #pragma unroll
    for(int ni=0;ni<4;ni++) acc[mi][ni] = (f32x4){0.f,0.f,0.f,0.f};

  auto STAGE = [&](int b, int kt){
    size_t k0 = (size_t)kt*64;
    #pragma unroll
    for(int r=0;r<4;r++){
      size_t go = (size_t)(r*32)*ldk + k0;
      int lo = lds0 + r*32*64;
      gload16(gA + go, &sA[b][lo]);
      gload16(gB + go, &sB[b][lo]);
    }
  };

  STAGE(0, tb);
  __syncthreads();
  int buf = 0;
  for(int kt=tb; kt<te; ++kt){
    if(kt+1 < te) STAGE(buf^1, kt+1);
    #pragma unroll
    for(int ks=0;ks<2;ks++){
      const int co = c0 ^ (ks<<5);
      s8b fa[4], fb[4];
      #pragma unroll
      for(int mi=0;mi<4;mi++) fa[mi] = *(const s8b*)&sA[buf][(wr+mi*16+l15)*64 + co];
      #pragma unroll
      for(int ni=0;ni<4;ni++) fb[ni] = *(const s8b*)&sB[buf][(wc+ni*16+l15)*64 + co];
      #pragma unroll
      for(int mi=0;mi<4;mi++)
        #pragma unroll
        for(int ni=0;ni<4;ni++)
          acc[mi][ni] = __builtin_amdgcn_mfma_f32_16x16x32_bf16(fa[mi], fb[ni], acc[mi][ni], 0,0,0);
    }
    __syncthreads();
    buf ^= 1;
  }

  #pragma unroll
  for(int ni=0;ni<4;ni++){
    int gn = col0 + wc + ni*16 + l15;
    if(gn >= N) continue;
    #pragma unroll
    for(int mi=0;mi<4;mi++){
      #pragma unroll
      for(int rg=0;rg<4;rg++){
        int gr = row0 + wr + mi*16 + quad*4 + rg;
        if(gr >= M) continue;
        atomicAdd(&C[(size_t)gr*ldc + gn], acc[mi][ni][rg]);
      }
    }
  }
}

// ---------------- per-row top-50 antecedents (1 wave / row) -----------------
// Register-resident selection (R5-verified: bit-identical, ~10x faster than LDS).
#define NT 13   // ceil(m/64) for m<=832
__global__ void topante_kernel(const float* __restrict__ tscore, const float* __restrict__ bilin,
                               int m, int* ante, float* tafast, float* out_ante){
  int i = blockIdx.x; int lane = threadIdx.x;
  float tsi = tscore[i];
  float v[NT];
  #pragma unroll
  for(int t=0;t<NT;t++){
    int j = lane + t*64;
    float f = -FLT_MAX;
    if(j < m){
      f = tsi + tscore[j];
      f += (j < i) ? 0.f : NEGF;
      f += bilin[(size_t)i*m + j];
    }
    v[t] = f;
  }
  unsigned consumed = 0u;
  int r_ante = 0; float r_fast = 0.f;
  for(int it=0; it<K2; ++it){
    float lv = -FLT_MAX; int li = m;
    #pragma unroll
    for(int t=0;t<NT;t++){
      bool live = ((consumed >> t) & 1u) == 0u;
      if(live && v[t] > lv){ lv = v[t]; li = lane + t*64; }
    }
    float bv = lv; int bi = li;
    #pragma unroll
    for(int off=32; off>0; off>>=1){
      float ov = __shfl_xor(bv, off);
      int   oi = __shfl_xor(bi, off);
      if(ov > bv || (ov == bv && oi < bi)){ bv = ov; bi = oi; }
    }
    if(bi < m && (bi & 63) == lane) consumed |= (1u << (bi >> 6));
    if(lane == it){ r_ante = bi; r_fast = bv; }
  }
  if(lane < K2){
    ante[(size_t)i*K2 + lane]   = r_ante;
    tafast[(size_t)i*K2 + lane] = r_fast;
    out_ante[(size_t)i*K2+lane] = (float)r_ante;
  }
}

// ---------------- depth loop pieces -----------------------------------------
__global__ void uv_kernel(const float* __restrict__ reps, const float* __restrict__ Wa3,
                          float* u, float* v, int m){
  int i = blockIdx.x; int tid = threadIdx.x;
  const float* rp = reps + (size_t)i*DD;
  float s1=0.f, s2=0.f;
  for(int d=tid; d<DD; d+=256){ float x = rp[d]; s1 += x*Wa3[d]; s2 += x*Wa3[DD+d]; }
  __shared__ float r1[256], r2[256];
  r1[tid]=s1; r2[tid]=s2; __syncthreads();
  for(int st=128; st>0; st>>=1){
    if(tid<st){ r1[tid]+=r1[tid+st]; r2[tid]+=r2[tid+st]; }
    __syncthreads();
  }
  if(tid==0){ u[i]=r1[0]; v[i]=r2[0]; }
}

// ---------------- R11: fused slow scores + attend ---------------------------
// Merges slow_scores (R10) and attend_kernel: the two kernels gathered the SAME
// 50 rows of cur. Phase 1 computes the 50 dots (rows become L2/L1-hot and sc
// stays in LDS), phase 2 does the softmax (exact replica of attend's serial
// form incl. the dummy-0 max seed), phase 3 re-reads the hot rows for the
// weighted accumulation. Saves one launch + one cold gather pass per depth.
__global__ __launch_bounds__(256)
void slow_attend(const float* __restrict__ cur, const float* __restrict__ Wa3,
                 const float* __restrict__ u, const float* __restrict__ v,
                 const int* __restrict__ ante, const float* __restrict__ tafast,
                 const float* __restrict__ ba, float* __restrict__ sc,
                 float* __restrict__ att, int m){
  int i = blockIdx.x;
  int tid = threadIdx.x;
  int lane = tid & 63, w = tid >> 6;
  __shared__ __align__(16) float xi[DD];            // DD = 2324 = 581 float4s
  __shared__ float s_sc[K2];
  __shared__ int   s_js[K2];
  __shared__ float s_wts[K2+1];
  const float* ri = cur + (size_t)i*DD;
  for(int k=tid; k<DD; k+=256) xi[k] = ri[k]*Wa3[2*DD + k];
  if(tid < K2) s_js[tid] = ante[(size_t)i*K2 + tid];
  __syncthreads();
  const float ui = u[i], b0 = ba[0];
  const int D4 = DD/4;                              // 581 exactly
  const f32x4* xi4 = (const f32x4*)xi;
  for(int t=w; t<K2; t+=4){
    int j = s_js[t];
    const f32x4* rj4 = (const f32x4*)(cur + (size_t)j*DD);
    float s = 0.f;
    for(int k=lane; k<D4; k+=64){
      f32x4 a = xi4[k], b = rj4[k];
      s += a[0]*b[0] + a[1]*b[1] + a[2]*b[2] + a[3]*b[3];
    }
    #pragma unroll
    for(int off=32; off>0; off>>=1) s += __shfl_xor(s, off);
    if(lane==0){
      float val = tafast[(size_t)i*K2 + t] + ui + v[j] + s + b0;
      s_sc[t] = val;
      sc[(size_t)i*K2 + t] = val;                   // still consumed by final_loss
    }
  }
  __syncthreads();
  if(tid==0){
    float mx = 0.f;
    for(int t=0;t<K2;t++) mx = fmaxf(mx, s_sc[t]);
    float sum = expf(0.f - mx); s_wts[0] = sum;
    for(int t=0;t<K2;t++){ float e = expf(s_sc[t]-mx); s_wts[t+1]=e; sum += e; }
    float inv = 1.f/sum;
    for(int t=0;t<=K2;t++) s_wts[t] *= inv;
  }
  __syncthreads();
  for(int d=tid; d<DD; d+=256){
    float a = s_wts[0]*ri[d];
    for(int t=0;t<K2;t++) a += s_wts[t+1]*cur[(size_t)s_js[t]*DD + d];
    att[(size_t)i*DD + d] = a;
  }
}

// ---------------- bf16 conversion for the fused gate GEMM (SWIZZLED) --------
// Fused zeroing of nxt (the gg GEMM's atomic target, total = m*DD elems).
__global__ void conv_acat(const float* __restrict__ cur, const float* __restrict__ att,
                          unsigned short* __restrict__ A,
                          float* __restrict__ nxt, int total, int m){
  int idx = blockIdx.x*256 + threadIdx.x;
  if(idx >= MPAD*KAW) return;
  if(idx < total) nxt[idx] = 0.f;
  int row = idx / KAW, col = idx - row*KAW;
  float v = 0.f;
  if(row < m){
    if(col < DD) v = cur[(size_t)row*DD + col];
    else if(col >= KPAD && col < KPAD + DD) v = att[(size_t)row*DD + (col - KPAD)];
  }
  A[row*KAW + swz_col(row, col)] = f2bf(v);
}

// Bt_cat (NPAD x KAW): Bt[n][s*KPAD+k] = Wf[s*DD+k][n], zero-padded
__global__ void conv_wf(const float* __restrict__ Wf, unsigned short* __restrict__ Bt){
  int n  = blockIdx.y*64 + threadIdx.x;
  int k8 = blockIdx.x*8;
  int s  = (k8 >= KPAD) ? 1 : 0;
  int kk = k8 - s*KPAD;
  u16x8 v;
  #pragma unroll
  for(int j=0;j<8;j++){
    int k = kk + j;
    float f = (n < DD && k < DD) ? Wf[(size_t)(s*DD + k)*DD + n] : 0.f;
    v[j] = f2bf(f);
  }
  int k8s = swz_col(n, k8);
  *(u16x8*)(Bt + (size_t)n*KAW + k8s) = v;
}

// gate epilogue: nxt holds accumulated pre-activation; apply bias+sigmoid+update
__global__ void gate_update(const float* __restrict__ bfv, const float* __restrict__ att,
                            const float* __restrict__ cur, float* __restrict__ nxt, int total){
  int idx = blockIdx.x*256 + threadIdx.x;
  if(idx >= total) return;
  int col = idx % DD;
  float pre = nxt[idx] + bfv[col];
  float g = 1.f/(1.f + expf(-pre));
  nxt[idx] = g*att[idx] + (1.f - g)*cur[idx];
}

// ---------------- final scores + per-row loss -------------------------------
__global__ void final_loss(const float* __restrict__ sc, const int* __restrict__ ante,
                           const int* __restrict__ tclust, float* out_fs, float* row_loss, int m){
  int i = blockIdx.x*blockDim.x + threadIdx.x;
  if(i >= m) return;
  int tci = tclust[i];
  unsigned long long labm = 0ull;
  bool anyp = false;
  float mx = 0.f;
  float mg = -FLT_MAX;
  for(int t=0;t<K2;t++){
    float v = sc[(size_t)i*K2 + t];
    mx = fmaxf(mx, v);
    int j = ante[(size_t)i*K2 + t];
    bool mk = (j < i);
    int ac = mk ? tclust[j] : -1;
    bool p = (ac == tci) && (tci > 0);
    if(p){ labm |= (1ull << (t+1)); anyp = true; mg = fmaxf(mg, v); }
  }
  if(!anyp){ labm |= 1ull; mg = 0.f; }
  float s1 = expf(0.f - mx);
  float s2 = (labm & 1ull) ? expf(0.f - mg) : 0.f;
  float* o = out_fs + (size_t)i*(K2+1);
  o[0] = 0.f;
  for(int t=0;t<K2;t++){
    float v = sc[(size_t)i*K2 + t];
    o[t+1] = v;
    s1 += expf(v - mx);
    if(labm & (1ull << (t+1))) s2 += expf(v - mg);
  }
  row_loss[i] = (mx + logf(s1)) - (mg + logf(s2));
}

__global__ void loss_sum(const float* __restrict__ row_loss, float* out, int m){
  int tid = threadIdx.x;
  float s = 0.f;
  for(int i=tid; i<m; i+=256) s += row_loss[i];
  __shared__ float red[256];
  red[tid]=s; __syncthreads();
  for(int st=128; st>0; st>>=1){ if(tid<st) red[tid]+=red[tid+st]; __syncthreads(); }
  if(tid==0) out[0] = red[0];
}

// ---------------------------------------------------------------------------
extern "C" void kernel_launch(void* const* d_in, const int* in_sizes, int n_in,
                              void* d_out, int out_size, void* d_ws, size_t ws_size,
                              hipStream_t stream){
  const int W = in_sizes[11];
  const int G = in_sizes[12];
  const int C = W * MSW;
  const int m = (int)(0.4 * (double)W);

  const float* seq   = (const float*)d_in[0];
  const float* Wal   = (const float*)d_in[1];
  const float* bal   = (const float*)d_in[2];
  const float* Wm    = (const float*)d_in[3];
  const float* bm    = (const float*)d_in[4];
  const float* Wc    = (const float*)d_in[5];
  const float* WaA   = (const float*)d_in[6];
  const float* baA   = (const float*)d_in[7];
  const float* Wf    = (const float*)d_in[8];
  const float* bf    = (const float*)d_in[9];
  const float* wfeat = (const float*)d_in[10];
  const int*   smap  = (const int*)d_in[11];
  const int*   gs    = (const int*)d_in[12];
  const int*   ge    = (const int*)d_in[13];
  const int*   cid   = (const int*)d_in[14];
  float* out = (float*)d_out;

  // workspace layout (phase-aliased; peak ~59 MB, proven safe <65 MB)
  char* ws = (char*)d_ws;
  size_t off = 0;
  auto alloc = [&](size_t bytes)->char*{
    char* p = ws + off;
    off += (bytes + 255) & ~(size_t)255;
    return p;
  };
  const size_t PLANE  = (size_t)MPAD*KPAD*2;   // 4.36 MB
  const size_t WPLANE = (size_t)NPAD*KPAD*2;   // 11.83 MB

  float* alphas  = (float*)alloc((size_t)W*4);
  float* p1      = (float*)alloc((size_t)W*4);
  float* p2      = (float*)alloc((size_t)W*4);
  float* p3      = (float*)alloc((size_t)W*4);
  float* mscore  = (float*)alloc((size_t)C*4);
  float* mmask   = (float*)alloc((size_t)C*4);
  int*   ccl     = (int*)  alloc((size_t)C*4);
  int*   top_idx = (int*)  alloc((size_t)m*4);
  float* tscore  = (float*)alloc((size_t)m*4);
  int*   tclust  = (int*)  alloc((size_t)m*4);
  float* B1      = (float*)alloc((size_t)m*DD*4);  // top_rep / reps ping
  float* B2      = (float*)alloc((size_t)m*DD*4);  // tmp / reps pong
  float* B3      = (float*)alloc((size_t)m*DD*4);  // attended
  float* bilin   = (float*)alloc((size_t)m*m*4);   // bilin (fast scores)
  int*   ante    = (int*)  alloc((size_t)m*K2*4);
  float* tafast  = (float*)alloc((size_t)m*K2*4);
  float* uB      = (float*)alloc((size_t)m*4);
  float* vB      = (float*)alloc((size_t)m*4);
  float* scB     = (float*)alloc((size_t)m*K2*4);
  float* rloss   = (float*)alloc((size_t)m*4);
  // regionA (2*PLANE), phase-aliased:
  //   bilinear: RepH | RepL      gate: Acat (spans both)
  char* regionA = alloc(2*PLANE);
  unsigned short* RepH  = (unsigned short*)regionA;
  unsigned short* RepL  = (unsigned short*)(regionA + PLANE);
  unsigned short* Acat  = (unsigned short*)regionA;            // MPAD*KAW*2 == 2*PLANE
  // regionB (2*WPLANE), phase-aliased:
  //   gemm1: WtH | WtL   ->  gemm2: A2H | A2L (after gemm1 done)  ->  depth: BtWf
  char* regionB = alloc(2*WPLANE);
  unsigned short* WtH  = (unsigned short*)regionB;
  unsigned short* WtL  = (unsigned short*)(regionB + WPLANE);
  unsigned short* A2H  = (unsigned short*)regionB;
  unsigned short* A2L  = (unsigned short*)(regionB + PLANE);
  unsigned short* BtWf = (unsigned short*)regionB;             // NPAD*KAW*2 == 2*WPLANE

  // output offsets (all float32)
  float* out_ts   = out;
  float* out_te   = out + m;
  float* out_ante = out + 2*m;
  float* out_fs   = out + 2*m + (size_t)m*K2;
  float* out_loss = out + 2*m + (size_t)m*K2 + (size_t)m*(K2+1);

  // 1) per-token projections
  row_proj<<<W, 256, 0, stream>>>(seq, Wal, bal, Wm, alphas, p1, p2, p3, W);
  // 2) candidate mention scores
  mention_kernel<<<(C+255)/256, 256, 0, stream>>>(alphas, p1, p2, p3, wfeat, Wm, bm,
                                                  smap, gs, ge, cid, G,
                                                  mscore, mmask, ccl, W);
  // 3) exact top-m selection + compaction
  select_kernel<<<1, 1024, 0, stream>>>(mmask, mscore, ccl, m, C, W,
                                        top_idx, tscore, tclust, out_ts, out_te);
  // 4) build top_rep into B1
  build_rep<<<m, 256, 0, stream>>>(seq, alphas, wfeat, top_idx, B1, W);
  // 5) bilinear antecedent scores via split-bf16 3-term MFMA (split-K, atomic)
  {
    const int NEL = MPAD*KPAD;
    // conv_split also zeroes B2 (g1's atomic target)
    conv_split<<<(NEL+255)/256, 256, 0, stream>>>(B1, m, DD, RepH, RepL, B2, m*DD);
    dim3 gw(KPAD/8, NPAD/64);
    conv_split_wcT<<<gw, 64, 0, stream>>>(Wc, WtH, WtL);
    dim3 g1(NPAD/128, MPAD/128, 3);     // (19, 7, 3) = 399 blocks <= 512: no tail wave
    gemm_split3_sk<<<g1, 256, 0, stream>>>(RepH, RepL, WtH, WtL, B2, m, DD, DD);
    // conv_split also zeroes bilin (g2's atomic target)
    conv_split<<<(NEL+255)/256, 256, 0, stream>>>(B2, m, DD, A2H, A2L, bilin, m*m);
    dim3 g2(MPAD/128, MPAD/128, 10);    // (7, 7, 10) = 490 blocks <= 512
    gemm_split3_sk<<<g2, 256, 0, stream>>>(A2H, A2L, RepH, RepL, bilin, m, m, m);
  }
  // 6) per-row top-50 (1 wave per row, register-resident)
  topante_kernel<<<m, 64, 0, stream>>>(tscore, bilin, m, ante, tafast, out_ante);
  // gate weights -> bf16 transposed (AFTER bilinear GEMMs: regionB alias)
  {
    dim3 g(KAW/8, NPAD/64);
    conv_wf<<<g, 64, 0, stream>>>(Wf, BtWf);
  }

  // 7) DEPTH=2 refinement (fused gathered slow scores + attend, then gate GEMM)
  float* cur = B1; float* nxt = B2;
  const int total = m * DD;
  for(int depth=0; depth<2; depth++){
    uv_kernel<<<m, 256, 0, stream>>>(cur, WaA, uB, vB, m);
    // R11: fused slow scores + softmax + attend (replaces slow_scores + attend_kernel)
    slow_attend<<<m, 256, 0, stream>>>(cur, WaA, uB, vB, ante, tafast, baA, scB, B3, m);
    // gate pre-activation accumulates into zeroed nxt; conv_acat zeroes nxt
    conv_acat<<<(MPAD*KAW+255)/256, 256, 0, stream>>>(cur, B3, Acat, nxt, total, m);
    dim3 gg(NPAD/128, MPAD/128, 3);     // (19, 7, 3) = 399 blocks <= 512: no tail wave
    gemm_bf16_m97<<<gg, 256, 0, stream>>>(Acat, BtWf, nxt, m, DD, DD, KAW, KAW/64);
    gate_update<<<(total+255)/256, 256, 0, stream>>>(bf, B3, cur, nxt, total);
    float* t = cur; cur = nxt; nxt = t;
  }

  // 8) final scores + loss
  final_loss<<<(m+255)/256, 256, 0, stream>>>(scB, ante, tclust, out_fs, rloss, m);
  loss_sum<<<1, 256, 0, stream>>>(rloss, out_loss, m);
}

// Round 12
// 718.219 us; speedup vs baseline: 1.2001x; 1.0916x over previous
//
#include <hip/hip_runtime.h>
#include <cfloat>
#include <climits>
#include <math.h>

#define HD   768
#define MSW  10
#define WFK  20
#define DD   2324    // 3*768+20
#define K2   50
#define NEGF (-1e30f)

// MFMA geometry (K padded to mult of 128 for deep-K tiles)
#define KPAD 2432          // 19*128, >= DD
#define KAW  4864          // 2*KPAD  (K-concat of [cur | att] for the gate GEMM)
#define MPAD 896           // 7 * 128 (>= m=819)
#define NPAD 2432          // 19 * 128 (>= DD)

typedef __attribute__((ext_vector_type(8))) short    s8b;
typedef __attribute__((ext_vector_type(8))) unsigned short u16x8;
typedef __attribute__((ext_vector_type(4))) float    f32x4;

__device__ inline unsigned short f2bf(float f){
  unsigned u = __float_as_uint(f);
  unsigned r = (u + 0x7FFFu + ((u >> 16) & 1u)) >> 16;   // RNE
  return (unsigned short)r;
}
__device__ inline float bf2f(unsigned short h){
  return __uint_as_float(((unsigned)h) << 16);
}

// async global->LDS, 16B per lane; LDS dest must be wave-uniform base (+lane*16 implicit)
__device__ __forceinline__ void gload16(const unsigned short* g, void* l){
  __builtin_amdgcn_global_load_lds(
      (const __attribute__((address_space(1))) void*)g,
      (__attribute__((address_space(3))) void*)l, 16, 0, 0);
}

// ---- bank-conflict swizzle (both-sides involution, rule #21) ----------------
// Verified R2: SQ_LDS_BANK_CONFLICT 7.76M -> 0.
__device__ __forceinline__ int swz_col(int row, int col){
  return col ^ ((row & 7) << 3);
}

// ---- T1: XCD-aware bijective block remap (m204 form) ------------------------
// Verified R7: g1 64.4 -> ~58us, frame -30us. Pure index permutation.
__device__ __forceinline__ void xcd_remap(int &bx, int &by, int &bz){
  int nwg  = (int)(gridDim.x*gridDim.y*gridDim.z);
  int orig = (int)(blockIdx.x + gridDim.x*(blockIdx.y + gridDim.y*blockIdx.z));
  int q = nwg >> 3, r = nwg & 7;
  int x8 = orig & 7, o8 = orig >> 3;
  int wg = (x8 < r ? x8*(q+1) : r*(q+1) + (x8-r)*q) + o8;
  bx = wg % (int)gridDim.x;
  int tmp = wg / (int)gridDim.x;
  by = tmp % (int)gridDim.y;
  bz = tmp / (int)gridDim.y;
}

// ---------------- per-token projections: alphas, p1,p2,p3 -------------------
__global__ void row_proj(const float* __restrict__ seq, const float* __restrict__ Wa,
                         const float* __restrict__ ba, const float* __restrict__ Wm,
                         float* alphas, float* p1, float* p2, float* p3, int W){
  int w = blockIdx.x; int tid = threadIdx.x;
  const float* row = seq + (size_t)w * HD;
  float s0=0.f, s1=0.f, s2=0.f, s3=0.f;
  for(int h=tid; h<HD; h+=256){
    float x = row[h];
    s0 += x * Wa[h];
    s1 += x * Wm[h];
    s2 += x * Wm[HD + h];
    s3 += x * Wm[2*HD + h];
  }
  __shared__ float r0[256], r1[256], r2[256], r3[256];
  r0[tid]=s0; r1[tid]=s1; r2[tid]=s2; r3[tid]=s3;
  __syncthreads();
  for(int st=128; st>0; st>>=1){
    if(tid<st){ r0[tid]+=r0[tid+st]; r1[tid]+=r1[tid+st]; r2[tid]+=r2[tid+st]; r3[tid]+=r3[tid+st]; }
    __syncthreads();
  }
  if(tid==0){ alphas[w]=r0[0]+ba[0]; p1[w]=r1[0]; p2[w]=r2[0]; p3[w]=r3[0]; }
}

// ---------------- mention scoring per candidate -----------------------------
__global__ void mention_kernel(const float* __restrict__ alphas, const float* __restrict__ p1,
                               const float* __restrict__ p2, const float* __restrict__ p3,
                               const float* __restrict__ wfeat, const float* __restrict__ Wm,
                               const float* __restrict__ bm,
                               const int* __restrict__ smap, const int* __restrict__ gs,
                               const int* __restrict__ ge, const int* __restrict__ cid, int G,
                               float* mscore, float* mmask, int* ccl, int W){
  int c = blockIdx.x*blockDim.x + threadIdx.x;
  int C = W * MSW;
  if(c >= C) return;
  int s = c / MSW, r = c - s*MSW;
  int e = s + r; int ec = min(e, W-1);
  int L = ec - s;
  bool valid = (e < W) && (smap[s] == smap[ec]);
  float maxa = -FLT_MAX;
  for(int j=0;j<=L;j++) maxa = fmaxf(maxa, alphas[s+j]);
  float sum=0.f, sdot=0.f;
  for(int j=0;j<=L;j++){ float ee = expf(alphas[s+j]-maxa); sum += ee; sdot += ee*p3[s+j]; }
  sdot /= sum;
  float wp=0.f;
  for(int f=0; f<WFK; f++) wp += wfeat[L*WFK+f] * Wm[3*HD+f];
  float ms = p1[s] + p2[ec] + sdot + wp + bm[0];
  mscore[c] = ms;
  mmask[c]  = valid ? ms : NEGF;
  int cc = 0;
  for(int g=0; g<G; g++) if(s==gs[g] && ec==ge[g]) cc += cid[g];
  ccl[c] = cc;
}

// ---------------- single-block exact top-m radix select ---------------------
__device__ inline unsigned fkey(float f){
  unsigned b = __float_as_uint(f);
  return (b & 0x80000000u) ? ~b : (b | 0x80000000u);
}

__global__ __launch_bounds__(1024)
void select_kernel(const float* __restrict__ mmask, const float* __restrict__ mscore,
                   const int* __restrict__ ccl, int m, int C, int W,
                   int* top_idx, float* tscore, int* tclust,
                   float* out_ts, float* out_te){
  const int T = 1024;
  int tid = threadIdx.x;
  int chunk = (C + T - 1)/T;
  int lo = tid*chunk, hi = min(lo+chunk, C);
  int n = hi - lo; if(n < 0) n = 0;
  unsigned kb[32];
  for(int t=0;t<n;t++) kb[t] = fkey(mmask[lo+t]);

  __shared__ unsigned s_hist[256];
  __shared__ unsigned s_scan[1024];
  __shared__ unsigned s_pref;
  __shared__ int s_rem;
  if(tid==0){ s_pref=0u; s_rem=m; }
  __syncthreads();

  for(int b=3;b>=0;b--){
    if(tid<256) s_hist[tid]=0u;
    __syncthreads();
    unsigned pref = s_pref;
    unsigned msk = (b==3)?0u:(0xFFFFFFFFu << ((b+1)*8));
    for(int t=0;t<n;t++){
      unsigned u = kb[t];
      if((u & msk)==pref) atomicAdd(&s_hist[(u>>(b*8))&0xFFu], 1u);
    }
    __syncthreads();
    if(tid==0){
      int rem = s_rem; unsigned acc=0u; int bin;
      for(bin=255;bin>=1;bin--){
        unsigned h = s_hist[bin];
        if(acc + h >= (unsigned)rem) break;
        acc += h;
      }
      if(bin < 0) bin = 0;
      s_pref = pref | ((unsigned)bin << (b*8));
      s_rem = rem - (int)acc;
    }
    __syncthreads();
  }
  unsigned Tk = s_pref;
  int need = s_rem;

  unsigned nG=0, nE=0;
  for(int t=0;t<n;t++){ unsigned u=kb[t]; nG += (u>Tk)?1u:0u; nE += (u==Tk)?1u:0u; }

  s_scan[tid]=nE; __syncthreads();
  for(int off=1; off<T; off<<=1){
    unsigned x = (tid>=off)? s_scan[tid-off]:0u; __syncthreads();
    s_scan[tid]+=x; __syncthreads();
  }
  unsigned eqBase = s_scan[tid]-nE;
  __syncthreads();

  int takeLeft = need - (int)eqBase;
  int take = takeLeft<0?0:(takeLeft>(int)nE?(int)nE:takeLeft);
  unsigned selCnt = nG + (unsigned)take;

  s_scan[tid]=selCnt; __syncthreads();
  for(int off=1; off<T; off<<=1){
    unsigned x = (tid>=off)? s_scan[tid-off]:0u; __syncthreads();
    s_scan[tid]+=x; __syncthreads();
  }
  unsigned posBase = s_scan[tid]-selCnt;

  int pos = (int)posBase; int eq = (int)eqBase;
  for(int t=0;t<n;t++){
    unsigned u = kb[t];
    bool sel = false;
    if(u>Tk) sel=true;
    else if(u==Tk){ if(eq<need) sel=true; eq++; }
    if(sel){
      int c = lo+t;
      top_idx[pos] = c;
      int s = c/MSW, r = c - s*MSW; int e = min(s + r, W-1);
      tscore[pos] = mscore[c];
      tclust[pos] = ccl[c];
      out_ts[pos] = (float)s;
      out_te[pos] = (float)e;
      pos++;
    }
  }
}

// ---------------- build top_rep (m x D) -------------------------------------
__global__ void build_rep(const float* __restrict__ seq, const float* __restrict__ alphas,
                          const float* __restrict__ wfeat, const int* __restrict__ top_idx,
                          float* rep, int W){
  int i = blockIdx.x; int tid = threadIdx.x;
  int c = top_idx[i];
  int s = c/MSW, r = c - s*MSW; int ec = min(s + r, W-1); int L = ec - s;
  float wv[MSW];
  float maxa = -FLT_MAX;
  for(int j=0;j<=L;j++) maxa = fmaxf(maxa, alphas[s+j]);
  float sum = 0.f;
  for(int j=0;j<=L;j++){ wv[j] = expf(alphas[s+j]-maxa); sum += wv[j]; }
  float inv = 1.f/sum;
  float* o = rep + (size_t)i*DD;
  for(int d=tid; d<HD; d+=256){
    o[d]      = seq[(size_t)s*HD + d];
    o[HD+d]   = seq[(size_t)ec*HD + d];
    float sp = 0.f;
    for(int j=0;j<=L;j++) sp += wv[j]*seq[(size_t)(s+j)*HD + d];
    o[2*HD+d] = sp*inv;
  }
  for(int f=tid; f<WFK; f+=256) o[3*HD+f] = wfeat[L*WFK+f];
}

// ---------------- split-bf16 conversions (SWIZZLED output layout) -----------
// Fused zeroing of the next GEMM's accumulation target (ztgt[0..zn)).
__global__ void conv_split(const float* __restrict__ src, int rows, int cols,
                           unsigned short* __restrict__ hi, unsigned short* __restrict__ lo,
                           float* __restrict__ ztgt, int zn){
  int idx = blockIdx.x*256 + threadIdx.x;
  if(idx >= MPAD*KPAD) return;
  if(idx < zn) ztgt[idx] = 0.f;
  int row = idx / KPAD, col = idx - row*KPAD;
  float v = (row < rows && col < cols) ? src[(size_t)row*cols + col] : 0.f;
  unsigned short h = f2bf(v);
  int w = row*KPAD + swz_col(row, col);
  hi[w] = h;
  lo[w] = f2bf(v - bf2f(h));
}

// Wc (DD x DD) -> transposed hi/lo planes (NPAD x KPAD): Wt[n][k] = Wc[k][n]
__global__ void conv_split_wcT(const float* __restrict__ Wc,
                               unsigned short* __restrict__ WtH, unsigned short* __restrict__ WtL){
  int n  = blockIdx.y*64 + threadIdx.x;
  int k8 = blockIdx.x*8;
  u16x8 vh, vl;
  #pragma unroll
  for(int j=0;j<8;j++){
    int k = k8 + j;
    float f = (n < DD && k < DD) ? Wc[(size_t)k*DD + n] : 0.f;
    unsigned short h = f2bf(f);
    vh[j] = h;
    vl[j] = f2bf(f - bf2f(h));
  }
  int k8s = swz_col(n, k8);          // XOR hits bits 3-5 only; 16B granularity
  *(u16x8*)(WtH + (size_t)n*KPAD + k8s) = vh;
  *(u16x8*)(WtL + (size_t)n*KPAD + k8s) = vl;
}

// ---------------- split-bf16 3-term MFMA GEMM, split-K ----------------------
// R5-measured-best structure + R7 T1 remap: single-buffered linear LDS via
// global_load_lds, 2 barriers per BK=64 step. LDS = 4 planes x 16 KiB = 64 KiB
// -> 2 blocks/CU. Swizzled reads (conflicts = 0). Grid <= 512 blocks.
__global__ __launch_bounds__(256,2)
void gemm_split3_sk(const unsigned short* __restrict__ Ah, const unsigned short* __restrict__ Al,
                    const unsigned short* __restrict__ Bth, const unsigned short* __restrict__ Btl,
                    float* __restrict__ C, int M, int N, int ldc){
  __shared__ __align__(16) unsigned short sAh[128*64];
  __shared__ __align__(16) unsigned short sAl[128*64];
  __shared__ __align__(16) unsigned short sBh[128*64];
  __shared__ __align__(16) unsigned short sBl[128*64];
  int bx, by, bz; xcd_remap(bx, by, bz);
  int t = threadIdx.x;
  int row0 = by*128, col0 = bx*128;
  const int tiles = KPAD/64;                              // 38
  int per = (tiles + (int)gridDim.z - 1)/(int)gridDim.z;
  int tb = min(bz*per, tiles), te = min(tb + per, tiles);
  if(tb >= te) return;
  int lane = t&63, w = t>>6;
  int wr = (w>>1)*64, wc = (w&1)*64;
  int quad = lane>>4, l15 = lane&15;
  int seg = lane&7;
  size_t ro = (size_t)(w*8 + (lane>>3));                  // staging row within 32-row group
  const unsigned short* gAh = Ah  + ((size_t)row0 + ro)*KPAD + seg*8;
  const unsigned short* gAl = Al  + ((size_t)row0 + ro)*KPAD + seg*8;
  const unsigned short* gBh = Bth + ((size_t)col0 + ro)*KPAD + seg*8;
  const unsigned short* gBl = Btl + ((size_t)col0 + ro)*KPAD + seg*8;
  const int lds0 = (w*8)*64;                              // wave-uniform LDS base (shorts)
  // swizzled read chunk offsets (shorts): ks=0 -> c0, ks=1 -> c0^32
  const int c0 = ((quad ^ (l15 & 7)) << 3);

  f32x4 acc[4][4];
  #pragma unroll
  for(int mi=0;mi<4;mi++)
    #pragma unroll
    for(int ni=0;ni<4;ni++) acc[mi][ni] = (f32x4){0.f,0.f,0.f,0.f};

  for(int kt=tb; kt<te; ++kt){
    size_t k0 = (size_t)kt*64;
    #pragma unroll
    for(int r=0;r<4;r++){
      size_t go = (size_t)(r*32)*KPAD + k0;
      int lo = lds0 + r*32*64;
      gload16(gAh + go, sAh + lo);
      gload16(gAl + go, sAl + lo);
      gload16(gBh + go, sBh + lo);
      gload16(gBl + go, sBl + lo);
    }
    __syncthreads();   // drains vmcnt(0): tile landed in LDS
    #pragma unroll
    for(int ks=0;ks<2;ks++){
      const int co = c0 ^ (ks<<5);
      s8b fah[4], fal[4], fbh[4], fbl[4];
      #pragma unroll
      for(int mi=0;mi<4;mi++){
        int ra = (wr+mi*16+l15)*64 + co;
        fah[mi] = *(const s8b*)&sAh[ra];
        fal[mi] = *(const s8b*)&sAl[ra];
      }
      #pragma unroll
      for(int ni=0;ni<4;ni++){
        int rb = (wc+ni*16+l15)*64 + co;
        fbh[ni] = *(const s8b*)&sBh[rb];
        fbl[ni] = *(const s8b*)&sBl[rb];
      }
      #pragma unroll
      for(int mi=0;mi<4;mi++)
        #pragma unroll
        for(int ni=0;ni<4;ni++){
          acc[mi][ni] = __builtin_amdgcn_mfma_f32_16x16x32_bf16(fah[mi], fbh[ni], acc[mi][ni], 0,0,0);
          acc[mi][ni] = __builtin_amdgcn_mfma_f32_16x16x32_bf16(fah[mi], fbl[ni], acc[mi][ni], 0,0,0);
          acc[mi][ni] = __builtin_amdgcn_mfma_f32_16x16x32_bf16(fal[mi], fbh[ni], acc[mi][ni], 0,0,0);
        }
    }
    __syncthreads();   // all waves done reading before next stage overwrites
  }

  #pragma unroll
  for(int ni=0;ni<4;ni++){
    int gn = col0 + wc + ni*16 + l15;
    if(gn >= N) continue;
    #pragma unroll
    for(int mi=0;mi<4;mi++){
      #pragma unroll
      for(int rg=0;rg<4;rg++){
        int gr = row0 + wr + mi*16 + quad*4 + rg;
        if(gr >= M) continue;
        atomicAdd(&C[(size_t)gr*ldc + gn], acc[mi][ni][rg]);
      }
    }
  }
}

// ---------------- plain bf16 MFMA GEMM, split-K (2-phase dbuf, BK=64) -------
// R7-proven config (58.7us @ gg). Used only for the gate GEMM (ldk=KAW).
__global__ __launch_bounds__(256,2)
void gemm_bf16_m97(const unsigned short* __restrict__ A, const unsigned short* __restrict__ Bt,
                   float* __restrict__ C, int M, int N, int ldc, int ldk, int tiles){
  __shared__ __align__(16) unsigned short sA[2][128*64];
  __shared__ __align__(16) unsigned short sB[2][128*64];
  int bx, by, bz; xcd_remap(bx, by, bz);
  int t = threadIdx.x;
  int row0 = by*128, col0 = bx*128;
  int per = (tiles + (int)gridDim.z - 1)/(int)gridDim.z;
  int tb = min(bz*per, tiles), te = min(tb + per, tiles);
  if(tb >= te) return;
  int lane = t&63, w = t>>6;
  int wr = (w>>1)*64, wc = (w&1)*64;
  int quad = lane>>4, l15 = lane&15;
  int seg = lane&7;
  size_t ro = (size_t)(w*8 + (lane>>3));
  const unsigned short* gA = A  + ((size_t)row0 + ro)*ldk + seg*8;
  const unsigned short* gB = Bt + ((size_t)col0 + ro)*ldk + seg*8;
  const int lds0 = (w*8)*64;
  const int c0 = ((quad ^ (l15 & 7)) << 3);

  f32x4 acc[4][4];
  #pragma unroll
  for(int mi=0;mi<4;mi++)
    #pragma unroll
    for(int ni=0;ni<4;ni++) acc[mi][ni] = (f32x4){0.f,0.f,0.f,0.f};

  auto STAGE = [&](int b, int kt){
    size_t k0 = (size_t)kt*64;
    #pragma unroll
    for(int r=0;r<4;r++){
      size_t go = (size_t)(r*32)*ldk + k0;
      int lo = lds0 + r*32*64;
      gload16(gA + go, &sA[b][lo]);
      gload16(gB + go, &sB[b][lo]);
    }
  };

  STAGE(0, tb);
  __syncthreads();
  int buf = 0;
  for(int kt=tb; kt<te; ++kt){
    if(kt+1 < te) STAGE(buf^1, kt+1);
    #pragma unroll
    for(int ks=0;ks<2;ks++){
      const int co = c0 ^ (ks<<5);
      s8b fa[4], fb[4];
      #pragma unroll
      for(int mi=0;mi<4;mi++) fa[mi] = *(const s8b*)&sA[buf][(wr+mi*16+l15)*64 + co];
      #pragma unroll
      for(int ni=0;ni<4;ni++) fb[ni] = *(const s8b*)&sB[buf][(wc+ni*16+l15)*64 + co];
      #pragma unroll
      for(int mi=0;mi<4;mi++)
        #pragma unroll
        for(int ni=0;ni<4;ni++)
          acc[mi][ni] = __builtin_amdgcn_mfma_f32_16x16x32_bf16(fa[mi], fb[ni], acc[mi][ni], 0,0,0);
    }
    __syncthreads();
    buf ^= 1;
  }

  #pragma unroll
  for(int ni=0;ni<4;ni++){
    int gn = col0 + wc + ni*16 + l15;
    if(gn >= N) continue;
    #pragma unroll
    for(int mi=0;mi<4;mi++){
      #pragma unroll
      for(int rg=0;rg<4;rg++){
        int gr = row0 + wr + mi*16 + quad*4 + rg;
        if(gr >= M) continue;
        atomicAdd(&C[(size_t)gr*ldc + gn], acc[mi][ni][rg]);
      }
    }
  }
}

// ---------------- per-row top-50 antecedents (1 wave / row) -----------------
// Register-resident selection (R5-verified: bit-identical, ~10x faster than LDS).
#define NT 13   // ceil(m/64) for m<=832
__global__ void topante_kernel(const float* __restrict__ tscore, const float* __restrict__ bilin,
                               int m, int* ante, float* tafast, float* out_ante){
  int i = blockIdx.x; int lane = threadIdx.x;
  float tsi = tscore[i];
  float v[NT];
  #pragma unroll
  for(int t=0;t<NT;t++){
    int j = lane + t*64;
    float f = -FLT_MAX;
    if(j < m){
      f = tsi + tscore[j];
      f += (j < i) ? 0.f : NEGF;
      f += bilin[(size_t)i*m + j];
    }
    v[t] = f;
  }
  unsigned consumed = 0u;
  int r_ante = 0; float r_fast = 0.f;
  for(int it=0; it<K2; ++it){
    float lv = -FLT_MAX; int li = m;
    #pragma unroll
    for(int t=0;t<NT;t++){
      bool live = ((consumed >> t) & 1u) == 0u;
      if(live && v[t] > lv){ lv = v[t]; li = lane + t*64; }
    }
    float bv = lv; int bi = li;
    #pragma unroll
    for(int off=32; off>0; off>>=1){
      float ov = __shfl_xor(bv, off);
      int   oi = __shfl_xor(bi, off);
      if(ov > bv || (ov == bv && oi < bi)){ bv = ov; bi = oi; }
    }
    if(bi < m && (bi & 63) == lane) consumed |= (1u << (bi >> 6));
    if(lane == it){ r_ante = bi; r_fast = bv; }
  }
  if(lane < K2){
    ante[(size_t)i*K2 + lane]   = r_ante;
    tafast[(size_t)i*K2 + lane] = r_fast;
    out_ante[(size_t)i*K2+lane] = (float)r_ante;
  }
}

// ---------------- depth loop pieces -----------------------------------------
__global__ void uv_kernel(const float* __restrict__ reps, const float* __restrict__ Wa3,
                          float* u, float* v, int m){
  int i = blockIdx.x; int tid = threadIdx.x;
  const float* rp = reps + (size_t)i*DD;
  float s1=0.f, s2=0.f;
  for(int d=tid; d<DD; d+=256){ float x = rp[d]; s1 += x*Wa3[d]; s2 += x*Wa3[DD+d]; }
  __shared__ float r1[256], r2[256];
  r1[tid]=s1; r2[tid]=s2; __syncthreads();
  for(int st=128; st>0; st>>=1){
    if(tid<st){ r1[tid]+=r1[tid+st]; r2[tid]+=r2[tid+st]; }
    __syncthreads();
  }
  if(tid==0){ u[i]=r1[0]; v[i]=r2[0]; }
}

// ---------------- R12: gathered slow scores, oversubscribed grid ------------
// grid (5, m): block (tq, i) stages xi = ri*w3 once in LDS; its 4 waves cover
// t in [tq*10, tq*10+10). Math identical to R10's verified slow_scores.
// 4095 blocks x 4 waves = 16.4k waves -> latency hidden (R11's 819-block
// fused form capped occupancy at 40% by grid size).
__global__ __launch_bounds__(256)
void slow_dots(const float* __restrict__ cur, const float* __restrict__ Wa3,
               const float* __restrict__ u, const float* __restrict__ v,
               const int* __restrict__ ante, const float* __restrict__ tafast,
               const float* __restrict__ ba, float* __restrict__ sc, int m){
  int i  = blockIdx.y;
  int tq = blockIdx.x;                              // 0..4
  int tid = threadIdx.x;
  int lane = tid & 63, w = tid >> 6;
  __shared__ __align__(16) float xi[DD];            // DD = 2324 = 581 float4s
  const float* ri = cur + (size_t)i*DD;
  for(int k=tid; k<DD; k+=256) xi[k] = ri[k]*Wa3[2*DD + k];
  __syncthreads();
  const float ui = u[i], b0 = ba[0];
  const int D4 = DD/4;                              // 581 exactly
  const f32x4* xi4 = (const f32x4*)xi;
  int t0 = tq*10;
  for(int t=t0+w; t<t0+10; t+=4){
    int j = ante[(size_t)i*K2 + t];
    const f32x4* rj4 = (const f32x4*)(cur + (size_t)j*DD);
    float s = 0.f;
    for(int k=lane; k<D4; k+=64){
      f32x4 a = xi4[k], b = rj4[k];
      s += a[0]*b[0] + a[1]*b[1] + a[2]*b[2] + a[3]*b[3];
    }
    #pragma unroll
    for(int off=32; off>0; off>>=1) s += __shfl_xor(s, off);
    if(lane==0)
      sc[(size_t)i*K2 + t] = tafast[(size_t)i*K2 + t] + ui + v[j] + s + b0;
  }
}

// ---------------- R12: attend, d-split grid ---------------------------------
// grid (4, m): block (ch, i) recomputes the 51-way softmax from sc (serial
// form identical to the R10 attend_kernel -> bitwise-same weights in all 4
// blocks of a row), then accumulates only its 146-float4 d-chunk over the 50
// gathered rows. 3276 blocks -> full occupancy (vs 40% cap at 819 blocks).
__global__ __launch_bounds__(256)
void attend_d(const float* __restrict__ cur, const float* __restrict__ sc,
              const int* __restrict__ ante, float* __restrict__ att, int m){
  int i  = blockIdx.y;
  int ch = blockIdx.x;                              // 0..3
  int tid = threadIdx.x;
  __shared__ float wts[K2+1];
  __shared__ float scs[K2];
  __shared__ int   js[K2];
  if(tid < K2){ scs[tid] = sc[(size_t)i*K2 + tid]; js[tid] = ante[(size_t)i*K2 + tid]; }
  __syncthreads();
  if(tid==0){
    float mx = 0.f;
    for(int t=0;t<K2;t++) mx = fmaxf(mx, scs[t]);
    float sum = expf(0.f - mx); wts[0] = sum;
    for(int t=0;t<K2;t++){ float e = expf(scs[t]-mx); wts[t+1]=e; sum += e; }
    float inv = 1.f/sum;
    for(int t=0;t<=K2;t++) wts[t] *= inv;
  }
  __syncthreads();
  const int D4 = DD/4;                              // 581
  const int C4 = 146;                               // ceil(581/4)
  int d4 = ch*C4 + tid;
  if(tid < C4 && d4 < D4){
    const f32x4* ri4 = (const f32x4*)(cur + (size_t)i*DD);
    f32x4 a = ri4[d4];
    float w0 = wts[0];
    a[0]*=w0; a[1]*=w0; a[2]*=w0; a[3]*=w0;
    for(int t=0;t<K2;t++){
      const f32x4* rj4 = (const f32x4*)(cur + (size_t)js[t]*DD);
      f32x4 b = rj4[d4];
      float wt = wts[t+1];
      a[0]+=wt*b[0]; a[1]+=wt*b[1]; a[2]+=wt*b[2]; a[3]+=wt*b[3];
    }
    ((f32x4*)(att + (size_t)i*DD))[d4] = a;
  }
}

// ---------------- bf16 conversion for the fused gate GEMM (SWIZZLED) --------
// Fused zeroing of nxt (the gg GEMM's atomic target, total = m*DD elems).
__global__ void conv_acat(const float* __restrict__ cur, const float* __restrict__ att,
                          unsigned short* __restrict__ A,
                          float* __restrict__ nxt, int total, int m){
  int idx = blockIdx.x*256 + threadIdx.x;
  if(idx >= MPAD*KAW) return;
  if(idx < total) nxt[idx] = 0.f;
  int row = idx / KAW, col = idx - row*KAW;
  float v = 0.f;
  if(row < m){
    if(col < DD) v = cur[(size_t)row*DD + col];
    else if(col >= KPAD && col < KPAD + DD) v = att[(size_t)row*DD + (col - KPAD)];
  }
  A[row*KAW + swz_col(row, col)] = f2bf(v);
}

// Bt_cat (NPAD x KAW): Bt[n][s*KPAD+k] = Wf[s*DD+k][n], zero-padded
__global__ void conv_wf(const float* __restrict__ Wf, unsigned short* __restrict__ Bt){
  int n  = blockIdx.y*64 + threadIdx.x;
  int k8 = blockIdx.x*8;
  int s  = (k8 >= KPAD) ? 1 : 0;
  int kk = k8 - s*KPAD;
  u16x8 v;
  #pragma unroll
  for(int j=0;j<8;j++){
    int k = kk + j;
    float f = (n < DD && k < DD) ? Wf[(size_t)(s*DD + k)*DD + n] : 0.f;
    v[j] = f2bf(f);
  }
  int k8s = swz_col(n, k8);
  *(u16x8*)(Bt + (size_t)n*KAW + k8s) = v;
}

// gate epilogue: nxt holds accumulated pre-activation; apply bias+sigmoid+update
__global__ void gate_update(const float* __restrict__ bfv, const float* __restrict__ att,
                            const float* __restrict__ cur, float* __restrict__ nxt, int total){
  int idx = blockIdx.x*256 + threadIdx.x;
  if(idx >= total) return;
  int col = idx % DD;
  float pre = nxt[idx] + bfv[col];
  float g = 1.f/(1.f + expf(-pre));
  nxt[idx] = g*att[idx] + (1.f - g)*cur[idx];
}

// ---------------- final scores + per-row loss -------------------------------
__global__ void final_loss(const float* __restrict__ sc, const int* __restrict__ ante,
                           const int* __restrict__ tclust, float* out_fs, float* row_loss, int m){
  int i = blockIdx.x*blockDim.x + threadIdx.x;
  if(i >= m) return;
  int tci = tclust[i];
  unsigned long long labm = 0ull;
  bool anyp = false;
  float mx = 0.f;
  float mg = -FLT_MAX;
  for(int t=0;t<K2;t++){
    float v = sc[(size_t)i*K2 + t];
    mx = fmaxf(mx, v);
    int j = ante[(size_t)i*K2 + t];
    bool mk = (j < i);
    int ac = mk ? tclust[j] : -1;
    bool p = (ac == tci) && (tci > 0);
    if(p){ labm |= (1ull << (t+1)); anyp = true; mg = fmaxf(mg, v); }
  }
  if(!anyp){ labm |= 1ull; mg = 0.f; }
  float s1 = expf(0.f - mx);
  float s2 = (labm & 1ull) ? expf(0.f - mg) : 0.f;
  float* o = out_fs + (size_t)i*(K2+1);
  o[0] = 0.f;
  for(int t=0;t<K2;t++){
    float v = sc[(size_t)i*K2 + t];
    o[t+1] = v;
    s1 += expf(v - mx);
    if(labm & (1ull << (t+1))) s2 += expf(v - mg);
  }
  row_loss[i] = (mx + logf(s1)) - (mg + logf(s2));
}

__global__ void loss_sum(const float* __restrict__ row_loss, float* out, int m){
  int tid = threadIdx.x;
  float s = 0.f;
  for(int i=tid; i<m; i+=256) s += row_loss[i];
  __shared__ float red[256];
  red[tid]=s; __syncthreads();
  for(int st=128; st>0; st>>=1){ if(tid<st) red[tid]+=red[tid+st]; __syncthreads(); }
  if(tid==0) out[0] = red[0];
}

// ---------------------------------------------------------------------------
extern "C" void kernel_launch(void* const* d_in, const int* in_sizes, int n_in,
                              void* d_out, int out_size, void* d_ws, size_t ws_size,
                              hipStream_t stream){
  const int W = in_sizes[11];
  const int G = in_sizes[12];
  const int C = W * MSW;
  const int m = (int)(0.4 * (double)W);

  const float* seq   = (const float*)d_in[0];
  const float* Wal   = (const float*)d_in[1];
  const float* bal   = (const float*)d_in[2];
  const float* Wm    = (const float*)d_in[3];
  const float* bm    = (const float*)d_in[4];
  const float* Wc    = (const float*)d_in[5];
  const float* WaA   = (const float*)d_in[6];
  const float* baA   = (const float*)d_in[7];
  const float* Wf    = (const float*)d_in[8];
  const float* bf    = (const float*)d_in[9];
  const float* wfeat = (const float*)d_in[10];
  const int*   smap  = (const int*)d_in[11];
  const int*   gs    = (const int*)d_in[12];
  const int*   ge    = (const int*)d_in[13];
  const int*   cid   = (const int*)d_in[14];
  float* out = (float*)d_out;

  // workspace layout (phase-aliased; peak ~59 MB, proven safe <65 MB)
  char* ws = (char*)d_ws;
  size_t off = 0;
  auto alloc = [&](size_t bytes)->char*{
    char* p = ws + off;
    off += (bytes + 255) & ~(size_t)255;
    return p;
  };
  const size_t PLANE  = (size_t)MPAD*KPAD*2;   // 4.36 MB
  const size_t WPLANE = (size_t)NPAD*KPAD*2;   // 11.83 MB

  float* alphas  = (float*)alloc((size_t)W*4);
  float* p1      = (float*)alloc((size_t)W*4);
  float* p2      = (float*)alloc((size_t)W*4);
  float* p3      = (float*)alloc((size_t)W*4);
  float* mscore  = (float*)alloc((size_t)C*4);
  float* mmask   = (float*)alloc((size_t)C*4);
  int*   ccl     = (int*)  alloc((size_t)C*4);
  int*   top_idx = (int*)  alloc((size_t)m*4);
  float* tscore  = (float*)alloc((size_t)m*4);
  int*   tclust  = (int*)  alloc((size_t)m*4);
  float* B1      = (float*)alloc((size_t)m*DD*4);  // top_rep / reps ping
  float* B2      = (float*)alloc((size_t)m*DD*4);  // tmp / reps pong
  float* B3      = (float*)alloc((size_t)m*DD*4);  // attended
  float* bilin   = (float*)alloc((size_t)m*m*4);   // bilin (fast scores)
  int*   ante    = (int*)  alloc((size_t)m*K2*4);
  float* tafast  = (float*)alloc((size_t)m*K2*4);
  float* uB      = (float*)alloc((size_t)m*4);
  float* vB      = (float*)alloc((size_t)m*4);
  float* scB     = (float*)alloc((size_t)m*K2*4);
  float* rloss   = (float*)alloc((size_t)m*4);
  // regionA (2*PLANE), phase-aliased:
  //   bilinear: RepH | RepL      gate: Acat (spans both)
  char* regionA = alloc(2*PLANE);
  unsigned short* RepH  = (unsigned short*)regionA;
  unsigned short* RepL  = (unsigned short*)(regionA + PLANE);
  unsigned short* Acat  = (unsigned short*)regionA;            // MPAD*KAW*2 == 2*PLANE
  // regionB (2*WPLANE), phase-aliased:
  //   gemm1: WtH | WtL   ->  gemm2: A2H | A2L (after gemm1 done)  ->  depth: BtWf
  char* regionB = alloc(2*WPLANE);
  unsigned short* WtH  = (unsigned short*)regionB;
  unsigned short* WtL  = (unsigned short*)(regionB + WPLANE);
  unsigned short* A2H  = (unsigned short*)regionB;
  unsigned short* A2L  = (unsigned short*)(regionB + PLANE);
  unsigned short* BtWf = (unsigned short*)regionB;             // NPAD*KAW*2 == 2*WPLANE

  // output offsets (all float32)
  float* out_ts   = out;
  float* out_te   = out + m;
  float* out_ante = out + 2*m;
  float* out_fs   = out + 2*m + (size_t)m*K2;
  float* out_loss = out + 2*m + (size_t)m*K2 + (size_t)m*(K2+1);

  // 1) per-token projections
  row_proj<<<W, 256, 0, stream>>>(seq, Wal, bal, Wm, alphas, p1, p2, p3, W);
  // 2) candidate mention scores
  mention_kernel<<<(C+255)/256, 256, 0, stream>>>(alphas, p1, p2, p3, wfeat, Wm, bm,
                                                  smap, gs, ge, cid, G,
                                                  mscore, mmask, ccl, W);
  // 3) exact top-m selection + compaction
  select_kernel<<<1, 1024, 0, stream>>>(mmask, mscore, ccl, m, C, W,
                                        top_idx, tscore, tclust, out_ts, out_te);
  // 4) build top_rep into B1
  build_rep<<<m, 256, 0, stream>>>(seq, alphas, wfeat, top_idx, B1, W);
  // 5) bilinear antecedent scores via split-bf16 3-term MFMA (split-K, atomic)
  {
    const int NEL = MPAD*KPAD;
    // conv_split also zeroes B2 (g1's atomic target)
    conv_split<<<(NEL+255)/256, 256, 0, stream>>>(B1, m, DD, RepH, RepL, B2, m*DD);
    dim3 gw(KPAD/8, NPAD/64);
    conv_split_wcT<<<gw, 64, 0, stream>>>(Wc, WtH, WtL);
    dim3 g1(NPAD/128, MPAD/128, 3);     // (19, 7, 3) = 399 blocks <= 512: no tail wave
    gemm_split3_sk<<<g1, 256, 0, stream>>>(RepH, RepL, WtH, WtL, B2, m, DD, DD);
    // conv_split also zeroes bilin (g2's atomic target)
    conv_split<<<(NEL+255)/256, 256, 0, stream>>>(B2, m, DD, A2H, A2L, bilin, m*m);
    dim3 g2(MPAD/128, MPAD/128, 10);    // (7, 7, 10) = 490 blocks <= 512
    gemm_split3_sk<<<g2, 256, 0, stream>>>(A2H, A2L, RepH, RepL, bilin, m, m, m);
  }
  // 6) per-row top-50 (1 wave per row, register-resident)
  topante_kernel<<<m, 64, 0, stream>>>(tscore, bilin, m, ante, tafast, out_ante);
  // gate weights -> bf16 transposed (AFTER bilinear GEMMs: regionB alias)
  {
    dim3 g(KAW/8, NPAD/64);
    conv_wf<<<g, 64, 0, stream>>>(Wf, BtWf);
  }

  // 7) DEPTH=2 refinement (oversubscribed dots + d-split attend + gate GEMM)
  float* cur = B1; float* nxt = B2;
  const int total = m * DD;
  for(int depth=0; depth<2; depth++){
    uv_kernel<<<m, 256, 0, stream>>>(cur, WaA, uB, vB, m);
    // R12: gathered dots (grid 5 x m, 16.4k waves)
    slow_dots<<<dim3(5, m), 256, 0, stream>>>(cur, WaA, uB, vB, ante, tafast, baA, scB, m);
    // R12: d-split attend (grid 4 x m, full occupancy)
    attend_d<<<dim3(4, m), 256, 0, stream>>>(cur, scB, ante, B3, m);
    // gate pre-activation accumulates into zeroed nxt; conv_acat zeroes nxt
    conv_acat<<<(MPAD*KAW+255)/256, 256, 0, stream>>>(cur, B3, Acat, nxt, total, m);
    dim3 gg(NPAD/128, MPAD/128, 3);     // (19, 7, 3) = 399 blocks <= 512: no tail wave
    gemm_bf16_m97<<<gg, 256, 0, stream>>>(Acat, BtWf, nxt, m, DD, DD, KAW, KAW/64);
    gate_update<<<(total+255)/256, 256, 0, stream>>>(bf, B3, cur, nxt, total);
    float* t = cur; cur = nxt; nxt = t;
  }

  // 8) final scores + loss
  final_loss<<<(m+255)/256, 256, 0, stream>>>(scB, ante, tclust, out_fs, rloss, m);
  loss_sum<<<1, 256, 0, stream>>>(rloss, out_loss, m);
}

// Round 13
// 710.265 us; speedup vs baseline: 1.2136x; 1.0112x over previous
//
#include <hip/hip_runtime.h>
#include <cfloat>
#include <climits>
#include <math.h>

#define HD   768
#define MSW  10
#define WFK  20
#define DD   2324    // 3*768+20
#define K2   50
#define NEGF (-1e30f)

// MFMA geometry (K padded to mult of 128 for deep-K tiles)
#define KPAD 2432          // 19*128, >= DD
#define KAW  4864          // 2*KPAD  (K-concat of [cur | att] for the gate GEMM)
#define MPAD 896           // 7 * 128 (>= m=819)
#define NPAD 2432          // 19 * 128 (>= DD)

typedef __attribute__((ext_vector_type(8))) short    s8b;
typedef __attribute__((ext_vector_type(8))) unsigned short u16x8;
typedef __attribute__((ext_vector_type(4))) float    f32x4;

__device__ inline unsigned short f2bf(float f){
  unsigned u = __float_as_uint(f);
  unsigned r = (u + 0x7FFFu + ((u >> 16) & 1u)) >> 16;   // RNE
  return (unsigned short)r;
}
__device__ inline float bf2f(unsigned short h){
  return __uint_as_float(((unsigned)h) << 16);
}

// async global->LDS, 16B per lane; LDS dest must be wave-uniform base (+lane*16 implicit)
__device__ __forceinline__ void gload16(const unsigned short* g, void* l){
  __builtin_amdgcn_global_load_lds(
      (const __attribute__((address_space(1))) void*)g,
      (__attribute__((address_space(3))) void*)l, 16, 0, 0);
}

// ---- bank-conflict swizzle (both-sides involution, rule #21) ----------------
// Verified R2: SQ_LDS_BANK_CONFLICT 7.76M -> 0.
__device__ __forceinline__ int swz_col(int row, int col){
  return col ^ ((row & 7) << 3);
}

// ---- T1: XCD-aware bijective block remap (m204 form) ------------------------
// Verified R7: g1 64.4 -> ~58us, frame -30us. Pure index permutation.
__device__ __forceinline__ void xcd_remap(int &bx, int &by, int &bz){
  int nwg  = (int)(gridDim.x*gridDim.y*gridDim.z);
  int orig = (int)(blockIdx.x + gridDim.x*(blockIdx.y + gridDim.y*blockIdx.z));
  int q = nwg >> 3, r = nwg & 7;
  int x8 = orig & 7, o8 = orig >> 3;
  int wg = (x8 < r ? x8*(q+1) : r*(q+1) + (x8-r)*q) + o8;
  bx = wg % (int)gridDim.x;
  int tmp = wg / (int)gridDim.x;
  by = tmp % (int)gridDim.y;
  bz = tmp / (int)gridDim.y;
}

// ---------------- per-token projections: alphas, p1,p2,p3 -------------------
__global__ void row_proj(const float* __restrict__ seq, const float* __restrict__ Wa,
                         const float* __restrict__ ba, const float* __restrict__ Wm,
                         float* alphas, float* p1, float* p2, float* p3, int W){
  int w = blockIdx.x; int tid = threadIdx.x;
  const float* row = seq + (size_t)w * HD;
  float s0=0.f, s1=0.f, s2=0.f, s3=0.f;
  for(int h=tid; h<HD; h+=256){
    float x = row[h];
    s0 += x * Wa[h];
    s1 += x * Wm[h];
    s2 += x * Wm[HD + h];
    s3 += x * Wm[2*HD + h];
  }
  __shared__ float r0[256], r1[256], r2[256], r3[256];
  r0[tid]=s0; r1[tid]=s1; r2[tid]=s2; r3[tid]=s3;
  __syncthreads();
  for(int st=128; st>0; st>>=1){
    if(tid<st){ r0[tid]+=r0[tid+st]; r1[tid]+=r1[tid+st]; r2[tid]+=r2[tid+st]; r3[tid]+=r3[tid+st]; }
    __syncthreads();
  }
  if(tid==0){ alphas[w]=r0[0]+ba[0]; p1[w]=r1[0]; p2[w]=r2[0]; p3[w]=r3[0]; }
}

// ---------------- mention scoring per candidate -----------------------------
__global__ void mention_kernel(const float* __restrict__ alphas, const float* __restrict__ p1,
                               const float* __restrict__ p2, const float* __restrict__ p3,
                               const float* __restrict__ wfeat, const float* __restrict__ Wm,
                               const float* __restrict__ bm,
                               const int* __restrict__ smap, const int* __restrict__ gs,
                               const int* __restrict__ ge, const int* __restrict__ cid, int G,
                               float* mscore, float* mmask, int* ccl, int W){
  int c = blockIdx.x*blockDim.x + threadIdx.x;
  int C = W * MSW;
  if(c >= C) return;
  int s = c / MSW, r = c - s*MSW;
  int e = s + r; int ec = min(e, W-1);
  int L = ec - s;
  bool valid = (e < W) && (smap[s] == smap[ec]);
  float maxa = -FLT_MAX;
  for(int j=0;j<=L;j++) maxa = fmaxf(maxa, alphas[s+j]);
  float sum=0.f, sdot=0.f;
  for(int j=0;j<=L;j++){ float ee = expf(alphas[s+j]-maxa); sum += ee; sdot += ee*p3[s+j]; }
  sdot /= sum;
  float wp=0.f;
  for(int f=0; f<WFK; f++) wp += wfeat[L*WFK+f] * Wm[3*HD+f];
  float ms = p1[s] + p2[ec] + sdot + wp + bm[0];
  mscore[c] = ms;
  mmask[c]  = valid ? ms : NEGF;
  int cc = 0;
  for(int g=0; g<G; g++) if(s==gs[g] && ec==ge[g]) cc += cid[g];
  ccl[c] = cc;
}

// ---------------- single-block exact top-m radix select ---------------------
// R13: serial scans parallelized. (a) the tid==0 256-bin pick is now a
// 256-thread suffix-scan + unique-winner predicate (equivalent: winner =
// highest b with SS[b]>=rem, fallback b=0; s_rem = rem - SS[b+1]);
// (b) the two 1024-wide Hillis-Steele scans (20 barriers each) are now
// wave-shfl scans + 16-partial combine (2 barriers each).
__device__ inline unsigned fkey(float f){
  unsigned b = __float_as_uint(f);
  return (b & 0x80000000u) ? ~b : (b | 0x80000000u);
}

__global__ __launch_bounds__(1024)
void select_kernel(const float* __restrict__ mmask, const float* __restrict__ mscore,
                   const int* __restrict__ ccl, int m, int C, int W,
                   int* top_idx, float* tscore, int* tclust,
                   float* out_ts, float* out_te){
  const int T = 1024;
  int tid = threadIdx.x;
  int lane = tid & 63, wid = tid >> 6;          // 16 waves
  int chunk = (C + T - 1)/T;
  int lo = tid*chunk, hi = min(lo+chunk, C);
  int n = hi - lo; if(n < 0) n = 0;
  unsigned kb[32];
  for(int t=0;t<n;t++) kb[t] = fkey(mmask[lo+t]);

  __shared__ unsigned s_hist[256];
  __shared__ unsigned s_w4[4];
  __shared__ unsigned s_w16[16];
  __shared__ unsigned s_pref;
  __shared__ int s_rem;
  if(tid==0){ s_pref=0u; s_rem=m; }
  __syncthreads();

  for(int b=3;b>=0;b--){
    if(tid<256) s_hist[tid]=0u;
    __syncthreads();
    unsigned pref = s_pref;
    unsigned msk = (b==3)?0u:(0xFFFFFFFFu << ((b+1)*8));
    for(int t=0;t<n;t++){
      unsigned u = kb[t];
      if((u & msk)==pref) atomicAdd(&s_hist[(u>>(b*8))&0xFFu], 1u);
    }
    __syncthreads();
    // parallel suffix-sum: thread t handles bin bbin=255-t; P = SS[bbin]
    unsigned x = 0, hb = 0;
    if(tid < 256){
      hb = s_hist[255 - tid];
      x = hb;
      #pragma unroll
      for(int off=1; off<64; off<<=1){
        unsigned y = __shfl_up(x, off);
        if(lane >= off) x += y;
      }
      if(lane==63) s_w4[wid] = x;      // wid 0..3 here
    }
    __syncthreads();
    if(tid < 256){
      unsigned add = 0;
      for(int q=0; q<wid; q++) add += s_w4[q];
      unsigned P = x + add;            // SS[255-tid]
      int bbin = 255 - tid;
      unsigned rem = (unsigned)s_rem;
      unsigned SSb1 = P - hb;          // SS[bbin+1]
      bool win = (bbin == 0) ? (SSb1 < rem) : (P >= rem && SSb1 < rem);
      if(win){
        s_pref = pref | ((unsigned)bbin << (b*8));
        s_rem  = (int)(rem - SSb1);
      }
    }
    __syncthreads();
  }
  unsigned Tk = s_pref;
  int need = s_rem;

  unsigned nG=0, nE=0;
  for(int t=0;t<n;t++){ unsigned u=kb[t]; nG += (u>Tk)?1u:0u; nE += (u==Tk)?1u:0u; }

  // scan #1: inclusive prefix of nE over 1024 threads (wave shfl + combine)
  unsigned x1 = nE;
  #pragma unroll
  for(int off=1; off<64; off<<=1){
    unsigned y = __shfl_up(x1, off);
    if(lane >= off) x1 += y;
  }
  if(lane==63) s_w16[wid] = x1;
  __syncthreads();
  if(wid==0){
    unsigned wv = (lane<16) ? s_w16[lane] : 0u;
    #pragma unroll
    for(int off=1; off<16; off<<=1){
      unsigned y = __shfl_up(wv, off);
      if(lane >= off) wv += y;
    }
    if(lane<16) s_w16[lane] = wv;      // inclusive wave sums
  }
  __syncthreads();
  unsigned incl1 = x1 + (wid>0 ? s_w16[wid-1] : 0u);
  unsigned eqBase = incl1 - nE;

  int takeLeft = need - (int)eqBase;
  int take = takeLeft<0?0:(takeLeft>(int)nE?(int)nE:takeLeft);
  unsigned selCnt = nG + (unsigned)take;

  // scan #2: inclusive prefix of selCnt
  __syncthreads();                     // protect s_w16 reuse
  unsigned x2 = selCnt;
  #pragma unroll
  for(int off=1; off<64; off<<=1){
    unsigned y = __shfl_up(x2, off);
    if(lane >= off) x2 += y;
  }
  if(lane==63) s_w16[wid] = x2;
  __syncthreads();
  if(wid==0){
    unsigned wv = (lane<16) ? s_w16[lane] : 0u;
    #pragma unroll
    for(int off=1; off<16; off<<=1){
      unsigned y = __shfl_up(wv, off);
      if(lane >= off) wv += y;
    }
    if(lane<16) s_w16[lane] = wv;
  }
  __syncthreads();
  unsigned incl2 = x2 + (wid>0 ? s_w16[wid-1] : 0u);
  unsigned posBase = incl2 - selCnt;

  int pos = (int)posBase; int eq = (int)eqBase;
  for(int t=0;t<n;t++){
    unsigned u = kb[t];
    bool sel = false;
    if(u>Tk) sel=true;
    else if(u==Tk){ if(eq<need) sel=true; eq++; }
    if(sel){
      int c = lo+t;
      top_idx[pos] = c;
      int s = c/MSW, r = c - s*MSW; int e = min(s + r, W-1);
      tscore[pos] = mscore[c];
      tclust[pos] = ccl[c];
      out_ts[pos] = (float)s;
      out_te[pos] = (float)e;
      pos++;
    }
  }
}

// ---------------- build top_rep (m x D) -------------------------------------
__global__ void build_rep(const float* __restrict__ seq, const float* __restrict__ alphas,
                          const float* __restrict__ wfeat, const int* __restrict__ top_idx,
                          float* rep, int W){
  int i = blockIdx.x; int tid = threadIdx.x;
  int c = top_idx[i];
  int s = c/MSW, r = c - s*MSW; int ec = min(s + r, W-1); int L = ec - s;
  float wv[MSW];
  float maxa = -FLT_MAX;
  for(int j=0;j<=L;j++) maxa = fmaxf(maxa, alphas[s+j]);
  float sum = 0.f;
  for(int j=0;j<=L;j++){ wv[j] = expf(alphas[s+j]-maxa); sum += wv[j]; }
  float inv = 1.f/sum;
  float* o = rep + (size_t)i*DD;
  for(int d=tid; d<HD; d+=256){
    o[d]      = seq[(size_t)s*HD + d];
    o[HD+d]   = seq[(size_t)ec*HD + d];
    float sp = 0.f;
    for(int j=0;j<=L;j++) sp += wv[j]*seq[(size_t)(s+j)*HD + d];
    o[2*HD+d] = sp*inv;
  }
  for(int f=tid; f<WFK; f+=256) o[3*HD+f] = wfeat[L*WFK+f];
}

// ---------------- split-bf16 conversions (SWIZZLED output layout) -----------
// Fused zeroing of the next GEMM's accumulation target (ztgt[0..zn)).
__global__ void conv_split(const float* __restrict__ src, int rows, int cols,
                           unsigned short* __restrict__ hi, unsigned short* __restrict__ lo,
                           float* __restrict__ ztgt, int zn){
  int idx = blockIdx.x*256 + threadIdx.x;
  if(idx >= MPAD*KPAD) return;
  if(idx < zn) ztgt[idx] = 0.f;
  int row = idx / KPAD, col = idx - row*KPAD;
  float v = (row < rows && col < cols) ? src[(size_t)row*cols + col] : 0.f;
  unsigned short h = f2bf(v);
  int w = row*KPAD + swz_col(row, col);
  hi[w] = h;
  lo[w] = f2bf(v - bf2f(h));
}

// Wc (DD x DD) -> transposed hi/lo planes (NPAD x KPAD): Wt[n][k] = Wc[k][n]
__global__ void conv_split_wcT(const float* __restrict__ Wc,
                               unsigned short* __restrict__ WtH, unsigned short* __restrict__ WtL){
  int n  = blockIdx.y*64 + threadIdx.x;
  int k8 = blockIdx.x*8;
  u16x8 vh, vl;
  #pragma unroll
  for(int j=0;j<8;j++){
    int k = k8 + j;
    float f = (n < DD && k < DD) ? Wc[(size_t)k*DD + n] : 0.f;
    unsigned short h = f2bf(f);
    vh[j] = h;
    vl[j] = f2bf(f - bf2f(h));
  }
  int k8s = swz_col(n, k8);          // XOR hits bits 3-5 only; 16B granularity
  *(u16x8*)(WtH + (size_t)n*KPAD + k8s) = vh;
  *(u16x8*)(WtL + (size_t)n*KPAD + k8s) = vl;
}

// ---------------- split-bf16 3-term MFMA GEMM, split-K ----------------------
// R5-measured-best structure + R7 T1 remap: single-buffered linear LDS via
// global_load_lds, 2 barriers per BK=64 step. LDS = 4 planes x 16 KiB = 64 KiB
// -> 2 blocks/CU. Swizzled reads (conflicts = 0). Grid <= 512 blocks.
__global__ __launch_bounds__(256,2)
void gemm_split3_sk(const unsigned short* __restrict__ Ah, const unsigned short* __restrict__ Al,
                    const unsigned short* __restrict__ Bth, const unsigned short* __restrict__ Btl,
                    float* __restrict__ C, int M, int N, int ldc){
  __shared__ __align__(16) unsigned short sAh[128*64];
  __shared__ __align__(16) unsigned short sAl[128*64];
  __shared__ __align__(16) unsigned short sBh[128*64];
  __shared__ __align__(16) unsigned short sBl[128*64];
  int bx, by, bz; xcd_remap(bx, by, bz);
  int t = threadIdx.x;
  int row0 = by*128, col0 = bx*128;
  const int tiles = KPAD/64;                              // 38
  int per = (tiles + (int)gridDim.z - 1)/(int)gridDim.z;
  int tb = min(bz*per, tiles), te = min(tb + per, tiles);
  if(tb >= te) return;
  int lane = t&63, w = t>>6;
  int wr = (w>>1)*64, wc = (w&1)*64;
  int quad = lane>>4, l15 = lane&15;
  int seg = lane&7;
  size_t ro = (size_t)(w*8 + (lane>>3));                  // staging row within 32-row group
  const unsigned short* gAh = Ah  + ((size_t)row0 + ro)*KPAD + seg*8;
  const unsigned short* gAl = Al  + ((size_t)row0 + ro)*KPAD + seg*8;
  const unsigned short* gBh = Bth + ((size_t)col0 + ro)*KPAD + seg*8;
  const unsigned short* gBl = Btl + ((size_t)col0 + ro)*KPAD + seg*8;
  const int lds0 = (w*8)*64;                              // wave-uniform LDS base (shorts)
  // swizzled read chunk offsets (shorts): ks=0 -> c0, ks=1 -> c0^32
  const int c0 = ((quad ^ (l15 & 7)) << 3);

  f32x4 acc[4][4];
  #pragma unroll
  for(int mi=0;mi<4;mi++)
    #pragma unroll
    for(int ni=0;ni<4;ni++) acc[mi][ni] = (f32x4){0.f,0.f,0.f,0.f};

  for(int kt=tb; kt<te; ++kt){
    size_t k0 = (size_t)kt*64;
    #pragma unroll
    for(int r=0;r<4;r++){
      size_t go = (size_t)(r*32)*KPAD + k0;
      int lo = lds0 + r*32*64;
      gload16(gAh + go, sAh + lo);
      gload16(gAl + go, sAl + lo);
      gload16(gBh + go, sBh + lo);
      gload16(gBl + go, sBl + lo);
    }
    __syncthreads();   // drains vmcnt(0): tile landed in LDS
    #pragma unroll
    for(int ks=0;ks<2;ks++){
      const int co = c0 ^ (ks<<5);
      s8b fah[4], fal[4], fbh[4], fbl[4];
      #pragma unroll
      for(int mi=0;mi<4;mi++){
        int ra = (wr+mi*16+l15)*64 + co;
        fah[mi] = *(const s8b*)&sAh[ra];
        fal[mi] = *(const s8b*)&sAl[ra];
      }
      #pragma unroll
      for(int ni=0;ni<4;ni++){
        int rb = (wc+ni*16+l15)*64 + co;
        fbh[ni] = *(const s8b*)&sBh[rb];
        fbl[ni] = *(const s8b*)&sBl[rb];
      }
      #pragma unroll
      for(int mi=0;mi<4;mi++)
        #pragma unroll
        for(int ni=0;ni<4;ni++){
          acc[mi][ni] = __builtin_amdgcn_mfma_f32_16x16x32_bf16(fah[mi], fbh[ni], acc[mi][ni], 0,0,0);
          acc[mi][ni] = __builtin_amdgcn_mfma_f32_16x16x32_bf16(fah[mi], fbl[ni], acc[mi][ni], 0,0,0);
          acc[mi][ni] = __builtin_amdgcn_mfma_f32_16x16x32_bf16(fal[mi], fbh[ni], acc[mi][ni], 0,0,0);
        }
    }
    __syncthreads();   // all waves done reading before next stage overwrites
  }

  #pragma unroll
  for(int ni=0;ni<4;ni++){
    int gn = col0 + wc + ni*16 + l15;
    if(gn >= N) continue;
    #pragma unroll
    for(int mi=0;mi<4;mi++){
      #pragma unroll
      for(int rg=0;rg<4;rg++){
        int gr = row0 + wr + mi*16 + quad*4 + rg;
        if(gr >= M) continue;
        atomicAdd(&C[(size_t)gr*ldc + gn], acc[mi][ni][rg]);
      }
    }
  }
}

// ---------------- plain bf16 MFMA GEMM, split-K (2-phase dbuf, BK=64) -------
// R7-proven config (58.7us @ gg). Used only for the gate GEMM (ldk=KAW).
__global__ __launch_bounds__(256,2)
void gemm_bf16_m97(const unsigned short* __restrict__ A, const unsigned short* __restrict__ Bt,
                   float* __restrict__ C, int M, int N, int ldc, int ldk, int tiles){
  __shared__ __align__(16) unsigned short sA[2][128*64];
  __shared__ __align__(16) unsigned short sB[2][128*64];
  int bx, by, bz; xcd_remap(bx, by, bz);
  int t = threadIdx.x;
  int row0 = by*128, col0 = bx*128;
  int per = (tiles + (int)gridDim.z - 1)/(int)gridDim.z;
  int tb = min(bz*per, tiles), te = min(tb + per, tiles);
  if(tb >= te) return;
  int lane = t&63, w = t>>6;
  int wr = (w>>1)*64, wc = (w&1)*64;
  int quad = lane>>4, l15 = lane&15;
  int seg = lane&7;
  size_t ro = (size_t)(w*8 + (lane>>3));
  const unsigned short* gA = A  + ((size_t)row0 + ro)*ldk + seg*8;
  const unsigned short* gB = Bt + ((size_t)col0 + ro)*ldk + seg*8;
  const int lds0 = (w*8)*64;
  const int c0 = ((quad ^ (l15 & 7)) << 3);

  f32x4 acc[4][4];
  #pragma unroll
  for(int mi=0;mi<4;mi++)
    #pragma unroll
    for(int ni=0;ni<4;ni++) acc[mi][ni] = (f32x4){0.f,0.f,0.f,0.f};

  auto STAGE = [&](int b, int kt){
    size_t k0 = (size_t)kt*64;
    #pragma unroll
    for(int r=0;r<4;r++){
      size_t go = (size_t)(r*32)*ldk + k0;
      int lo = lds0 + r*32*64;
      gload16(gA + go, &sA[b][lo]);
      gload16(gB + go, &sB[b][lo]);
    }
  };

  STAGE(0, tb);
  __syncthreads();
  int buf = 0;
  for(int kt=tb; kt<te; ++kt){
    if(kt+1 < te) STAGE(buf^1, kt+1);
    #pragma unroll
    for(int ks=0;ks<2;ks++){
      const int co = c0 ^ (ks<<5);
      s8b fa[4], fb[4];
      #pragma unroll
      for(int mi=0;mi<4;mi++) fa[mi] = *(const s8b*)&sA[buf][(wr+mi*16+l15)*64 + co];
      #pragma unroll
      for(int ni=0;ni<4;ni++) fb[ni] = *(const s8b*)&sB[buf][(wc+ni*16+l15)*64 + co];
      #pragma unroll
      for(int mi=0;mi<4;mi++)
        #pragma unroll
        for(int ni=0;ni<4;ni++)
          acc[mi][ni] = __builtin_amdgcn_mfma_f32_16x16x32_bf16(fa[mi], fb[ni], acc[mi][ni], 0,0,0);
    }
    __syncthreads();
    buf ^= 1;
  }

  #pragma unroll
  for(int ni=0;ni<4;ni++){
    int gn = col0 + wc + ni*16 + l15;
    if(gn >= N) continue;
    #pragma unroll
    for(int mi=0;mi<4;mi++){
      #pragma unroll
      for(int rg=0;rg<4;rg++){
        int gr = row0 + wr + mi*16 + quad*4 + rg;
        if(gr >= M) continue;
        atomicAdd(&C[(size_t)gr*ldc + gn], acc[mi][ni][rg]);
      }
    }
  }
}

// ---------------- per-row top-50 antecedents (1 wave / row) -----------------
// Register-resident selection (R5-verified: bit-identical, ~10x faster than LDS).
#define NT 13   // ceil(m/64) for m<=832
__global__ void topante_kernel(const float* __restrict__ tscore, const float* __restrict__ bilin,
                               int m, int* ante, float* tafast, float* out_ante){
  int i = blockIdx.x; int lane = threadIdx.x;
  float tsi = tscore[i];
  float v[NT];
  #pragma unroll
  for(int t=0;t<NT;t++){
    int j = lane + t*64;
    float f = -FLT_MAX;
    if(j < m){
      f = tsi + tscore[j];
      f += (j < i) ? 0.f : NEGF;
      f += bilin[(size_t)i*m + j];
    }
    v[t] = f;
  }
  unsigned consumed = 0u;
  int r_ante = 0; float r_fast = 0.f;
  for(int it=0; it<K2; ++it){
    float lv = -FLT_MAX; int li = m;
    #pragma unroll
    for(int t=0;t<NT;t++){
      bool live = ((consumed >> t) & 1u) == 0u;
      if(live && v[t] > lv){ lv = v[t]; li = lane + t*64; }
    }
    float bv = lv; int bi = li;
    #pragma unroll
    for(int off=32; off>0; off>>=1){
      float ov = __shfl_xor(bv, off);
      int   oi = __shfl_xor(bi, off);
      if(ov > bv || (ov == bv && oi < bi)){ bv = ov; bi = oi; }
    }
    if(bi < m && (bi & 63) == lane) consumed |= (1u << (bi >> 6));
    if(lane == it){ r_ante = bi; r_fast = bv; }
  }
  if(lane < K2){
    ante[(size_t)i*K2 + lane]   = r_ante;
    tafast[(size_t)i*K2 + lane] = r_fast;
    out_ante[(size_t)i*K2+lane] = (float)r_ante;
  }
}

// ---------------- depth loop pieces -----------------------------------------
__global__ void uv_kernel(const float* __restrict__ reps, const float* __restrict__ Wa3,
                          float* u, float* v, int m){
  int i = blockIdx.x; int tid = threadIdx.x;
  const float* rp = reps + (size_t)i*DD;
  float s1=0.f, s2=0.f;
  for(int d=tid; d<DD; d+=256){ float x = rp[d]; s1 += x*Wa3[d]; s2 += x*Wa3[DD+d]; }
  __shared__ float r1[256], r2[256];
  r1[tid]=s1; r2[tid]=s2; __syncthreads();
  for(int st=128; st>0; st>>=1){
    if(tid<st){ r1[tid]+=r1[tid+st]; r2[tid]+=r2[tid+st]; }
    __syncthreads();
  }
  if(tid==0){ u[i]=r1[0]; v[i]=r2[0]; }
}

// ---------------- R12: gathered slow scores, oversubscribed grid ------------
__global__ __launch_bounds__(256)
void slow_dots(const float* __restrict__ cur, const float* __restrict__ Wa3,
               const float* __restrict__ u, const float* __restrict__ v,
               const int* __restrict__ ante, const float* __restrict__ tafast,
               const float* __restrict__ ba, float* __restrict__ sc, int m){
  int i  = blockIdx.y;
  int tq = blockIdx.x;                              // 0..4
  int tid = threadIdx.x;
  int lane = tid & 63, w = tid >> 6;
  __shared__ __align__(16) float xi[DD];            // DD = 2324 = 581 float4s
  const float* ri = cur + (size_t)i*DD;
  for(int k=tid; k<DD; k+=256) xi[k] = ri[k]*Wa3[2*DD + k];
  __syncthreads();
  const float ui = u[i], b0 = ba[0];
  const int D4 = DD/4;                              // 581 exactly
  const f32x4* xi4 = (const f32x4*)xi;
  int t0 = tq*10;
  for(int t=t0+w; t<t0+10; t+=4){
    int j = ante[(size_t)i*K2 + t];
    const f32x4* rj4 = (const f32x4*)(cur + (size_t)j*DD);
    float s = 0.f;
    for(int k=lane; k<D4; k+=64){
      f32x4 a = xi4[k], b = rj4[k];
      s += a[0]*b[0] + a[1]*b[1] + a[2]*b[2] + a[3]*b[3];
    }
    #pragma unroll
    for(int off=32; off>0; off>>=1) s += __shfl_xor(s, off);
    if(lane==0)
      sc[(size_t)i*K2 + t] = tafast[(size_t)i*K2 + t] + ui + v[j] + s + b0;
  }
}

// ---------------- R12: attend, d-split grid ---------------------------------
__global__ __launch_bounds__(256)
void attend_d(const float* __restrict__ cur, const float* __restrict__ sc,
              const int* __restrict__ ante, float* __restrict__ att, int m){
  int i  = blockIdx.y;
  int ch = blockIdx.x;                              // 0..3
  int tid = threadIdx.x;
  __shared__ float wts[K2+1];
  __shared__ float scs[K2];
  __shared__ int   js[K2];
  if(tid < K2){ scs[tid] = sc[(size_t)i*K2 + tid]; js[tid] = ante[(size_t)i*K2 + tid]; }
  __syncthreads();
  if(tid==0){
    float mx = 0.f;
    for(int t=0;t<K2;t++) mx = fmaxf(mx, scs[t]);
    float sum = expf(0.f - mx); wts[0] = sum;
    for(int t=0;t<K2;t++){ float e = expf(scs[t]-mx); wts[t+1]=e; sum += e; }
    float inv = 1.f/sum;
    for(int t=0;t<=K2;t++) wts[t] *= inv;
  }
  __syncthreads();
  const int D4 = DD/4;                              // 581
  const int C4 = 146;                               // ceil(581/4)
  int d4 = ch*C4 + tid;
  if(tid < C4 && d4 < D4){
    const f32x4* ri4 = (const f32x4*)(cur + (size_t)i*DD);
    f32x4 a = ri4[d4];
    float w0 = wts[0];
    a[0]*=w0; a[1]*=w0; a[2]*=w0; a[3]*=w0;
    for(int t=0;t<K2;t++){
      const f32x4* rj4 = (const f32x4*)(cur + (size_t)js[t]*DD);
      f32x4 b = rj4[d4];
      float wt = wts[t+1];
      a[0]+=wt*b[0]; a[1]+=wt*b[1]; a[2]+=wt*b[2]; a[3]+=wt*b[3];
    }
    ((f32x4*)(att + (size_t)i*DD))[d4] = a;
  }
}

// ---------------- bf16 conversion for the fused gate GEMM (SWIZZLED) --------
// Fused zeroing of nxt (the gg GEMM's atomic target, total = m*DD elems).
__global__ void conv_acat(const float* __restrict__ cur, const float* __restrict__ att,
                          unsigned short* __restrict__ A,
                          float* __restrict__ nxt, int total, int m){
  int idx = blockIdx.x*256 + threadIdx.x;
  if(idx >= MPAD*KAW) return;
  if(idx < total) nxt[idx] = 0.f;
  int row = idx / KAW, col = idx - row*KAW;
  float v = 0.f;
  if(row < m){
    if(col < DD) v = cur[(size_t)row*DD + col];
    else if(col >= KPAD && col < KPAD + DD) v = att[(size_t)row*DD + (col - KPAD)];
  }
  A[row*KAW + swz_col(row, col)] = f2bf(v);
}

// Bt_cat (NPAD x KAW): Bt[n][s*KPAD+k] = Wf[s*DD+k][n], zero-padded
__global__ void conv_wf(const float* __restrict__ Wf, unsigned short* __restrict__ Bt){
  int n  = blockIdx.y*64 + threadIdx.x;
  int k8 = blockIdx.x*8;
  int s  = (k8 >= KPAD) ? 1 : 0;
  int kk = k8 - s*KPAD;
  u16x8 v;
  #pragma unroll
  for(int j=0;j<8;j++){
    int k = kk + j;
    float f = (n < DD && k < DD) ? Wf[(size_t)(s*DD + k)*DD + n] : 0.f;
    v[j] = f2bf(f);
  }
  int k8s = swz_col(n, k8);
  *(u16x8*)(Bt + (size_t)n*KAW + k8s) = v;
}

// ---------------- R13: fused gate epilogue + next-depth u,v -----------------
// Per-row block: apply bias+sigmoid+gate update to nxt AND accumulate the
// u,v projections of the UPDATED row (replaces gate_update + following uv:
// saves one launch and one 7.6MB re-read pass). Values bit-identical: same
// per-element math, same strided accumulation order, same tree reduce.
// Also zeroes out_loss (block 0) for final_loss's atomic accumulation.
__global__ void gate_uv(const float* __restrict__ bfv, const float* __restrict__ att,
                        const float* __restrict__ cur, float* __restrict__ nxt,
                        const float* __restrict__ Wa3, float* u, float* v,
                        float* __restrict__ out_loss, int m){
  int i = blockIdx.x; int tid = threadIdx.x;
  if(i==0 && tid==0) out_loss[0] = 0.f;
  const size_t base = (size_t)i*DD;
  float s1=0.f, s2=0.f;
  for(int d=tid; d<DD; d+=256){
    float pre = nxt[base+d] + bfv[d];
    float g = 1.f/(1.f + expf(-pre));
    float val = g*att[base+d] + (1.f - g)*cur[base+d];
    nxt[base+d] = val;
    s1 += val*Wa3[d]; s2 += val*Wa3[DD+d];
  }
  __shared__ float r1[256], r2[256];
  r1[tid]=s1; r2[tid]=s2; __syncthreads();
  for(int st=128; st>0; st>>=1){
    if(tid<st){ r1[tid]+=r1[tid+st]; r2[tid]+=r2[tid+st]; }
    __syncthreads();
  }
  if(tid==0){ u[i]=r1[0]; v[i]=r2[0]; }
}

// ---------------- final scores + loss (R13: fused loss reduction) -----------
__global__ void final_loss(const float* __restrict__ sc, const int* __restrict__ ante,
                           const int* __restrict__ tclust, float* out_fs,
                           float* __restrict__ out_loss, int m){
  int i = blockIdx.x*blockDim.x + threadIdx.x;
  float L = 0.f;
  if(i < m){
    int tci = tclust[i];
    unsigned long long labm = 0ull;
    bool anyp = false;
    float mx = 0.f;
    float mg = -FLT_MAX;
    for(int t=0;t<K2;t++){
      float v = sc[(size_t)i*K2 + t];
      mx = fmaxf(mx, v);
      int j = ante[(size_t)i*K2 + t];
      bool mk = (j < i);
      int ac = mk ? tclust[j] : -1;
      bool p = (ac == tci) && (tci > 0);
      if(p){ labm |= (1ull << (t+1)); anyp = true; mg = fmaxf(mg, v); }
    }
    if(!anyp){ labm |= 1ull; mg = 0.f; }
    float s1 = expf(0.f - mx);
    float s2 = (labm & 1ull) ? expf(0.f - mg) : 0.f;
    float* o = out_fs + (size_t)i*(K2+1);
    o[0] = 0.f;
    for(int t=0;t<K2;t++){
      float v = sc[(size_t)i*K2 + t];
      o[t+1] = v;
      s1 += expf(v - mx);
      if(labm & (1ull << (t+1))) s2 += expf(v - mg);
    }
    L = (mx + logf(s1)) - (mg + logf(s2));
  }
  __shared__ float red[256];
  red[threadIdx.x] = L; __syncthreads();
  for(int st=128; st>0; st>>=1){
    if(threadIdx.x < st) red[threadIdx.x] += red[threadIdx.x+st];
    __syncthreads();
  }
  if(threadIdx.x==0) atomicAdd(out_loss, red[0]);
}

// ---------------------------------------------------------------------------
extern "C" void kernel_launch(void* const* d_in, const int* in_sizes, int n_in,
                              void* d_out, int out_size, void* d_ws, size_t ws_size,
                              hipStream_t stream){
  const int W = in_sizes[11];
  const int G = in_sizes[12];
  const int C = W * MSW;
  const int m = (int)(0.4 * (double)W);

  const float* seq   = (const float*)d_in[0];
  const float* Wal   = (const float*)d_in[1];
  const float* bal   = (const float*)d_in[2];
  const float* Wm    = (const float*)d_in[3];
  const float* bm    = (const float*)d_in[4];
  const float* Wc    = (const float*)d_in[5];
  const float* WaA   = (const float*)d_in[6];
  const float* baA   = (const float*)d_in[7];
  const float* Wf    = (const float*)d_in[8];
  const float* bf    = (const float*)d_in[9];
  const float* wfeat = (const float*)d_in[10];
  const int*   smap  = (const int*)d_in[11];
  const int*   gs    = (const int*)d_in[12];
  const int*   ge    = (const int*)d_in[13];
  const int*   cid   = (const int*)d_in[14];
  float* out = (float*)d_out;

  // workspace layout (phase-aliased; peak ~59 MB, proven safe <65 MB)
  char* ws = (char*)d_ws;
  size_t off = 0;
  auto alloc = [&](size_t bytes)->char*{
    char* p = ws + off;
    off += (bytes + 255) & ~(size_t)255;
    return p;
  };
  const size_t PLANE  = (size_t)MPAD*KPAD*2;   // 4.36 MB
  const size_t WPLANE = (size_t)NPAD*KPAD*2;   // 11.83 MB

  float* alphas  = (float*)alloc((size_t)W*4);
  float* p1      = (float*)alloc((size_t)W*4);
  float* p2      = (float*)alloc((size_t)W*4);
  float* p3      = (float*)alloc((size_t)W*4);
  float* mscore  = (float*)alloc((size_t)C*4);
  float* mmask   = (float*)alloc((size_t)C*4);
  int*   ccl     = (int*)  alloc((size_t)C*4);
  int*   top_idx = (int*)  alloc((size_t)m*4);
  float* tscore  = (float*)alloc((size_t)m*4);
  int*   tclust  = (int*)  alloc((size_t)m*4);
  float* B1      = (float*)alloc((size_t)m*DD*4);  // top_rep / reps ping
  float* B2      = (float*)alloc((size_t)m*DD*4);  // tmp / reps pong
  float* B3      = (float*)alloc((size_t)m*DD*4);  // attended
  float* bilin   = (float*)alloc((size_t)m*m*4);   // bilin (fast scores)
  int*   ante    = (int*)  alloc((size_t)m*K2*4);
  float* tafast  = (float*)alloc((size_t)m*K2*4);
  float* uB      = (float*)alloc((size_t)m*4);
  float* vB      = (float*)alloc((size_t)m*4);
  float* scB     = (float*)alloc((size_t)m*K2*4);
  float* rloss   = (float*)alloc((size_t)m*4);     // unused (kept for layout)
  // regionA (2*PLANE), phase-aliased:
  //   bilinear: RepH | RepL      gate: Acat (spans both)
  char* regionA = alloc(2*PLANE);
  unsigned short* RepH  = (unsigned short*)regionA;
  unsigned short* RepL  = (unsigned short*)(regionA + PLANE);
  unsigned short* Acat  = (unsigned short*)regionA;            // MPAD*KAW*2 == 2*PLANE
  // regionB (2*WPLANE), phase-aliased:
  //   gemm1: WtH | WtL   ->  gemm2: A2H | A2L (after gemm1 done)  ->  depth: BtWf
  char* regionB = alloc(2*WPLANE);
  unsigned short* WtH  = (unsigned short*)regionB;
  unsigned short* WtL  = (unsigned short*)(regionB + WPLANE);
  unsigned short* A2H  = (unsigned short*)regionB;
  unsigned short* A2L  = (unsigned short*)(regionB + PLANE);
  unsigned short* BtWf = (unsigned short*)regionB;             // NPAD*KAW*2 == 2*WPLANE
  (void)rloss;

  // output offsets (all float32)
  float* out_ts   = out;
  float* out_te   = out + m;
  float* out_ante = out + 2*m;
  float* out_fs   = out + 2*m + (size_t)m*K2;
  float* out_loss = out + 2*m + (size_t)m*K2 + (size_t)m*(K2+1);

  // 1) per-token projections
  row_proj<<<W, 256, 0, stream>>>(seq, Wal, bal, Wm, alphas, p1, p2, p3, W);
  // 2) candidate mention scores
  mention_kernel<<<(C+255)/256, 256, 0, stream>>>(alphas, p1, p2, p3, wfeat, Wm, bm,
                                                  smap, gs, ge, cid, G,
                                                  mscore, mmask, ccl, W);
  // 3) exact top-m selection + compaction (R13: parallel scans)
  select_kernel<<<1, 1024, 0, stream>>>(mmask, mscore, ccl, m, C, W,
                                        top_idx, tscore, tclust, out_ts, out_te);
  // 4) build top_rep into B1
  build_rep<<<m, 256, 0, stream>>>(seq, alphas, wfeat, top_idx, B1, W);
  // 5) bilinear antecedent scores via split-bf16 3-term MFMA (split-K, atomic)
  {
    const int NEL = MPAD*KPAD;
    // conv_split also zeroes B2 (g1's atomic target)
    conv_split<<<(NEL+255)/256, 256, 0, stream>>>(B1, m, DD, RepH, RepL, B2, m*DD);
    dim3 gw(KPAD/8, NPAD/64);
    conv_split_wcT<<<gw, 64, 0, stream>>>(Wc, WtH, WtL);
    dim3 g1(NPAD/128, MPAD/128, 3);     // (19, 7, 3) = 399 blocks <= 512: no tail wave
    gemm_split3_sk<<<g1, 256, 0, stream>>>(RepH, RepL, WtH, WtL, B2, m, DD, DD);
    // conv_split also zeroes bilin (g2's atomic target)
    conv_split<<<(NEL+255)/256, 256, 0, stream>>>(B2, m, DD, A2H, A2L, bilin, m*m);
    dim3 g2(MPAD/128, MPAD/128, 10);    // (7, 7, 10) = 490 blocks <= 512
    gemm_split3_sk<<<g2, 256, 0, stream>>>(A2H, A2L, RepH, RepL, bilin, m, m, m);
  }
  // 6) per-row top-50 (1 wave per row, register-resident)
  topante_kernel<<<m, 64, 0, stream>>>(tscore, bilin, m, ante, tafast, out_ante);
  // gate weights -> bf16 transposed (AFTER bilinear GEMMs: regionB alias)
  {
    dim3 g(KAW/8, NPAD/64);
    conv_wf<<<g, 64, 0, stream>>>(Wf, BtWf);
  }

  // 7) DEPTH=2 refinement (dots + attend + gate GEMM + fused gate/uv)
  float* cur = B1; float* nxt = B2;
  const int total = m * DD;
  uv_kernel<<<m, 256, 0, stream>>>(cur, WaA, uB, vB, m);   // u,v of initial reps
  for(int depth=0; depth<2; depth++){
    // R12: gathered dots (grid 5 x m, 16.4k waves)
    slow_dots<<<dim3(5, m), 256, 0, stream>>>(cur, WaA, uB, vB, ante, tafast, baA, scB, m);
    // R12: d-split attend (grid 4 x m, full occupancy)
    attend_d<<<dim3(4, m), 256, 0, stream>>>(cur, scB, ante, B3, m);
    // gate pre-activation accumulates into zeroed nxt; conv_acat zeroes nxt
    conv_acat<<<(MPAD*KAW+255)/256, 256, 0, stream>>>(cur, B3, Acat, nxt, total, m);
    dim3 gg(NPAD/128, MPAD/128, 3);     // (19, 7, 3) = 399 blocks <= 512: no tail wave
    gemm_bf16_m97<<<gg, 256, 0, stream>>>(Acat, BtWf, nxt, m, DD, DD, KAW, KAW/64);
    // R13: fused gate update + next-depth u,v (+ out_loss zeroing)
    gate_uv<<<m, 256, 0, stream>>>(bf, B3, cur, nxt, WaA, uB, vB, out_loss, m);
    float* t = cur; cur = nxt; nxt = t;
  }

  // 8) final scores + loss (fused reduction, atomicAdd into zeroed out_loss)
  final_loss<<<(m+255)/256, 256, 0, stream>>>(scB, ante, tclust, out_fs, out_loss, m);
}